// Round 2
// 635.251 us; speedup vs baseline: 1.0554x; 1.0554x over previous
//
#include <hip/hip_runtime.h>
#include <stdint.h>

// LinearAttention (gated delta rule), S=2048, HID=2048, H=16, DK=64, DV=128, conv K=4.
// r12: fix r11's aliasing bug (wlocT@12M overlapped wzb[8,16M) -> z path corrupted,
// absmax 1.94) and harden precision:
//   - phase B now computes delta (f32, from f32 state) AND O1 = d_t*(Q S0) (f32),
//     so the running state never round-trips through bf16 (sstore removed).
//   - wlocT promoted to f32; phase B double-buffered staging; k-rotation to kill
//     the 32-way LDS bank conflict on the Q.S0 loop.
//   - full buffer schedule re-derived, all phase read/write sets disjoint:
//     ws: [0,8M) hsb -> dTg | [8,16M) wqkv/wzb -> o1g | [16,24M) wqkv -> zbuf
//         [24,32M) mixed -> wlocT f32 | [32,40M) mixed -> woutb | [40,48M) q,k -> gated
//     d_out: [0,8M) vbuf -> core | [8,16M) dloc.
// Chunked delta rule (C=64): delta = (I+A)^-1(bV - b D K S0) = Dloc - W S0;
//   S_C = e^{cumC} S0 + K'^T delta;  O = D Q S0 + (Minc o QK^T) delta.

#define SEQ 2048
#define HIDDEN 2048
#define NH 16
#define DKv 64
#define DVv 128
#define KEY_DIM 1024
#define VAL_DIM 2048
#define CONV_DIM 4096

typedef __bf16 bf16;
typedef unsigned short u16;
typedef __attribute__((ext_vector_type(8))) __bf16 bf16x8;
typedef __attribute__((ext_vector_type(4))) __bf16 bf16x4;
typedef __attribute__((ext_vector_type(4))) float f32x4;

#define AS1 __attribute__((address_space(1)))
#define AS3 __attribute__((address_space(3)))
#define GLDS16(src, dst) __builtin_amdgcn_global_load_lds((AS1 const void*)(src), (AS3 void*)(dst), 16, 0, 0)

__device__ __forceinline__ float b2f(u16 u) {
  union { unsigned int i; float f; } c; c.i = ((unsigned int)u) << 16; return c.f;
}
__device__ __forceinline__ float sigmoidf_(float x) { return 1.0f / (1.0f + __expf(-x)); }

// ---------------------------------------------------------------- dtype detector
__global__ void detect_dtype(const u16* __restrict__ p, unsigned* __restrict__ flag) {
  int lane = threadIdx.x;  // 64 threads
  int cnt = 0;
  for (int w = lane; w < 2048; w += 64) {
    unsigned e = (p[2 * w] >> 7) & 0xFF;
    if (e < 64) cnt++;
  }
  cnt += __shfl_xor(cnt, 1);  cnt += __shfl_xor(cnt, 2);  cnt += __shfl_xor(cnt, 4);
  cnt += __shfl_xor(cnt, 8);  cnt += __shfl_xor(cnt, 16); cnt += __shfl_xor(cnt, 32);
  if (lane == 0) *flag = (cnt > 64) ? 1u : 0u;   // 1 = inputs are f32
}

// ---------------------------------------------------------------- f32 -> bf16 convert
__global__ __launch_bounds__(256)
void cvt_bf16(const void* __restrict__ src, bf16* __restrict__ dst, long n,
              const unsigned* __restrict__ flagp) {
  long i = ((long)blockIdx.x * 256 + threadIdx.x) * 8;
  if (i >= n) return;
  if (*flagp) {
    const f32x4* s = (const f32x4*)((const float*)src + i);
    f32x4 a = s[0], b = s[1];
    bf16x8 o;
#pragma unroll
    for (int j = 0; j < 4; ++j) { o[j] = (bf16)a[j]; o[4 + j] = (bf16)b[j]; }
    *(bf16x8*)(dst + i) = o;
  } else {
    *(bf16x8*)(dst + i) = *(const bf16x8*)((const bf16*)src + i);
  }
}

// ---------------------------------------------------------------- GEMM (NT) standalone
template<bool F32OUT>
__global__ __launch_bounds__(256, 2)
void gemm_nt(const void* __restrict__ Araw, const void* __restrict__ Braw,
             void* __restrict__ Cv, int N, int K,
             const unsigned* __restrict__ flagp, int useA, int useB) {
  __shared__ __align__(16) bf16 As[128 * 32];
  __shared__ __align__(16) bf16 Bs[128 * 32];
  const bool f32g = (*flagp != 0);
  const bool fA = useA && f32g;
  const bool fB = useB && f32g;
  const int tid  = threadIdx.x;
  const int lane = tid & 63;
  const int wv   = tid >> 6;
  const int wm   = (wv & 1) << 6;
  const int wn   = (wv >> 1) << 6;
  const long bm  = (long)blockIdx.y * 128;
  const long bn  = (long)blockIdx.x * 128;

  f32x4 acc[4][4] = {};

  for (int k0 = 0; k0 < K; k0 += 32) {
#pragma unroll
    for (int it = 0; it < 2; ++it) {
      int e   = (it * 256 + tid) * 8;
      int row = e >> 5;
      int col = e & 31;
      long offA = (bm + row) * (long)K + (k0 + col);
      long offB = (bn + row) * (long)K + (k0 + col);
      if (fA) {
        const float* g = (const float*)Araw + offA;
        f32x4 u0 = *(const f32x4*)g, u1 = *(const f32x4*)(g + 4);
        bf16x8 bv;
#pragma unroll
        for (int j = 0; j < 4; ++j) { bv[j] = (bf16)u0[j]; bv[4 + j] = (bf16)u1[j]; }
        *(bf16x8*)&As[e] = bv;
      } else {
        const bf16* g = (const bf16*)Araw + offA;
        GLDS16(g, &As[e]);
      }
      if (fB) {
        const float* g = (const float*)Braw + offB;
        f32x4 u0 = *(const f32x4*)g, u1 = *(const f32x4*)(g + 4);
        bf16x8 bv;
#pragma unroll
        for (int j = 0; j < 4; ++j) { bv[j] = (bf16)u0[j]; bv[4 + j] = (bf16)u1[j]; }
        *(bf16x8*)&Bs[e] = bv;
      } else {
        const bf16* g = (const bf16*)Braw + offB;
        GLDS16(g, &Bs[e]);
      }
    }
    __syncthreads();

    const bf16x8* As8 = (const bf16x8*)As;
    const bf16x8* Bs8 = (const bf16x8*)Bs;
    const int r = lane & 15, q = lane >> 4;
    bf16x8 af[4], bfr[4];
#pragma unroll
    for (int i = 0; i < 4; ++i) af[i]  = As8[(wm + i * 16 + r) * 4 + q];
#pragma unroll
    for (int j = 0; j < 4; ++j) bfr[j] = Bs8[(wn + j * 16 + r) * 4 + q];
#pragma unroll
    for (int i = 0; i < 4; ++i)
#pragma unroll
      for (int j = 0; j < 4; ++j)
        acc[i][j] = __builtin_amdgcn_mfma_f32_16x16x32_bf16(af[i], bfr[j], acc[i][j], 0, 0, 0);
    __syncthreads();
  }

  const int r = lane & 15, q = lane >> 4;
#pragma unroll
  for (int i = 0; i < 4; ++i)
#pragma unroll
    for (int j = 0; j < 4; ++j) {
      long row = bm + wm + i * 16 + q * 4;
      long col = bn + wn + j * 16 + r;
#pragma unroll
      for (int rr = 0; rr < 4; ++rr) {
        if constexpr (F32OUT) ((float*)Cv)[(row + rr) * N + col] = acc[i][j][rr];
        else                  ((bf16*)Cv)[(row + rr) * N + col] = (bf16)acc[i][j][rr];
      }
    }
}

// ---------------------------------------------------------------- GEMM body (bf16-only, fused)
__device__ void gemm_body_bf16(char* smemc, const bf16* __restrict__ A,
                               const bf16* __restrict__ B, bf16* __restrict__ C,
                               int N, int K, int bx, int by, int tid) {
  bf16* As = (bf16*)smemc;             // 8 KiB
  bf16* Bs = (bf16*)(smemc + 8192);    // 8 KiB
  const int lane = tid & 63;
  const int wv = tid >> 6, wm = (wv & 1) << 6, wn = (wv >> 1) << 6;
  const long bm = (long)by * 128, bn = (long)bx * 128;
  f32x4 acc[4][4] = {};
  for (int k0 = 0; k0 < K; k0 += 32) {
#pragma unroll
    for (int it = 0; it < 2; ++it) {
      int e = (it * 256 + tid) * 8;
      int row = e >> 5, col = e & 31;
      const bf16* gA = A + (bm + row) * (long)K + k0 + col;
      const bf16* gB = B + (bn + row) * (long)K + k0 + col;
      GLDS16(gA, &As[e]);
      GLDS16(gB, &Bs[e]);
    }
    __syncthreads();
    const bf16x8* As8 = (const bf16x8*)As;
    const bf16x8* Bs8 = (const bf16x8*)Bs;
    const int r = lane & 15, q = lane >> 4;
    bf16x8 af[4], bfr[4];
#pragma unroll
    for (int i = 0; i < 4; ++i) af[i]  = As8[(wm + i * 16 + r) * 4 + q];
#pragma unroll
    for (int j = 0; j < 4; ++j) bfr[j] = Bs8[(wn + j * 16 + r) * 4 + q];
#pragma unroll
    for (int i = 0; i < 4; ++i)
#pragma unroll
      for (int j = 0; j < 4; ++j)
        acc[i][j] = __builtin_amdgcn_mfma_f32_16x16x32_bf16(af[i], bfr[j], acc[i][j], 0, 0, 0);
    __syncthreads();
  }
  const int r = lane & 15, q = lane >> 4;
#pragma unroll
  for (int i = 0; i < 4; ++i)
#pragma unroll
    for (int j = 0; j < 4; ++j) {
      long row = bm + wm + i * 16 + q * 4;
      long col = bn + wn + j * 16 + r;
#pragma unroll
      for (int rr = 0; rr < 4; ++rr)
        C[(row + rr) * (long)N + col] = (bf16)acc[i][j][rr];
    }
}

// ---------------------------------------------------------------- a/b proj -> exp(g), g, beta
__global__ __launch_bounds__(256)
void proj_ab(const void* __restrict__ hsr, const void* __restrict__ War,
             const void* __restrict__ Wbr, const void* __restrict__ A_logr,
             const void* __restrict__ dtbr,
             float* __restrict__ eg, float* __restrict__ bet,
             float* __restrict__ gb,
             const unsigned* __restrict__ flagp) {
  const bool f32g = (*flagp != 0);
  const int s = blockIdx.x;
  const int t = threadIdx.x;
  const int o = t & 31;
  const int part = t >> 5;
  const int h = o & 15;
  const int kbeg = part * 256;
  float a0 = 0.f, a1 = 0.f;
  if (f32g) {
    const f32x4* x4 = (const f32x4*)((const float*)hsr + (long)s * HIDDEN + kbeg);
    const f32x4* w4 = (const f32x4*)((const float*)((o < 16) ? War : Wbr) + (long)h * HIDDEN + kbeg);
#pragma unroll 8
    for (int k4 = 0; k4 < 64; ++k4) {
      f32x4 xv = x4[k4], wv = w4[k4];
      a0 += xv[0] * wv[0] + xv[1] * wv[1];
      a1 += xv[2] * wv[2] + xv[3] * wv[3];
    }
  } else {
    const bf16x8* x8 = (const bf16x8*)((const bf16*)hsr + (long)s * HIDDEN + kbeg);
    const bf16x8* w8 = (const bf16x8*)((const bf16*)((o < 16) ? War : Wbr) + (long)h * HIDDEN + kbeg);
#pragma unroll 8
    for (int k8 = 0; k8 < 32; ++k8) {
      bf16x8 xv = x8[k8], wv = w8[k8];
#pragma unroll
      for (int j = 0; j < 4; ++j) a0 += (float)xv[j] * (float)wv[j];
#pragma unroll
      for (int j = 4; j < 8; ++j) a1 += (float)xv[j] * (float)wv[j];
    }
  }
  __shared__ float red[256];
  red[t] = a0 + a1;
  __syncthreads();
  if (t < 32) {
    float a = 0.f;
#pragma unroll
    for (int p = 0; p < 8; ++p) a += red[t + p * 32];
    const int hh = t & 15;
    if (t < 16) {
      float alog = f32g ? ((const float*)A_logr)[hh] : b2f(((const u16*)A_logr)[hh]);
      float dtb  = f32g ? ((const float*)dtbr)[hh]   : b2f(((const u16*)dtbr)[hh]);
      float xx = a + dtb;
      float sp = fmaxf(xx, 0.f) + log1pf(__expf(-fabsf(xx)));   // stable softplus
      float gg = -__expf(alog) * sp;                             // log-decay
      if (gb) gb[(long)s * NH + hh] = gg;
      eg[(long)s * NH + hh] = __expf(gg);
    } else {
      bet[(long)s * NH + hh] = sigmoidf_(a);
    }
  }
}

// ---------------------------------------------------------------- conv + SiLU + l2norm
__global__ __launch_bounds__(256)
void conv_norm(const bf16* __restrict__ mixed, const void* __restrict__ convwr,
               bf16* __restrict__ qbuf, bf16* __restrict__ kbuf, bf16* __restrict__ vbuf,
               const unsigned* __restrict__ flagp) {
  const bool f32g = (*flagp != 0);
  const int s = blockIdx.x;
  const int c = blockIdx.y * 256 + threadIdx.x;
  float w0, w1, w2, w3;
  if (f32g) {
    const float* wp = (const float*)convwr + (long)c * 4;
    w0 = wp[0]; w1 = wp[1]; w2 = wp[2]; w3 = wp[3];
  } else {
    const u16* wp = (const u16*)convwr + (long)c * 4;
    w0 = b2f(wp[0]); w1 = b2f(wp[1]); w2 = b2f(wp[2]); w3 = b2f(wp[3]);
  }
  float acc = w3 * (float)mixed[(long)s * CONV_DIM + c];
  if (s >= 1) acc += w2 * (float)mixed[(long)(s - 1) * CONV_DIM + c];
  if (s >= 2) acc += w1 * (float)mixed[(long)(s - 2) * CONV_DIM + c];
  if (s >= 3) acc += w0 * (float)mixed[(long)(s - 3) * CONV_DIM + c];
  float y = acc * sigmoidf_(acc);  // SiLU
  if (c < 2 * KEY_DIM) {
    float ss = y * y;
    ss += __shfl_xor(ss, 1);  ss += __shfl_xor(ss, 2);  ss += __shfl_xor(ss, 4);
    ss += __shfl_xor(ss, 8);  ss += __shfl_xor(ss, 16); ss += __shfl_xor(ss, 32);
    float scale = rsqrtf(ss + 1e-6f);
    if (c < KEY_DIM) scale *= 0.125f;
    y *= scale;
  }
  if (c < KEY_DIM)            qbuf[(long)s * KEY_DIM + c] = (bf16)y;
  else if (c < 2 * KEY_DIM)   kbuf[(long)s * KEY_DIM + (c - KEY_DIM)] = (bf16)y;
  else                        vbuf[(long)s * VAL_DIM + (c - 2 * KEY_DIM)] = (bf16)y;
}

// ---------------------------------------------------------------- DPP 16-lane sum (fallback scan)
template<int CTRL>
__device__ __forceinline__ float dpp_add(float x) {
  int y = __builtin_amdgcn_update_dpp(0, __float_as_int(x), CTRL, 0xF, 0xF, true);
  return x + __int_as_float(y);
}
__device__ __forceinline__ float dpp_sum16(float x) {
  x = dpp_add<0xB1>(x);   // quad_perm xor1
  x = dpp_add<0x4E>(x);   // quad_perm xor2
  x = dpp_add<0x141>(x);  // row_half_mirror (xor4)
  x = dpp_add<0x140>(x);  // row_mirror (xor8)
  return x;
}

// ---------------------------------------------------------------- fused per-step scan (FALLBACK path only)
__global__ __launch_bounds__(256, 2)
void fused_scan(const bf16* __restrict__ qbuf, const bf16* __restrict__ kbuf,
                const bf16* __restrict__ vbuf, const float* __restrict__ eg,
                const float* __restrict__ bet, bf16* __restrict__ core,
                const bf16* __restrict__ hsb, const bf16* __restrict__ wzb,
                bf16* __restrict__ zbuf, const void* __restrict__ woutr,
                bf16* __restrict__ woutb, const unsigned* __restrict__ flagp,
                int nScan, int nGemm) {
  __shared__ __align__(16) char smem[16384];
  const int t = threadIdx.x;
  const int b = blockIdx.x;

  if (b < nScan) {
    const int h  = b >> 3;
    const int vg = (b & 7) * 16;
    const int g  = t >> 4;
    const int L  = t & 15;
    bf16*  kqs = (bf16*)smem;               // [2][2048] elems
    bf16*  vts = (bf16*)(smem + 8192);      // [2][256] elems
    float* ets = (float*)(smem + 9216);     // [2][16]
    float* bts = (float*)(smem + 9344);     // [2][16]

#define STAGE(buf, s0)                                                          \
    {                                                                           \
      int byte = t * 16;                                                        \
      const bf16* src;                                                          \
      if (byte < 2048) {                                                        \
        int row = byte >> 7, el = (byte & 127) >> 1;                            \
        src = kbuf + (long)((s0) + row) * KEY_DIM + h * DKv + el;               \
      } else {                                                                  \
        int b2 = byte - 2048;                                                   \
        int row = b2 >> 7, el = (b2 & 127) >> 1;                                \
        src = qbuf + (long)((s0) + row) * KEY_DIM + h * DKv + el;               \
      }                                                                         \
      GLDS16(src, smem + (buf) * 4096 + byte);                                  \
      if (t < 32) {                                                             \
        int row = t >> 1, el = (t & 1) * 8;                                     \
        const bf16* vsrc = vbuf + (long)((s0) + row) * VAL_DIM + h * DVv + vg + el; \
        GLDS16(vsrc, smem + 8192 + (buf) * 512 + t * 16);                       \
      }                                                                         \
    }

    float er = 0.f, br = 0.f;
    if (t < 16)      er = eg[(long)t * NH + h];
    else if (t < 32) br = bet[(long)(t - 16) * NH + h];
    STAGE(0, 0);
    if (t < 16)      ets[t] = er;
    else if (t < 32) bts[t - 16] = br;
    __syncthreads();

    float S0 = 0.f, S1 = 0.f, S2 = 0.f, S3 = 0.f;
    for (int tile = 0; tile < 128; ++tile) {
      const int buf = tile & 1, nb = buf ^ 1;
      if (tile < 127) {
        STAGE(nb, (tile + 1) * 16);
        if (t < 16)      er = eg[(long)((tile + 1) * 16 + t) * NH + h];
        else if (t < 32) br = bet[(long)((tile + 1) * 16 + (t - 16)) * NH + h];
      }
      const bf16*  ktb = kqs + buf * 2048;
      const bf16*  qtb = ktb + 1024;
      const bf16*  vtb = vts + buf * 256;
      const float* etb = ets + buf * 16;
      const float* btb = bts + buf * 16;
      const long sbase = (long)tile * 16;

      bf16x4 kR[2], qR[2];
      float  vR[2], eR[2], bR[2];
      kR[0] = *(const bf16x4*)(ktb + 0 * 64 + L * 4);
      qR[0] = *(const bf16x4*)(qtb + 0 * 64 + L * 4);
      vR[0] = (float)vtb[0 * 16 + g];  eR[0] = etb[0];  bR[0] = btb[0];
      kR[1] = *(const bf16x4*)(ktb + 1 * 64 + L * 4);
      qR[1] = *(const bf16x4*)(qtb + 1 * 64 + L * 4);
      vR[1] = (float)vtb[1 * 16 + g];  eR[1] = etb[1];  bR[1] = btb[1];
#pragma unroll
      for (int s = 0; s < 16; ++s) {
        const int sl = s & 1;
        bf16x4 kk = kR[sl], qq = qR[sl];
        float vv = vR[sl], ee = eR[sl], bb = bR[sl];
        if (s < 14) {
          const int s2 = s + 2;
          kR[sl] = *(const bf16x4*)(ktb + s2 * 64 + L * 4);
          qR[sl] = *(const bf16x4*)(qtb + s2 * 64 + L * 4);
          vR[sl] = (float)vtb[s2 * 16 + g];
          eR[sl] = etb[s2];  bR[sl] = btb[s2];
        }
        float ebt = ee * bb, vbt = vv * bb;
        float k0 = (float)kk[0], k1 = (float)kk[1], k2 = (float)kk[2], k3 = (float)kk[3];
        float D0 = S0 * ee, D1 = S1 * ee, D2 = S2 * ee, D3 = S3 * ee;
        float p = (k0 * S0 + k1 * S1) + (k2 * S2 + k3 * S3);
        p = dpp_sum16(p);
        float delta = vbt - ebt * p;
        S0 = fmaf(k0, delta, D0); S1 = fmaf(k1, delta, D1);
        S2 = fmaf(k2, delta, D2); S3 = fmaf(k3, delta, D3);
        float q0 = (float)qq[0], q1 = (float)qq[1], q2 = (float)qq[2], q3 = (float)qq[3];
        float o = (q0 * S0 + q1 * S1) + (q2 * S2 + q3 * S3);
        o = dpp_sum16(o);
        if (L == 0) core[(sbase + s) * VAL_DIM + h * DVv + vg + g] = (bf16)o;
      }
      if (tile < 127) {
        if (t < 16)      ets[nb * 16 + t] = er;
        else if (t < 32) bts[nb * 16 + (t - 16)] = br;
      }
      __syncthreads();
    }
#undef STAGE
  } else if (b < nScan + nGemm) {
    int gb = b - nScan;
    gemm_body_bf16(smem, hsb, wzb, zbuf, VAL_DIM, HIDDEN, gb & 15, gb >> 4, t);
  } else {
    long i = ((long)(b - nScan - nGemm) * 256 + t) * 8;
    if (i < (long)HIDDEN * VAL_DIM) {
      if (*flagp) {
        const f32x4* s = (const f32x4*)((const float*)woutr + i);
        f32x4 a = s[0], c = s[1];
        bf16x8 o;
#pragma unroll
        for (int j = 0; j < 4; ++j) { o[j] = (bf16)a[j]; o[4 + j] = (bf16)c[j]; }
        *(bf16x8*)(woutb + i) = o;
      } else {
        *(bf16x8*)(woutb + i) = *(const bf16x8*)((const bf16*)woutr + i);
      }
    }
  }
}

// ================================================================ CHUNKED DELTA RULE
// chunk length 64, 32 chunks, 16 heads. Per chunk-head (c,h):
//   cum_t = prefix-sum of g; d_t = e^{cum_t}
//   A[t][i] = beta_t e^{cum_t-cum_i} (k_t.k_i), strictly lower
//   [Dloc | W] = (I+A)^{-1} [diag(beta)V | diag(beta*d)K]
//   delta = Dloc - W S0;  S' = e^{cumC} S0 + K'^T delta, K'[i]=e^{cumC-cum_i}k_i
//   O = diag(d) Q S0 + (Minc o Q K^T) delta,  Minc[t][i] = e^{cum_t-cum_i}, i<=t
// dloc[(c,h)][t][v] bf16 (8MB, d_out+8M); wlocT[(c,h)][k][t] f32 (8MB, ws+24M);
// dTg[(c,h)][v][t] bf16 (8MB, ws+0); o1g[(c,h)][v][t] bf16, pre-scaled by d_t (ws+8M).

// ---------------------------------------------------------------- phase A (+ fused zgemm + woutcvt)
__global__ __launch_bounds__(256, 2)
void chunk_a(const bf16* __restrict__ kbuf, const bf16* __restrict__ vbuf,
             const float* __restrict__ gbuf, const float* __restrict__ betp,
             bf16* __restrict__ dloc, float* __restrict__ wlocT,
             const bf16* __restrict__ hsb, const bf16* __restrict__ wzb,
             bf16* __restrict__ zbuf, const void* __restrict__ woutr,
             bf16* __restrict__ woutb, const unsigned* __restrict__ flagp) {
  __shared__ __align__(16) char smem[25600];
  const int t = threadIdx.x;
  const int b = blockIdx.x;
  if (b < 512) {
    const int c = b >> 4, h = b & 15;
    bf16*  Ks   = (bf16*)smem;                 // [64][64] 8192 B
    float* At   = (float*)(smem + 8192);       // [64][64] 16384 B, At[i][t] = A[t][i]
    float* cumS = (float*)(smem + 24576);      // 64
    float* bS   = (float*)(smem + 24832);      // 64
    float* dS   = (float*)(smem + 25088);      // 64
    // stage K chunk -> LDS (linear)
#pragma unroll
    for (int it = 0; it < 2; ++it) {
      int byte = (it * 256 + t) * 16;
      int row = byte >> 7, col = (byte & 127) >> 1;
      const bf16* src = kbuf + (long)(c * 64 + row) * KEY_DIM + h * DKv + col;
      GLDS16(src, smem + byte);
    }
    if (t < 64) {  // wave 0: within-chunk prefix sum of log-decay
      float cc = gbuf[(long)(c * 64 + t) * NH + h];
#pragma unroll
      for (int d = 1; d < 64; d <<= 1) { float y = __shfl_up(cc, d); if (t >= d) cc += y; }
      cumS[t] = cc;
      dS[t] = __expf(cc);
      bS[t] = betp[(long)(c * 64 + t) * NH + h];
    }
    {  // zero At (upper+diag must read as 0 in the quad-vectorized substitution)
      f32x4 z = {0.f, 0.f, 0.f, 0.f};
#pragma unroll
      for (int i = 0; i < 4; ++i) ((f32x4*)At)[t * 4 + i] = z;
    }
    __syncthreads();
    // G = K K^T via MFMA; masked+scaled, stored transposed into At
    {
      const int lane = t & 63, wv = t >> 6;
      const int r = lane & 15, q = lane >> 4;
      const bf16x8* Ks8 = (const bf16x8*)Ks;
#pragma unroll
      for (int n = 0; n < 4; ++n) {
        f32x4 acc = {0.f, 0.f, 0.f, 0.f};
#pragma unroll
        for (int kk = 0; kk < 2; ++kk) {
          bf16x8 af  = Ks8[(wv * 16 + r) * 8 + kk * 4 + q];
          bf16x8 bfv = Ks8[(n  * 16 + r) * 8 + kk * 4 + q];
          acc = __builtin_amdgcn_mfma_f32_16x16x32_bf16(af, bfv, acc, 0, 0, 0);
        }
        const int i = n * 16 + r;
#pragma unroll
        for (int rr = 0; rr < 4; ++rr) {
          const int tr = wv * 16 + q * 4 + rr;
          if (i < tr)
            At[i * 64 + tr] = bS[tr] * __expf(cumS[tr] - cumS[i]) * acc[rr];
        }
      }
    }
    __syncthreads();
    // column-parallel forward substitution: x = (I+A)^{-1} r, one column per thread
    if (t < 192) {
      float x[64];
      const long base = ((long)(c * 16 + h)) * 64;
      if (t < 128) {
#pragma unroll
        for (int s = 0; s < 64; ++s)
          x[s] = bS[s] * (float)vbuf[(long)(c * 64 + s) * VAL_DIM + h * DVv + t];
      } else {
        const int k = t - 128;
#pragma unroll
        for (int s = 0; s < 64; ++s)
          x[s] = bS[s] * dS[s] * (float)Ks[s * 64 + k];
      }
#pragma unroll
      for (int s = 0; s < 64; ++s) {
        const float val = x[s];
        const f32x4* row4 = (const f32x4*)(At + s * 64);
#pragma unroll
        for (int qd = (s >> 2); qd < 16; ++qd) {
          f32x4 a4 = row4[qd];
          x[qd * 4 + 0] = fmaf(-a4[0], val, x[qd * 4 + 0]);
          x[qd * 4 + 1] = fmaf(-a4[1], val, x[qd * 4 + 1]);
          x[qd * 4 + 2] = fmaf(-a4[2], val, x[qd * 4 + 2]);
          x[qd * 4 + 3] = fmaf(-a4[3], val, x[qd * 4 + 3]);
        }
      }
      if (t < 128) {          // Dloc column t  -> dloc[t][v] rows
#pragma unroll
        for (int s = 0; s < 64; ++s)
          dloc[(base + s) * 128 + t] = (bf16)x[s];
      } else {                // W column k -> wlocT[k][t] contiguous, f32
        const int k = t - 128;
        float* wp = wlocT + base * 64 + k * 64;
#pragma unroll
        for (int s4 = 0; s4 < 16; ++s4) {
          f32x4 o = { x[s4 * 4 + 0], x[s4 * 4 + 1], x[s4 * 4 + 2], x[s4 * 4 + 3] };
          *(f32x4*)(wp + s4 * 4) = o;
        }
      }
    }
  } else if (b < 768) {
    int gb = b - 512;
    gemm_body_bf16(smem, hsb, wzb, zbuf, VAL_DIM, HIDDEN, gb & 15, gb >> 4, t);
  } else {
    long i = ((long)(b - 768) * 256 + t) * 8;
    if (i < (long)HIDDEN * VAL_DIM) {
      if (*flagp) {
        const f32x4* s = (const f32x4*)((const float*)woutr + i);
        f32x4 a = s[0], cc = s[1];
        bf16x8 o;
#pragma unroll
        for (int j = 0; j < 4; ++j) { o[j] = (bf16)a[j]; o[4 + j] = (bf16)cc[j]; }
        *(bf16x8*)(woutb + i) = o;
      } else {
        *(bf16x8*)(woutb + i) = *(const bf16x8*)((const bf16*)woutr + i);
      }
    }
  }
}

// ---------------------------------------------------------------- phase B: chunk-serial state recurrence
// grid 256 = h*16 + vb (vb -> 8 v-columns). State S kept f32 in LDS [v][k].
// Emits delta^T bf16 [(c,h)][v][t] and o1 = d_t*(Q S0) bf16 [(c,h)][v][t].
__global__ __launch_bounds__(256, 1)
void chunk_b(const bf16* __restrict__ kbuf, const bf16* __restrict__ qbuf,
             const float* __restrict__ gbuf, const bf16* __restrict__ dloc,
             const float* __restrict__ wlocT,
             bf16* __restrict__ dTg, bf16* __restrict__ o1g) {
  // LDS: g[2048]f32 @0 | W[2][64][64]f32 @8192 | K[2][64][64]bf16 @40960
  //      Q[2][64][64]bf16 @57344 | Dl[2][64][8]bf16 @73728 | St[8][64]f32 @75776
  //      Dp[8][64]f32 @77824 | fSb[2][64] @79872 | dSb[2][64] @80384
  __shared__ __align__(16) char smem[80896];
  float* g_lds = (float*)smem;
  float* St  = (float*)(smem + 75776);
  float* Dp  = (float*)(smem + 77824);
  float* fSb = (float*)(smem + 79872);
  float* dSb = (float*)(smem + 80384);
  const int t = threadIdx.x;
  const int h = blockIdx.x >> 4, vb = blockIdx.x & 15;
  const int tt = t & 63, vh = t >> 6;
  const int v0 = vh * 2, v1 = v0 + 1;

#pragma unroll
  for (int i = 0; i < 8; ++i)
    g_lds[i * 256 + t] = gbuf[(long)(i * 256 + t) * NH + h];
  if (t < 128) { f32x4 z = {0.f, 0.f, 0.f, 0.f}; ((f32x4*)St)[t] = z; }

  auto stage_b = [&](int bb, int cc) {
    const long ch_ = (long)(cc * 16 + h);
#pragma unroll
    for (int it = 0; it < 4; ++it) {   // W f32, 16 KiB
      int byte = (it * 256 + t) * 16;
      GLDS16((const char*)wlocT + ch_ * 16384 + byte, smem + 8192 + bb * 16384 + byte);
    }
#pragma unroll
    for (int it = 0; it < 2; ++it) {   // K, Q bf16, 8 KiB each
      int byte = (it * 256 + t) * 16;
      int row = byte >> 7, col = (byte & 127) >> 1;
      GLDS16(kbuf + (long)(cc * 64 + row) * KEY_DIM + h * DKv + col, smem + 40960 + bb * 8192 + byte);
      GLDS16(qbuf + (long)(cc * 64 + row) * KEY_DIM + h * DKv + col, smem + 57344 + bb * 8192 + byte);
    }
    if (t < 64)
      GLDS16(dloc + ((ch_ * 64 + t) * 128 + vb * 8), smem + 73728 + bb * 1024 + t * 16);
  };
  auto prefix_b = [&](int bb, int cc) {
    if (t < 64) {
      float cs = g_lds[cc * 64 + t];
#pragma unroll
      for (int d = 1; d < 64; d <<= 1) { float y = __shfl_up(cs, d); if (t >= d) cs += y; }
      float tot = __shfl(cs, 63);
      fSb[bb * 64 + t] = __expf(tot - cs);   // e^{cumC - cum_t}
      dSb[bb * 64 + t] = __expf(cs);         // d_t = e^{cum_t}
    }
  };

  stage_b(0, 0);
  prefix_b(0, 0);

  for (int c = 0; c < 32; ++c) {
    const int buf = c & 1, nb = buf ^ 1;
    __syncthreads();   // (1) chunk-c stage drained; prev mm3 St visible
    if (c < 31) { stage_b(nb, c + 1); prefix_b(nb, c + 1); }  // prefetch (drained at (2))
    const float* Wr = (const float*)(smem + 8192 + buf * 16384);
    const bf16*  Kr = (const bf16*)(smem + 40960 + buf * 8192);
    const bf16*  Qr = (const bf16*)(smem + 57344 + buf * 8192);
    const bf16*  Dl = (const bf16*)(smem + 73728 + buf * 1024);
    const float* fS = fSb + buf * 64;
    const float* dS = dSb + buf * 64;
    const long gb_ = (long)(c * 16 + h) * 8192 + (long)(vb * 8) * 64;
    // mm2: delta^T[v][tt] = Dl[tt][v] - sum_k W[tt][k] St[v][k]
    {
      float a0 = (float)Dl[tt * 8 + v0];
      float a1 = (float)Dl[tt * 8 + v1];
#pragma unroll 4
      for (int k = 0; k < 64; ++k) {
        float w = Wr[k * 64 + tt];
        a0 = fmaf(-w, St[v0 * 64 + k], a0);
        a1 = fmaf(-w, St[v1 * 64 + k], a1);
      }
      Dp[v0 * 64 + tt] = a0;
      Dp[v1 * 64 + tt] = a1;
      dTg[gb_ + v0 * 64 + tt] = (bf16)a0;
      dTg[gb_ + v1 * 64 + tt] = (bf16)a1;
    }
    // mmO1: o1[v][tt] = d_tt * sum_k Q[tt][k] St[v][k]  (k rotated per-lane: bank-free)
    {
      float o0 = 0.f, o1v = 0.f;
#pragma unroll 4
      for (int k = 0; k < 64; ++k) {
        int kp = (k + tt) & 63;
        float qv = (float)Qr[tt * 64 + kp];
        o0  = fmaf(qv, St[v0 * 64 + kp], o0);
        o1v = fmaf(qv, St[v1 * 64 + kp], o1v);
      }
      float dt = dS[tt];
      o1g[gb_ + v0 * 64 + tt] = (bf16)(dt * o0);
      o1g[gb_ + v1 * 64 + tt] = (bf16)(dt * o1v);
    }
    __syncthreads();   // (2) Dp ready; St reads of this chunk complete
    // mm3: St'[v][tt] = dC*St[v][tt] + sum_i fS_i K[i][tt] Dp[v][i]
    {
      const float dC = dS[63];
      float s0 = dC * St[v0 * 64 + tt];
      float s1 = dC * St[v1 * 64 + tt];
#pragma unroll 4
      for (int i = 0; i < 64; ++i) {
        float kv = fS[i] * (float)Kr[i * 64 + tt];
        s0 = fmaf(kv, Dp[v0 * 64 + i], s0);
        s1 = fmaf(kv, Dp[v1 * 64 + i], s1);
      }
      St[v0 * 64 + tt] = s0;
      St[v1 * 64 + tt] = s1;
    }
  }
}

// ---------------------------------------------------------------- phase C: outputs, MFMA
// grid 512 = c*16 + h.  O[t][v] = o1[v][t] + sum_i P[t][i] delta^T[v][i]
__global__ __launch_bounds__(256, 2)
void chunk_c(const bf16* __restrict__ qbuf, const bf16* __restrict__ kbuf,
             const float* __restrict__ gbuf, const bf16* __restrict__ dTg,
             const bf16* __restrict__ o1g, bf16* __restrict__ core) {
  // Qs@0 8K | Ks@8192 8K | Pl@16384 8K | dT@24576 16K | o1l@40960 16K | cum@57344
  __shared__ __align__(16) char smem[57600];
  const int t = threadIdx.x;
  const int c = blockIdx.x >> 4, h = blockIdx.x & 15;
  const long c16h = (long)(c * 16 + h);
  bf16* Qs  = (bf16*)smem;
  bf16* Ksl = (bf16*)(smem + 8192);
  bf16* Pl  = (bf16*)(smem + 16384);
  const bf16* dT  = (const bf16*)(smem + 24576);
  const bf16* o1l = (const bf16*)(smem + 40960);
  float* cumS = (float*)(smem + 57344);

#pragma unroll
  for (int it = 0; it < 2; ++it) {
    int byte = (it * 256 + t) * 16;
    int row = byte >> 7, col = (byte & 127) >> 1;
    GLDS16(qbuf + (long)(c * 64 + row) * KEY_DIM + h * DKv + col, smem + byte);
    GLDS16(kbuf + (long)(c * 64 + row) * KEY_DIM + h * DKv + col, smem + 8192 + byte);
  }
#pragma unroll
  for (int it = 0; it < 4; ++it) {
    int byte = (it * 256 + t) * 16;
    GLDS16(dTg + c16h * 8192 + (byte >> 1), smem + 24576 + byte);
    GLDS16(o1g + c16h * 8192 + (byte >> 1), smem + 40960 + byte);
  }
  if (t < 64) {
    float cc = gbuf[(long)(c * 64 + t) * NH + h];
#pragma unroll
    for (int d = 1; d < 64; d <<= 1) { float y = __shfl_up(cc, d); if (t >= d) cc += y; }
    cumS[t] = cc;
  }
  __syncthreads();

  const int lane = t & 63, wv = t >> 6;
  const int r = lane & 15, q = lane >> 4;
  const bf16x8* Qs8 = (const bf16x8*)Qs;
  const bf16x8* Ks8 = (const bf16x8*)Ksl;

  // c1: P[t][i] = (i<=t) ? e^{cum_t-cum_i} (q_t.k_i) : 0
#pragma unroll
  for (int n = 0; n < 4; ++n) {
    f32x4 acc = {0.f, 0.f, 0.f, 0.f};
#pragma unroll
    for (int kk = 0; kk < 2; ++kk)
      acc = __builtin_amdgcn_mfma_f32_16x16x32_bf16(
          Qs8[(wv * 16 + r) * 8 + kk * 4 + q], Ks8[(n * 16 + r) * 8 + kk * 4 + q], acc, 0, 0, 0);
    const int i = n * 16 + r;
#pragma unroll
    for (int rr = 0; rr < 4; ++rr) {
      const int tr = wv * 16 + q * 4 + rr;
      Pl[tr * 64 + i] = (i <= tr) ? (bf16)(__expf(cumS[tr] - cumS[i]) * acc[rr]) : (bf16)0.0f;
    }
  }
  __syncthreads();

  // c2: O = o1 (acc init) + P.deltaT via MFMA
  {
    const bf16x8* Pl8 = (const bf16x8*)Pl;
    const bf16x8* dT8 = (const bf16x8*)dT;
    bf16x8 pf[2];
#pragma unroll
    for (int kk = 0; kk < 2; ++kk) pf[kk] = Pl8[(wv * 16 + r) * 8 + kk * 4 + q];
#pragma unroll
    for (int n = 0; n < 8; ++n) {
      const int v = n * 16 + r;
      f32x4 acc;
#pragma unroll
      for (int rr = 0; rr < 4; ++rr)
        acc[rr] = (float)o1l[v * 64 + (wv * 16 + q * 4 + rr)];
#pragma unroll
      for (int kk = 0; kk < 2; ++kk)
        acc = __builtin_amdgcn_mfma_f32_16x16x32_bf16(
            pf[kk], dT8[(n * 16 + r) * 8 + kk * 4 + q], acc, 0, 0, 0);
#pragma unroll
      for (int rr = 0; rr < 4; ++rr) {
        const int tr = wv * 16 + q * 4 + rr;
        core[(long)(c * 64 + tr) * VAL_DIM + h * DVv + v] = (bf16)acc[rr];
      }
    }
  }
}

// ---------------------------------------------------------------- RMSNorm + SiLU(z) gate
__global__ __launch_bounds__(256)
void gate_norm(const bf16* __restrict__ core, const bf16* __restrict__ zb,
               const void* __restrict__ normwr, bf16* __restrict__ gated,
               const unsigned* __restrict__ flagp) {
  const bool f32g = (*flagp != 0);
  const int s  = blockIdx.x;
  const int t  = threadIdx.x;
  const int h  = t >> 4;
  const int li = t & 15;
  const long base = (long)s * VAL_DIM + h * DVv + li * 8;
  bf16x8 c8 = *(const bf16x8*)(core + base);
  bf16x8 z8 = *(const bf16x8*)(zb + base);
  float x[8], z[8], nw[8];
  float ss = 0.f;
#pragma unroll
  for (int j = 0; j < 8; ++j) { x[j] = (float)c8[j]; z[j] = (float)z8[j]; ss += x[j] * x[j]; }
  if (f32g) {
    const float* np_ = (const float*)normwr + li * 8;
#pragma unroll
    for (int j = 0; j < 8; ++j) nw[j] = np_[j];
  } else {
    const u16* np_ = (const u16*)normwr + li * 8;
#pragma unroll
    for (int j = 0; j < 8; ++j) nw[j] = b2f(np_[j]);
  }
  ss += __shfl_xor(ss, 1); ss += __shfl_xor(ss, 2);
  ss += __shfl_xor(ss, 4); ss += __shfl_xor(ss, 8);
  float scale = rsqrtf(ss * (1.f / 128.f) + 1e-6f);
#pragma unroll
  for (int j = 0; j < 8; ++j) {
    float y = x[j] * scale * nw[j];
    y *= z[j] * sigmoidf_(z[j]);
    gated[base + j] = (bf16)y;
  }
}

// ---------------------------------------------------------------- launcher
extern "C" void kernel_launch(void* const* d_in, const int* in_sizes, int n_in,
                              void* d_out, int out_size, void* d_ws, size_t ws_size,
                              hipStream_t stream) {
  char* ws = (char*)d_ws;
  const bool big = ws_size >= ((48u << 20) + (512u << 10));

  if (big) {
    // ws: [0,8M) hsb -> dTg | [8,16M) wqkvb/wzb -> o1g | [16,24M) wqkvb -> zbuf
    //     [24,32M) mixed -> wlocT f32 | [32,40M) mixed -> woutb | [40,44M) qbuf
    //     [44,48M) kbuf -> (with qbuf) gated | [48M..) eg|beta|g|flag
    // d_out: [0,8M) vbuf -> core | [8,16M) dloc; final gemm overwrites all 16M f32.
    bf16*  hsb   = (bf16*)ws;
    bf16*  wqkvb = (bf16*)(ws + (8u << 20));
    bf16*  wzb   = (bf16*)(ws + (8u << 20));
    bf16*  zbuf  = (bf16*)(ws + (16u << 20));
    bf16*  mixed = (bf16*)(ws + (24u << 20));
    float* wlocT = (float*)(ws + (24u << 20));
    bf16*  woutb = (bf16*)(ws + (32u << 20));
    bf16*  qbuf  = (bf16*)(ws + (40u << 20));
    bf16*  kbuf  = (bf16*)(ws + (44u << 20));
    bf16*  gated = (bf16*)(ws + (40u << 20));
    bf16*  dTg   = (bf16*)ws;
    bf16*  o1g   = (bf16*)(ws + (8u << 20));
    float* egp  = (float*)(ws + (48u << 20));
    float* betp = (float*)(ws + (48u << 20) + (128u << 10));
    float* gbp  = (float*)(ws + (48u << 20) + (256u << 10));
    unsigned* flagp = (unsigned*)(ws + (48u << 20) + (384u << 10));
    bf16* vbuf  = (bf16*)d_out;
    bf16* dlocp = (bf16*)((char*)d_out + (8u << 20));
    bf16* corep = (bf16*)d_out;

    detect_dtype<<<1, 64, 0, stream>>>((const u16*)d_in[0], flagp);
    proj_ab<<<SEQ, 256, 0, stream>>>(d_in[0], d_in[2], d_in[3], d_in[6], d_in[7], egp, betp, gbp, flagp);
    cvt_bf16<<<(SEQ * HIDDEN) / 2048, 256, 0, stream>>>(d_in[0], hsb, (long)SEQ * HIDDEN, flagp);
    cvt_bf16<<<(CONV_DIM * HIDDEN) / 2048, 256, 0, stream>>>(d_in[1], wqkvb, (long)CONV_DIM * HIDDEN, flagp);
    gemm_nt<false><<<dim3(CONV_DIM / 128, SEQ / 128), 256, 0, stream>>>(hsb, wqkvb, mixed, CONV_DIM, HIDDEN, flagp, 0, 0);
    cvt_bf16<<<(VAL_DIM * HIDDEN) / 2048, 256, 0, stream>>>(d_in[4], wzb, (long)VAL_DIM * HIDDEN, flagp);
    conv_norm<<<dim3(SEQ, CONV_DIM / 256), 256, 0, stream>>>(mixed, d_in[5], qbuf, kbuf, vbuf, flagp);
    chunk_a<<<512 + 256 + 2048, 256, 0, stream>>>(kbuf, vbuf, gbp, betp, dlocp, wlocT,
                                                  hsb, wzb, zbuf, d_in[9], woutb, flagp);
    chunk_b<<<256, 256, 0, stream>>>(kbuf, qbuf, gbp, dlocp, wlocT, dTg, o1g);
    chunk_c<<<512, 256, 0, stream>>>(qbuf, kbuf, gbp, dTg, o1g, corep);
    gate_norm<<<SEQ, 256, 0, stream>>>(corep, zbuf, d_in[8], gated, flagp);
    gemm_nt<true><<<dim3(HIDDEN / 128, SEQ / 128), 256, 0, stream>>>(gated, woutb, d_out, HIDDEN, VAL_DIM, flagp, 0, 0);
  } else {
    // Fallback layout (peak 24.26 MiB): r6-style staging GEMMs; per-step scan.
    bf16* mixed = (bf16*)ws;
    bf16* qbuf  = (bf16*)(ws + (16u << 20));
    bf16* kbuf  = (bf16*)(ws + (20u << 20));
    bf16* zbuf  = (bf16*)ws;
    bf16* corep = (bf16*)(ws + (8u << 20));
    bf16* gated = (bf16*)(ws + (16u << 20));
    float* egp  = (float*)(ws + (24u << 20));
    float* betp = (float*)(ws + (24u << 20) + (128u << 10));
    unsigned* flagp = (unsigned*)(ws + (24u << 20) + (256u << 10));
    bf16* vbuf  = (bf16*)d_out;

    detect_dtype<<<1, 64, 0, stream>>>((const u16*)d_in[0], flagp);
    proj_ab<<<SEQ, 256, 0, stream>>>(d_in[0], d_in[2], d_in[3], d_in[6], d_in[7], egp, betp, nullptr, flagp);
    gemm_nt<false><<<dim3(CONV_DIM / 128, SEQ / 128), 256, 0, stream>>>(d_in[0], d_in[1], mixed, CONV_DIM, HIDDEN, flagp, 1, 1);
    conv_norm<<<dim3(SEQ, CONV_DIM / 256), 256, 0, stream>>>(mixed, d_in[5], qbuf, kbuf, vbuf, flagp);
    gemm_nt<false><<<dim3(VAL_DIM / 128, SEQ / 128), 256, 0, stream>>>(d_in[0], d_in[4], zbuf, VAL_DIM, HIDDEN, flagp, 1, 1);
    fused_scan<<<128, 256, 0, stream>>>(qbuf, kbuf, vbuf, egp, betp, corep,
                                        nullptr, nullptr, nullptr, nullptr, nullptr, flagp,
                                        128, 0);
    gate_norm<<<SEQ, 256, 0, stream>>>(corep, zbuf, d_in[8], gated, flagp);
    gemm_nt<true><<<dim3(HIDDEN / 128, SEQ / 128), 256, 0, stream>>>(gated, d_in[9], d_out, HIDDEN, VAL_DIM, flagp, 0, 1);
  }
}

// Round 3
// 531.716 us; speedup vs baseline: 1.2609x; 1.1947x over previous
//
#include <hip/hip_runtime.h>
#include <stdint.h>

// LinearAttention (gated delta rule), S=2048, HID=2048, H=16, DK=64, DV=128, conv K=4.
// r13: MFMA-ize chunk_b. r12's chunk_b (195us) was LDS-pipe-bound: ~2300 wave ds_reads
// per chunk per CU (every FMA operand from LDS) = 13.4k cyc ~ measured 14.6k cyc/chunk.
// New chunk_b: 32 blocks (h x vhalf), state in persistent f32 accregs; bf16 hi/lo state
// copies in LDS as MFMA B-operands (~f32 precision); phase A emits -W as bf16 hi/lo
// [t][k] (C-init from Dl -> pure mfma-accumulate); fS folded into hi/lo deltaT so the
// state update matches r12's f32 product. X8 group-XOR swizzle on all LDS tiles
// (pre-swizzled global src for staged, swizzled stores for register-produced).
// Two barriers/chunk; prefetch issued after B2 (no barrier drains fresh DMA).

#define SEQ 2048
#define HIDDEN 2048
#define NH 16
#define DKv 64
#define DVv 128
#define KEY_DIM 1024
#define VAL_DIM 2048
#define CONV_DIM 4096

typedef __bf16 bf16;
typedef unsigned short u16;
typedef __attribute__((ext_vector_type(8))) __bf16 bf16x8;
typedef __attribute__((ext_vector_type(4))) __bf16 bf16x4;
typedef __attribute__((ext_vector_type(4))) float f32x4;

#define AS1 __attribute__((address_space(1)))
#define AS3 __attribute__((address_space(3)))
#define GLDS16(src, dst) __builtin_amdgcn_global_load_lds((AS1 const void*)(src), (AS3 void*)(dst), 16, 0, 0)

__device__ __forceinline__ float b2f(u16 u) {
  union { unsigned int i; float f; } c; c.i = ((unsigned int)u) << 16; return c.f;
}
__device__ __forceinline__ float sigmoidf_(float x) { return 1.0f / (1.0f + __expf(-x)); }

// ---------------------------------------------------------------- dtype detector
__global__ void detect_dtype(const u16* __restrict__ p, unsigned* __restrict__ flag) {
  int lane = threadIdx.x;  // 64 threads
  int cnt = 0;
  for (int w = lane; w < 2048; w += 64) {
    unsigned e = (p[2 * w] >> 7) & 0xFF;
    if (e < 64) cnt++;
  }
  cnt += __shfl_xor(cnt, 1);  cnt += __shfl_xor(cnt, 2);  cnt += __shfl_xor(cnt, 4);
  cnt += __shfl_xor(cnt, 8);  cnt += __shfl_xor(cnt, 16); cnt += __shfl_xor(cnt, 32);
  if (lane == 0) *flag = (cnt > 64) ? 1u : 0u;   // 1 = inputs are f32
}

// ---------------------------------------------------------------- f32 -> bf16 convert
__global__ __launch_bounds__(256)
void cvt_bf16(const void* __restrict__ src, bf16* __restrict__ dst, long n,
              const unsigned* __restrict__ flagp) {
  long i = ((long)blockIdx.x * 256 + threadIdx.x) * 8;
  if (i >= n) return;
  if (*flagp) {
    const f32x4* s = (const f32x4*)((const float*)src + i);
    f32x4 a = s[0], b = s[1];
    bf16x8 o;
#pragma unroll
    for (int j = 0; j < 4; ++j) { o[j] = (bf16)a[j]; o[4 + j] = (bf16)b[j]; }
    *(bf16x8*)(dst + i) = o;
  } else {
    *(bf16x8*)(dst + i) = *(const bf16x8*)((const bf16*)src + i);
  }
}

// ---------------------------------------------------------------- GEMM (NT) standalone
template<bool F32OUT>
__global__ __launch_bounds__(256, 2)
void gemm_nt(const void* __restrict__ Araw, const void* __restrict__ Braw,
             void* __restrict__ Cv, int N, int K,
             const unsigned* __restrict__ flagp, int useA, int useB) {
  __shared__ __align__(16) bf16 As[128 * 32];
  __shared__ __align__(16) bf16 Bs[128 * 32];
  const bool f32g = (*flagp != 0);
  const bool fA = useA && f32g;
  const bool fB = useB && f32g;
  const int tid  = threadIdx.x;
  const int lane = tid & 63;
  const int wv   = tid >> 6;
  const int wm   = (wv & 1) << 6;
  const int wn   = (wv >> 1) << 6;
  const long bm  = (long)blockIdx.y * 128;
  const long bn  = (long)blockIdx.x * 128;

  f32x4 acc[4][4] = {};

  for (int k0 = 0; k0 < K; k0 += 32) {
#pragma unroll
    for (int it = 0; it < 2; ++it) {
      int e   = (it * 256 + tid) * 8;
      int row = e >> 5;
      int col = e & 31;
      long offA = (bm + row) * (long)K + (k0 + col);
      long offB = (bn + row) * (long)K + (k0 + col);
      if (fA) {
        const float* g = (const float*)Araw + offA;
        f32x4 u0 = *(const f32x4*)g, u1 = *(const f32x4*)(g + 4);
        bf16x8 bv;
#pragma unroll
        for (int j = 0; j < 4; ++j) { bv[j] = (bf16)u0[j]; bv[4 + j] = (bf16)u1[j]; }
        *(bf16x8*)&As[e] = bv;
      } else {
        const bf16* g = (const bf16*)Araw + offA;
        GLDS16(g, &As[e]);
      }
      if (fB) {
        const float* g = (const float*)Braw + offB;
        f32x4 u0 = *(const f32x4*)g, u1 = *(const f32x4*)(g + 4);
        bf16x8 bv;
#pragma unroll
        for (int j = 0; j < 4; ++j) { bv[j] = (bf16)u0[j]; bv[4 + j] = (bf16)u1[j]; }
        *(bf16x8*)&Bs[e] = bv;
      } else {
        const bf16* g = (const bf16*)Braw + offB;
        GLDS16(g, &Bs[e]);
      }
    }
    __syncthreads();

    const bf16x8* As8 = (const bf16x8*)As;
    const bf16x8* Bs8 = (const bf16x8*)Bs;
    const int r = lane & 15, q = lane >> 4;
    bf16x8 af[4], bfr[4];
#pragma unroll
    for (int i = 0; i < 4; ++i) af[i]  = As8[(wm + i * 16 + r) * 4 + q];
#pragma unroll
    for (int j = 0; j < 4; ++j) bfr[j] = Bs8[(wn + j * 16 + r) * 4 + q];
#pragma unroll
    for (int i = 0; i < 4; ++i)
#pragma unroll
      for (int j = 0; j < 4; ++j)
        acc[i][j] = __builtin_amdgcn_mfma_f32_16x16x32_bf16(af[i], bfr[j], acc[i][j], 0, 0, 0);
    __syncthreads();
  }

  const int r = lane & 15, q = lane >> 4;
#pragma unroll
  for (int i = 0; i < 4; ++i)
#pragma unroll
    for (int j = 0; j < 4; ++j) {
      long row = bm + wm + i * 16 + q * 4;
      long col = bn + wn + j * 16 + r;
#pragma unroll
      for (int rr = 0; rr < 4; ++rr) {
        if constexpr (F32OUT) ((float*)Cv)[(row + rr) * N + col] = acc[i][j][rr];
        else                  ((bf16*)Cv)[(row + rr) * N + col] = (bf16)acc[i][j][rr];
      }
    }
}

// ---------------------------------------------------------------- GEMM body (bf16-only, fused)
__device__ void gemm_body_bf16(char* smemc, const bf16* __restrict__ A,
                               const bf16* __restrict__ B, bf16* __restrict__ C,
                               int N, int K, int bx, int by, int tid) {
  bf16* As = (bf16*)smemc;             // 8 KiB
  bf16* Bs = (bf16*)(smemc + 8192);    // 8 KiB
  const int lane = tid & 63;
  const int wv = tid >> 6, wm = (wv & 1) << 6, wn = (wv >> 1) << 6;
  const long bm = (long)by * 128, bn = (long)bx * 128;
  f32x4 acc[4][4] = {};
  for (int k0 = 0; k0 < K; k0 += 32) {
#pragma unroll
    for (int it = 0; it < 2; ++it) {
      int e = (it * 256 + tid) * 8;
      int row = e >> 5, col = e & 31;
      const bf16* gA = A + (bm + row) * (long)K + k0 + col;
      const bf16* gB = B + (bn + row) * (long)K + k0 + col;
      GLDS16(gA, &As[e]);
      GLDS16(gB, &Bs[e]);
    }
    __syncthreads();
    const bf16x8* As8 = (const bf16x8*)As;
    const bf16x8* Bs8 = (const bf16x8*)Bs;
    const int r = lane & 15, q = lane >> 4;
    bf16x8 af[4], bfr[4];
#pragma unroll
    for (int i = 0; i < 4; ++i) af[i]  = As8[(wm + i * 16 + r) * 4 + q];
#pragma unroll
    for (int j = 0; j < 4; ++j) bfr[j] = Bs8[(wn + j * 16 + r) * 4 + q];
#pragma unroll
    for (int i = 0; i < 4; ++i)
#pragma unroll
      for (int j = 0; j < 4; ++j)
        acc[i][j] = __builtin_amdgcn_mfma_f32_16x16x32_bf16(af[i], bfr[j], acc[i][j], 0, 0, 0);
    __syncthreads();
  }
  const int r = lane & 15, q = lane >> 4;
#pragma unroll
  for (int i = 0; i < 4; ++i)
#pragma unroll
    for (int j = 0; j < 4; ++j) {
      long row = bm + wm + i * 16 + q * 4;
      long col = bn + wn + j * 16 + r;
#pragma unroll
      for (int rr = 0; rr < 4; ++rr)
        C[(row + rr) * (long)N + col] = (bf16)acc[i][j][rr];
    }
}

// ---------------------------------------------------------------- a/b proj -> exp(g), g, beta
__global__ __launch_bounds__(256)
void proj_ab(const void* __restrict__ hsr, const void* __restrict__ War,
             const void* __restrict__ Wbr, const void* __restrict__ A_logr,
             const void* __restrict__ dtbr,
             float* __restrict__ eg, float* __restrict__ bet,
             float* __restrict__ gb,
             const unsigned* __restrict__ flagp) {
  const bool f32g = (*flagp != 0);
  const int s = blockIdx.x;
  const int t = threadIdx.x;
  const int o = t & 31;
  const int part = t >> 5;
  const int h = o & 15;
  const int kbeg = part * 256;
  float a0 = 0.f, a1 = 0.f;
  if (f32g) {
    const f32x4* x4 = (const f32x4*)((const float*)hsr + (long)s * HIDDEN + kbeg);
    const f32x4* w4 = (const f32x4*)((const float*)((o < 16) ? War : Wbr) + (long)h * HIDDEN + kbeg);
#pragma unroll 8
    for (int k4 = 0; k4 < 64; ++k4) {
      f32x4 xv = x4[k4], wv = w4[k4];
      a0 += xv[0] * wv[0] + xv[1] * wv[1];
      a1 += xv[2] * wv[2] + xv[3] * wv[3];
    }
  } else {
    const bf16x8* x8 = (const bf16x8*)((const bf16*)hsr + (long)s * HIDDEN + kbeg);
    const bf16x8* w8 = (const bf16x8*)((const bf16*)((o < 16) ? War : Wbr) + (long)h * HIDDEN + kbeg);
#pragma unroll 8
    for (int k8 = 0; k8 < 32; ++k8) {
      bf16x8 xv = x8[k8], wv = w8[k8];
#pragma unroll
      for (int j = 0; j < 4; ++j) a0 += (float)xv[j] * (float)wv[j];
#pragma unroll
      for (int j = 4; j < 8; ++j) a1 += (float)xv[j] * (float)wv[j];
    }
  }
  __shared__ float red[256];
  red[t] = a0 + a1;
  __syncthreads();
  if (t < 32) {
    float a = 0.f;
#pragma unroll
    for (int p = 0; p < 8; ++p) a += red[t + p * 32];
    const int hh = t & 15;
    if (t < 16) {
      float alog = f32g ? ((const float*)A_logr)[hh] : b2f(((const u16*)A_logr)[hh]);
      float dtb  = f32g ? ((const float*)dtbr)[hh]   : b2f(((const u16*)dtbr)[hh]);
      float xx = a + dtb;
      float sp = fmaxf(xx, 0.f) + log1pf(__expf(-fabsf(xx)));   // stable softplus
      float gg = -__expf(alog) * sp;                             // log-decay
      if (gb) gb[(long)s * NH + hh] = gg;
      eg[(long)s * NH + hh] = __expf(gg);
    } else {
      bet[(long)s * NH + hh] = sigmoidf_(a);
    }
  }
}

// ---------------------------------------------------------------- conv + SiLU + l2norm
__global__ __launch_bounds__(256)
void conv_norm(const bf16* __restrict__ mixed, const void* __restrict__ convwr,
               bf16* __restrict__ qbuf, bf16* __restrict__ kbuf, bf16* __restrict__ vbuf,
               const unsigned* __restrict__ flagp) {
  const bool f32g = (*flagp != 0);
  const int s = blockIdx.x;
  const int c = blockIdx.y * 256 + threadIdx.x;
  float w0, w1, w2, w3;
  if (f32g) {
    const float* wp = (const float*)convwr + (long)c * 4;
    w0 = wp[0]; w1 = wp[1]; w2 = wp[2]; w3 = wp[3];
  } else {
    const u16* wp = (const u16*)convwr + (long)c * 4;
    w0 = b2f(wp[0]); w1 = b2f(wp[1]); w2 = b2f(wp[2]); w3 = b2f(wp[3]);
  }
  float acc = w3 * (float)mixed[(long)s * CONV_DIM + c];
  if (s >= 1) acc += w2 * (float)mixed[(long)(s - 1) * CONV_DIM + c];
  if (s >= 2) acc += w1 * (float)mixed[(long)(s - 2) * CONV_DIM + c];
  if (s >= 3) acc += w0 * (float)mixed[(long)(s - 3) * CONV_DIM + c];
  float y = acc * sigmoidf_(acc);  // SiLU
  if (c < 2 * KEY_DIM) {
    float ss = y * y;
    ss += __shfl_xor(ss, 1);  ss += __shfl_xor(ss, 2);  ss += __shfl_xor(ss, 4);
    ss += __shfl_xor(ss, 8);  ss += __shfl_xor(ss, 16); ss += __shfl_xor(ss, 32);
    float scale = rsqrtf(ss + 1e-6f);
    if (c < KEY_DIM) scale *= 0.125f;
    y *= scale;
  }
  if (c < KEY_DIM)            qbuf[(long)s * KEY_DIM + c] = (bf16)y;
  else if (c < 2 * KEY_DIM)   kbuf[(long)s * KEY_DIM + (c - KEY_DIM)] = (bf16)y;
  else                        vbuf[(long)s * VAL_DIM + (c - 2 * KEY_DIM)] = (bf16)y;
}

// ---------------------------------------------------------------- DPP 16-lane sum (fallback scan)
template<int CTRL>
__device__ __forceinline__ float dpp_add(float x) {
  int y = __builtin_amdgcn_update_dpp(0, __float_as_int(x), CTRL, 0xF, 0xF, true);
  return x + __int_as_float(y);
}
__device__ __forceinline__ float dpp_sum16(float x) {
  x = dpp_add<0xB1>(x);   // quad_perm xor1
  x = dpp_add<0x4E>(x);   // quad_perm xor2
  x = dpp_add<0x141>(x);  // row_half_mirror (xor4)
  x = dpp_add<0x140>(x);  // row_mirror (xor8)
  return x;
}

// ---------------------------------------------------------------- fused per-step scan (FALLBACK path only)
__global__ __launch_bounds__(256, 2)
void fused_scan(const bf16* __restrict__ qbuf, const bf16* __restrict__ kbuf,
                const bf16* __restrict__ vbuf, const float* __restrict__ eg,
                const float* __restrict__ bet, bf16* __restrict__ core,
                const bf16* __restrict__ hsb, const bf16* __restrict__ wzb,
                bf16* __restrict__ zbuf, const void* __restrict__ woutr,
                bf16* __restrict__ woutb, const unsigned* __restrict__ flagp,
                int nScan, int nGemm) {
  __shared__ __align__(16) char smem[16384];
  const int t = threadIdx.x;
  const int b = blockIdx.x;

  if (b < nScan) {
    const int h  = b >> 3;
    const int vg = (b & 7) * 16;
    const int g  = t >> 4;
    const int L  = t & 15;
    bf16*  kqs = (bf16*)smem;               // [2][2048] elems
    bf16*  vts = (bf16*)(smem + 8192);      // [2][256] elems
    float* ets = (float*)(smem + 9216);     // [2][16]
    float* bts = (float*)(smem + 9344);     // [2][16]

#define STAGE(buf, s0)                                                          \
    {                                                                           \
      int byte = t * 16;                                                        \
      const bf16* src;                                                          \
      if (byte < 2048) {                                                        \
        int row = byte >> 7, el = (byte & 127) >> 1;                            \
        src = kbuf + (long)((s0) + row) * KEY_DIM + h * DKv + el;               \
      } else {                                                                  \
        int b2 = byte - 2048;                                                   \
        int row = b2 >> 7, el = (b2 & 127) >> 1;                                \
        src = qbuf + (long)((s0) + row) * KEY_DIM + h * DKv + el;               \
      }                                                                         \
      GLDS16(src, smem + (buf) * 4096 + byte);                                  \
      if (t < 32) {                                                             \
        int row = t >> 1, el = (t & 1) * 8;                                     \
        const bf16* vsrc = vbuf + (long)((s0) + row) * VAL_DIM + h * DVv + vg + el; \
        GLDS16(vsrc, smem + 8192 + (buf) * 512 + t * 16);                       \
      }                                                                         \
    }

    float er = 0.f, br = 0.f;
    if (t < 16)      er = eg[(long)t * NH + h];
    else if (t < 32) br = bet[(long)(t - 16) * NH + h];
    STAGE(0, 0);
    if (t < 16)      ets[t] = er;
    else if (t < 32) bts[t - 16] = br;
    __syncthreads();

    float S0 = 0.f, S1 = 0.f, S2 = 0.f, S3 = 0.f;
    for (int tile = 0; tile < 128; ++tile) {
      const int buf = tile & 1, nb = buf ^ 1;
      if (tile < 127) {
        STAGE(nb, (tile + 1) * 16);
        if (t < 16)      er = eg[(long)((tile + 1) * 16 + t) * NH + h];
        else if (t < 32) br = bet[(long)((tile + 1) * 16 + (t - 16)) * NH + h];
      }
      const bf16*  ktb = kqs + buf * 2048;
      const bf16*  qtb = ktb + 1024;
      const bf16*  vtb = vts + buf * 256;
      const float* etb = ets + buf * 16;
      const float* btb = bts + buf * 16;
      const long sbase = (long)tile * 16;

      bf16x4 kR[2], qR[2];
      float  vR[2], eR[2], bR[2];
      kR[0] = *(const bf16x4*)(ktb + 0 * 64 + L * 4);
      qR[0] = *(const bf16x4*)(qtb + 0 * 64 + L * 4);
      vR[0] = (float)vtb[0 * 16 + g];  eR[0] = etb[0];  bR[0] = btb[0];
      kR[1] = *(const bf16x4*)(ktb + 1 * 64 + L * 4);
      qR[1] = *(const bf16x4*)(qtb + 1 * 64 + L * 4);
      vR[1] = (float)vtb[1 * 16 + g];  eR[1] = etb[1];  bR[1] = btb[1];
#pragma unroll
      for (int s = 0; s < 16; ++s) {
        const int sl = s & 1;
        bf16x4 kk = kR[sl], qq = qR[sl];
        float vv = vR[sl], ee = eR[sl], bb = bR[sl];
        if (s < 14) {
          const int s2 = s + 2;
          kR[sl] = *(const bf16x4*)(ktb + s2 * 64 + L * 4);
          qR[sl] = *(const bf16x4*)(qtb + s2 * 64 + L * 4);
          vR[sl] = (float)vtb[s2 * 16 + g];
          eR[sl] = etb[s2];  bR[sl] = btb[s2];
        }
        float ebt = ee * bb, vbt = vv * bb;
        float k0 = (float)kk[0], k1 = (float)kk[1], k2 = (float)kk[2], k3 = (float)kk[3];
        float D0 = S0 * ee, D1 = S1 * ee, D2 = S2 * ee, D3 = S3 * ee;
        float p = (k0 * S0 + k1 * S1) + (k2 * S2 + k3 * S3);
        p = dpp_sum16(p);
        float delta = vbt - ebt * p;
        S0 = fmaf(k0, delta, D0); S1 = fmaf(k1, delta, D1);
        S2 = fmaf(k2, delta, D2); S3 = fmaf(k3, delta, D3);
        float q0 = (float)qq[0], q1 = (float)qq[1], q2 = (float)qq[2], q3 = (float)qq[3];
        float o = (q0 * S0 + q1 * S1) + (q2 * S2 + q3 * S3);
        o = dpp_sum16(o);
        if (L == 0) core[(sbase + s) * VAL_DIM + h * DVv + vg + g] = (bf16)o;
      }
      if (tile < 127) {
        if (t < 16)      ets[nb * 16 + t] = er;
        else if (t < 32) bts[nb * 16 + (t - 16)] = br;
      }
      __syncthreads();
    }
#undef STAGE
  } else if (b < nScan + nGemm) {
    int gb = b - nScan;
    gemm_body_bf16(smem, hsb, wzb, zbuf, VAL_DIM, HIDDEN, gb & 15, gb >> 4, t);
  } else {
    long i = ((long)(b - nScan - nGemm) * 256 + t) * 8;
    if (i < (long)HIDDEN * VAL_DIM) {
      if (*flagp) {
        const f32x4* s = (const f32x4*)((const float*)woutr + i);
        f32x4 a = s[0], c = s[1];
        bf16x8 o;
#pragma unroll
        for (int j = 0; j < 4; ++j) { o[j] = (bf16)a[j]; o[4 + j] = (bf16)c[j]; }
        *(bf16x8*)(woutb + i) = o;
      } else {
        *(bf16x8*)(woutb + i) = *(const bf16x8*)((const bf16*)woutr + i);
      }
    }
  }
}

// ================================================================ CHUNKED DELTA RULE
// chunk length 64, 32 chunks, 16 heads. Per chunk-head (c,h):
//   cum_t = prefix-sum of g; d_t = e^{cum_t}
//   A[t][i] = beta_t e^{cum_t-cum_i} (k_t.k_i), strictly lower
//   [Dloc | W] = (I+A)^{-1} [diag(beta)V | diag(beta*d)K]
//   delta = Dloc - W S0;  S' = e^{cumC} S0 + K'^T delta, K'[i]=e^{cumC-cum_i}k_i
//   O = diag(d) Q S0 + (Minc o Q K^T) delta
// dloc[(c,h)][t][v] bf16 (d_out+8M); negW hi/lo [t][k] bf16 (ws+24M,+28M);
// dTg[(c,h)][v][t] bf16 (ws+0); o1g[(c,h)][v][t] bf16 pre-scaled by d_t (ws+8M).

// ---------------------------------------------------------------- phase A (+ fused zgemm + woutcvt)
__global__ __launch_bounds__(256, 2)
void chunk_a(const bf16* __restrict__ kbuf, const bf16* __restrict__ vbuf,
             const float* __restrict__ gbuf, const float* __restrict__ betp,
             bf16* __restrict__ dloc, bf16* __restrict__ whig, bf16* __restrict__ wlog,
             const bf16* __restrict__ hsb, const bf16* __restrict__ wzb,
             bf16* __restrict__ zbuf, const void* __restrict__ woutr,
             bf16* __restrict__ woutb, const unsigned* __restrict__ flagp) {
  __shared__ __align__(16) char smem[25600];
  const int t = threadIdx.x;
  const int b = blockIdx.x;
  if (b < 512) {
    const int c = b >> 4, h = b & 15;
    bf16*  Ks   = (bf16*)smem;                 // [64][64] 8192 B
    float* At   = (float*)(smem + 8192);       // [64][64] 16384 B, At[i][t] = A[t][i]
    float* cumS = (float*)(smem + 24576);      // 64
    float* bS   = (float*)(smem + 24832);      // 64
    float* dS   = (float*)(smem + 25088);      // 64
    // stage K chunk -> LDS (linear)
#pragma unroll
    for (int it = 0; it < 2; ++it) {
      int byte = (it * 256 + t) * 16;
      int row = byte >> 7, col = (byte & 127) >> 1;
      const bf16* src = kbuf + (long)(c * 64 + row) * KEY_DIM + h * DKv + col;
      GLDS16(src, smem + byte);
    }
    if (t < 64) {  // wave 0: within-chunk prefix sum of log-decay
      float cc = gbuf[(long)(c * 64 + t) * NH + h];
#pragma unroll
      for (int d = 1; d < 64; d <<= 1) { float y = __shfl_up(cc, d); if (t >= d) cc += y; }
      cumS[t] = cc;
      dS[t] = __expf(cc);
      bS[t] = betp[(long)(c * 64 + t) * NH + h];
    }
    {  // zero At (upper+diag must read as 0 in the quad-vectorized substitution)
      f32x4 z = {0.f, 0.f, 0.f, 0.f};
#pragma unroll
      for (int i = 0; i < 4; ++i) ((f32x4*)At)[t * 4 + i] = z;
    }
    __syncthreads();
    // G = K K^T via MFMA; masked+scaled, stored transposed into At
    {
      const int lane = t & 63, wv = t >> 6;
      const int r = lane & 15, q = lane >> 4;
      const bf16x8* Ks8 = (const bf16x8*)Ks;
#pragma unroll
      for (int n = 0; n < 4; ++n) {
        f32x4 acc = {0.f, 0.f, 0.f, 0.f};
#pragma unroll
        for (int kk = 0; kk < 2; ++kk) {
          bf16x8 af  = Ks8[(wv * 16 + r) * 8 + kk * 4 + q];
          bf16x8 bfv = Ks8[(n  * 16 + r) * 8 + kk * 4 + q];
          acc = __builtin_amdgcn_mfma_f32_16x16x32_bf16(af, bfv, acc, 0, 0, 0);
        }
        const int i = n * 16 + r;
#pragma unroll
        for (int rr = 0; rr < 4; ++rr) {
          const int tr = wv * 16 + q * 4 + rr;
          if (i < tr)
            At[i * 64 + tr] = bS[tr] * __expf(cumS[tr] - cumS[i]) * acc[rr];
        }
      }
    }
    __syncthreads();
    // column-parallel forward substitution: x = (I+A)^{-1} r, one column per thread
    if (t < 192) {
      float x[64];
      const long base = ((long)(c * 16 + h)) * 64;
      if (t < 128) {
#pragma unroll
        for (int s = 0; s < 64; ++s)
          x[s] = bS[s] * (float)vbuf[(long)(c * 64 + s) * VAL_DIM + h * DVv + t];
      } else {
        const int k = t - 128;
#pragma unroll
        for (int s = 0; s < 64; ++s)
          x[s] = bS[s] * dS[s] * (float)Ks[s * 64 + k];
      }
#pragma unroll
      for (int s = 0; s < 64; ++s) {
        const float val = x[s];
        const f32x4* row4 = (const f32x4*)(At + s * 64);
#pragma unroll
        for (int qd = (s >> 2); qd < 16; ++qd) {
          f32x4 a4 = row4[qd];
          x[qd * 4 + 0] = fmaf(-a4[0], val, x[qd * 4 + 0]);
          x[qd * 4 + 1] = fmaf(-a4[1], val, x[qd * 4 + 1]);
          x[qd * 4 + 2] = fmaf(-a4[2], val, x[qd * 4 + 2]);
          x[qd * 4 + 3] = fmaf(-a4[3], val, x[qd * 4 + 3]);
        }
      }
      if (t < 128) {          // Dloc column t  -> dloc[t][v] rows (bf16)
#pragma unroll
        for (int s = 0; s < 64; ++s)
          dloc[(base + s) * 128 + t] = (bf16)x[s];
      } else {                // W column k -> negW hi/lo [t][k] (coalesced per-s across wave)
        const int k = t - 128;
        const long wb = base * 64;   // = (c*16+h)*4096
#pragma unroll
        for (int s = 0; s < 64; ++s) {
          float v = -x[s];
          bf16 hh = (bf16)v;
          whig[wb + s * 64 + k] = hh;
          wlog[wb + s * 64 + k] = (bf16)(v - (float)hh);
        }
      }
    }
  } else if (b < 768) {
    int gb = b - 512;
    gemm_body_bf16(smem, hsb, wzb, zbuf, VAL_DIM, HIDDEN, gb & 15, gb >> 4, t);
  } else {
    long i = ((long)(b - 768) * 256 + t) * 8;
    if (i < (long)HIDDEN * VAL_DIM) {
      if (*flagp) {
        const f32x4* s = (const f32x4*)((const float*)woutr + i);
        f32x4 a = s[0], cc = s[1];
        bf16x8 o;
#pragma unroll
        for (int j = 0; j < 4; ++j) { o[j] = (bf16)a[j]; o[4 + j] = (bf16)cc[j]; }
        *(bf16x8*)(woutb + i) = o;
      } else {
        *(bf16x8*)(woutb + i) = *(const bf16x8*)((const bf16*)woutr + i);
      }
    }
  }
}

// ---------------------------------------------------------------- phase B: MFMA chunk-serial recurrence
// grid 32 = h*2 + vhalf (64 v per block). State: persistent f32 accregs (wave w owns
// v-rows w*16..w*16+15); bf16 hi/lo copies in LDS (X8 swizzle) feed MFMA B-operands.
// Per chunk:  delta = Dl + negW*(Shi+Slo)   [C-init from Dl; 3 hi/lo terms]
//             o1    = dS_t * Q*(Shi+Slo)
//             S'    = dC*S + (fS-scaled deltaT hi/lo) x K^T
// X8 swizzle: 8-elem group g of row R lives at phys group g ^ (R&7).
__global__ __launch_bounds__(256, 1)
void chunk_b(const bf16* __restrict__ qbuf, const bf16* __restrict__ kbuf,
             const float* __restrict__ gbuf, const bf16* __restrict__ dloc,
             const bf16* __restrict__ whig, const bf16* __restrict__ wlog,
             bf16* __restrict__ dTg, bf16* __restrict__ o1g) {
  __shared__ __align__(16) char smem[123904];
  bf16* Wh  = (bf16*)(smem);             // [2][64][64] swz
  bf16* Wl  = (bf16*)(smem + 16384);     // [2][64][64] swz
  bf16* Qs  = (bf16*)(smem + 32768);     // [2][64][64] swz
  bf16* Ks  = (bf16*)(smem + 49152);     // [2][64][64] linear
  bf16* Dls = (bf16*)(smem + 65536);     // [2][64][64] swz
  bf16* KT  = (bf16*)(smem + 81920);     // [64][64] swz (K^T)
  bf16* Shi = (bf16*)(smem + 90112);     // [64][64] swz
  bf16* Slo = (bf16*)(smem + 98304);     // [64][64] swz
  bf16* Dth = (bf16*)(smem + 106496);    // [64][64] swz (fS-scaled deltaT hi)
  bf16* Dtl = (bf16*)(smem + 114688);    // [64][64] swz (lo)
  float* fSb = (float*)(smem + 122880);  // [2][64]
  float* dSb = (float*)(smem + 123392);  // [2][64]

  const int t = threadIdx.x;
  const int h = blockIdx.x >> 1, vhalf = blockIdx.x & 1;
  const int lane = t & 63, w = t >> 6;
  const int r = lane & 15, q = lane >> 4;
  const int tb = w * 16 + q * 4;         // this lane's C-row base (t or v dim)

  auto stage = [&](int bb, int cc) {
    const long c16h = (long)(cc * 16 + h);
#pragma unroll
    for (int it = 0; it < 2; ++it) {
      int p = it * 256 + t;              // 16B-group id, 0..511
      int row = p >> 3, g = p & 7;
      int sg = ((g ^ (row & 7)) << 3);   // pre-swizzled source column
      GLDS16(whig + c16h * 4096 + row * 64 + sg, (char*)Wh + bb * 8192 + p * 16);
      GLDS16(wlog + c16h * 4096 + row * 64 + sg, (char*)Wl + bb * 8192 + p * 16);
      GLDS16(qbuf + (long)(cc * 64 + row) * KEY_DIM + h * DKv + sg, (char*)Qs + bb * 8192 + p * 16);
      GLDS16(kbuf + (long)(cc * 64 + row) * KEY_DIM + h * DKv + (g << 3), (char*)Ks + bb * 8192 + p * 16);
      GLDS16(dloc + (c16h * 64 + row) * 128 + vhalf * 64 + sg, (char*)Dls + bb * 8192 + p * 16);
    }
  };
  auto prefix = [&](int bb, int cc) {
    if (t < 64) {
      float cs = gbuf[(long)(cc * 64 + t) * NH + h];
#pragma unroll
      for (int d = 1; d < 64; d <<= 1) { float y = __shfl_up(cs, d); if (t >= d) cs += y; }
      float tot = __shfl(cs, 63);
      fSb[bb * 64 + t] = __expf(tot - cs);   // e^{cumC - cum_t}
      dSb[bb * 64 + t] = __expf(cs);         // d_t
    }
  };

  // prologue: zero state copies, stage chunk 0
  {
    f32x4 z = {0.f, 0.f, 0.f, 0.f};
    ((f32x4*)Shi)[t] = z; ((f32x4*)Shi)[t + 256] = z;
    ((f32x4*)Slo)[t] = z; ((f32x4*)Slo)[t + 256] = z;
  }
  stage(0, 0);
  prefix(0, 0);
  f32x4 Sacc[4] = {};   // k-tiles n=0..3 for this wave's v-rows

  for (int c = 0; c < 32; ++c) {
    const int buf = c & 1, nb = buf ^ 1;
    __syncthreads();   // B1: stage[buf] drained; prev chunk's S hi/lo visible
    const bf16* wh = Wh + buf * 4096;
    const bf16* wl = Wl + buf * 4096;
    const bf16* qs = Qs + buf * 4096;
    const bf16* ks = Ks + buf * 4096;
    const bf16* dl = Dls + buf * 4096;
    const float* fS = fSb + buf * 64;
    const float* dS = dSb + buf * 64;
    const long gch = (long)(c * 16 + h) * 8192 + (long)(vhalf * 64) * 64;

    // K^T build (swizzled): lane k, rows i = w*16..w*16+15
    if (c < 31) {
      const int k = lane;
#pragma unroll
      for (int ii = 0; ii < 16; ++ii) {
        const int i = w * 16 + ii;
        const int pg = (i >> 3) ^ (k & 7);
        KT[k * 64 + pg * 8 + (i & 7)] = ks[i * 64 + k];
      }
    }

    // hoisted decay factors for this lane's 4 t-rows
    float fs4[4], ds4[4];
#pragma unroll
    for (int rr = 0; rr < 4; ++rr) { fs4[rr] = fS[tb + rr]; ds4[rr] = dS[tb + rr]; }

    // A-frags: negW hi/lo rows t, Q rows t  (swizzled group)
    bf16x8 wahi[2], walo[2], qa[2];
#pragma unroll
    for (int kk = 0; kk < 2; ++kk) {
      const int row = w * 16 + r;
      const int g = (kk * 4 + q) ^ (row & 7);
      wahi[kk] = *(const bf16x8*)(wh + row * 64 + g * 8);
      walo[kk] = *(const bf16x8*)(wl + row * 64 + g * 8);
      qa[kk]   = *(const bf16x8*)(qs + row * 64 + g * 8);
    }

    // mm2 + o1 per v-tile n
#pragma unroll
    for (int n = 0; n < 4; ++n) {
      const int vrow = n * 16 + r;
      bf16x8 sh[2], sl[2];
#pragma unroll
      for (int kk = 0; kk < 2; ++kk) {
        const int g = (kk * 4 + q) ^ (vrow & 7);
        sh[kk] = *(const bf16x8*)(Shi + vrow * 64 + g * 8);
        sl[kk] = *(const bf16x8*)(Slo + vrow * 64 + g * 8);
      }
      f32x4 da;
#pragma unroll
      for (int rr = 0; rr < 4; ++rr) {
        const int trow = tb + rr;
        const int pg = (vrow >> 3) ^ (trow & 7);   // Dl swizzled scalar read
        da[rr] = (float)dl[trow * 64 + pg * 8 + (vrow & 7)];
      }
      f32x4 oa = {0.f, 0.f, 0.f, 0.f};
#pragma unroll
      for (int kk = 0; kk < 2; ++kk) {
        da = __builtin_amdgcn_mfma_f32_16x16x32_bf16(wahi[kk], sh[kk], da, 0, 0, 0);
        da = __builtin_amdgcn_mfma_f32_16x16x32_bf16(wahi[kk], sl[kk], da, 0, 0, 0);
        da = __builtin_amdgcn_mfma_f32_16x16x32_bf16(walo[kk], sh[kk], da, 0, 0, 0);
        oa = __builtin_amdgcn_mfma_f32_16x16x32_bf16(qa[kk],   sh[kk], oa, 0, 0, 0);
        oa = __builtin_amdgcn_mfma_f32_16x16x32_bf16(qa[kk],   sl[kk], oa, 0, 0, 0);
      }
      // emit: dTg (raw delta), o1g (dS-scaled), DltT hi/lo (fS-scaled, swizzled)
      bf16x4 dpk, opk, fhk, flk;
#pragma unroll
      for (int rr = 0; rr < 4; ++rr) {
        float dv = da[rr];
        dpk[rr] = (bf16)dv;
        float p = fs4[rr] * dv;
        bf16 ph = (bf16)p;
        fhk[rr] = ph;
        flk[rr] = (bf16)(p - (float)ph);
        opk[rr] = (bf16)(ds4[rr] * oa[rr]);
      }
      *(bf16x4*)(dTg + gch + (long)vrow * 64 + tb) = dpk;
      *(bf16x4*)(o1g + gch + (long)vrow * 64 + tb) = opk;
      const int pg = (tb >> 3) ^ (vrow & 7);
      *(bf16x4*)(Dth + vrow * 64 + pg * 8 + (tb & 7)) = fhk;
      *(bf16x4*)(Dtl + vrow * 64 + pg * 8 + (tb & 7)) = flk;
    }

    __syncthreads();   // B2: DltT + KT ready; stage[buf]/S reads complete
    if (c < 31) {
      stage(nb, c + 1);      // prefetch (drained at next B1)
      prefix(nb, c + 1);
      // update: S' = dC*S + DltT(hi/lo) x KT   [wave w owns v-rows w*16..+15]
      const float dC = dS[63];
      bf16x8 dh[2], dlo[2];
#pragma unroll
      for (int kk = 0; kk < 2; ++kk) {
        const int vrow = w * 16 + r;
        const int g = (kk * 4 + q) ^ (vrow & 7);
        dh[kk]  = *(const bf16x8*)(Dth + vrow * 64 + g * 8);
        dlo[kk] = *(const bf16x8*)(Dtl + vrow * 64 + g * 8);
      }
#pragma unroll
      for (int n = 0; n < 4; ++n) {
        f32x4 sa;
#pragma unroll
        for (int rr = 0; rr < 4; ++rr) sa[rr] = dC * Sacc[n][rr];
        bf16x8 ktf[2];
#pragma unroll
        for (int kk = 0; kk < 2; ++kk) {
          const int krow = n * 16 + r;
          const int g = (kk * 4 + q) ^ (krow & 7);
          ktf[kk] = *(const bf16x8*)(KT + krow * 64 + g * 8);
        }
#pragma unroll
        for (int kk = 0; kk < 2; ++kk) {
          sa = __builtin_amdgcn_mfma_f32_16x16x32_bf16(dh[kk],  ktf[kk], sa, 0, 0, 0);
          sa = __builtin_amdgcn_mfma_f32_16x16x32_bf16(dlo[kk], ktf[kk], sa, 0, 0, 0);
        }
        Sacc[n] = sa;
        // write S hi/lo (swizzled scalar stores): elems (v = tb+rr, k = n*16+r)
        const int k = n * 16 + r;
#pragma unroll
        for (int rr = 0; rr < 4; ++rr) {
          const int v = tb + rr;
          float s = sa[rr];
          bf16 hh = (bf16)s;
          const int pg = (k >> 3) ^ (v & 7);
          Shi[v * 64 + pg * 8 + (k & 7)] = hh;
          Slo[v * 64 + pg * 8 + (k & 7)] = (bf16)(s - (float)hh);
        }
      }
    }
  }
}

// ---------------------------------------------------------------- phase C: outputs, MFMA
// grid 512 = c*16 + h.  O[t][v] = o1[v][t] + sum_i P[t][i] delta^T[v][i]
__global__ __launch_bounds__(256, 2)
void chunk_c(const bf16* __restrict__ qbuf, const bf16* __restrict__ kbuf,
             const float* __restrict__ gbuf, const bf16* __restrict__ dTg,
             const bf16* __restrict__ o1g, bf16* __restrict__ core) {
  // Qs@0 8K | Ks@8192 8K | Pl@16384 8K | dT@24576 16K | o1l@40960 16K | cum@57344
  __shared__ __align__(16) char smem[57600];
  const int t = threadIdx.x;
  const int c = blockIdx.x >> 4, h = blockIdx.x & 15;
  const long c16h = (long)(c * 16 + h);
  bf16* Qs  = (bf16*)smem;
  bf16* Ksl = (bf16*)(smem + 8192);
  bf16* Pl  = (bf16*)(smem + 16384);
  const bf16* dT  = (const bf16*)(smem + 24576);
  const bf16* o1l = (const bf16*)(smem + 40960);
  float* cumS = (float*)(smem + 57344);

#pragma unroll
  for (int it = 0; it < 2; ++it) {
    int byte = (it * 256 + t) * 16;
    int row = byte >> 7, col = (byte & 127) >> 1;
    GLDS16(qbuf + (long)(c * 64 + row) * KEY_DIM + h * DKv + col, smem + byte);
    GLDS16(kbuf + (long)(c * 64 + row) * KEY_DIM + h * DKv + col, smem + 8192 + byte);
  }
#pragma unroll
  for (int it = 0; it < 4; ++it) {
    int byte = (it * 256 + t) * 16;
    GLDS16(dTg + c16h * 8192 + (byte >> 1), smem + 24576 + byte);
    GLDS16(o1g + c16h * 8192 + (byte >> 1), smem + 40960 + byte);
  }
  if (t < 64) {
    float cc = gbuf[(long)(c * 64 + t) * NH + h];
#pragma unroll
    for (int d = 1; d < 64; d <<= 1) { float y = __shfl_up(cc, d); if (t >= d) cc += y; }
    cumS[t] = cc;
  }
  __syncthreads();

  const int lane = t & 63, wv = t >> 6;
  const int r = lane & 15, q = lane >> 4;
  const bf16x8* Qs8 = (const bf16x8*)Qs;
  const bf16x8* Ks8 = (const bf16x8*)Ksl;

  // c1: P[t][i] = (i<=t) ? e^{cum_t-cum_i} (q_t.k_i) : 0
#pragma unroll
  for (int n = 0; n < 4; ++n) {
    f32x4 acc = {0.f, 0.f, 0.f, 0.f};
#pragma unroll
    for (int kk = 0; kk < 2; ++kk)
      acc = __builtin_amdgcn_mfma_f32_16x16x32_bf16(
          Qs8[(wv * 16 + r) * 8 + kk * 4 + q], Ks8[(n * 16 + r) * 8 + kk * 4 + q], acc, 0, 0, 0);
    const int i = n * 16 + r;
#pragma unroll
    for (int rr = 0; rr < 4; ++rr) {
      const int tr = wv * 16 + q * 4 + rr;
      Pl[tr * 64 + i] = (i <= tr) ? (bf16)(__expf(cumS[tr] - cumS[i]) * acc[rr]) : (bf16)0.0f;
    }
  }
  __syncthreads();

  // c2: O = o1 (acc init) + P.deltaT via MFMA
  {
    const bf16x8* Pl8 = (const bf16x8*)Pl;
    const bf16x8* dT8 = (const bf16x8*)dT;
    bf16x8 pf[2];
#pragma unroll
    for (int kk = 0; kk < 2; ++kk) pf[kk] = Pl8[(wv * 16 + r) * 8 + kk * 4 + q];
#pragma unroll
    for (int n = 0; n < 8; ++n) {
      const int v = n * 16 + r;
      f32x4 acc;
#pragma unroll
      for (int rr = 0; rr < 4; ++rr)
        acc[rr] = (float)o1l[v * 64 + (wv * 16 + q * 4 + rr)];
#pragma unroll
      for (int kk = 0; kk < 2; ++kk)
        acc = __builtin_amdgcn_mfma_f32_16x16x32_bf16(
            pf[kk], dT8[(n * 16 + r) * 8 + kk * 4 + q], acc, 0, 0, 0);
#pragma unroll
      for (int rr = 0; rr < 4; ++rr) {
        const int tr = wv * 16 + q * 4 + rr;
        core[(long)(c * 64 + tr) * VAL_DIM + h * DVv + v] = (bf16)acc[rr];
      }
    }
  }
}

// ---------------------------------------------------------------- RMSNorm + SiLU(z) gate
__global__ __launch_bounds__(256)
void gate_norm(const bf16* __restrict__ core, const bf16* __restrict__ zb,
               const void* __restrict__ normwr, bf16* __restrict__ gated,
               const unsigned* __restrict__ flagp) {
  const bool f32g = (*flagp != 0);
  const int s  = blockIdx.x;
  const int t  = threadIdx.x;
  const int h  = t >> 4;
  const int li = t & 15;
  const long base = (long)s * VAL_DIM + h * DVv + li * 8;
  bf16x8 c8 = *(const bf16x8*)(core + base);
  bf16x8 z8 = *(const bf16x8*)(zb + base);
  float x[8], z[8], nw[8];
  float ss = 0.f;
#pragma unroll
  for (int j = 0; j < 8; ++j) { x[j] = (float)c8[j]; z[j] = (float)z8[j]; ss += x[j] * x[j]; }
  if (f32g) {
    const float* np_ = (const float*)normwr + li * 8;
#pragma unroll
    for (int j = 0; j < 8; ++j) nw[j] = np_[j];
  } else {
    const u16* np_ = (const u16*)normwr + li * 8;
#pragma unroll
    for (int j = 0; j < 8; ++j) nw[j] = b2f(np_[j]);
  }
  ss += __shfl_xor(ss, 1); ss += __shfl_xor(ss, 2);
  ss += __shfl_xor(ss, 4); ss += __shfl_xor(ss, 8);
  float scale = rsqrtf(ss * (1.f / 128.f) + 1e-6f);
#pragma unroll
  for (int j = 0; j < 8; ++j) {
    float y = x[j] * scale * nw[j];
    y *= z[j] * sigmoidf_(z[j]);
    gated[base + j] = (bf16)y;
  }
}

// ---------------------------------------------------------------- launcher
extern "C" void kernel_launch(void* const* d_in, const int* in_sizes, int n_in,
                              void* d_out, int out_size, void* d_ws, size_t ws_size,
                              hipStream_t stream) {
  char* ws = (char*)d_ws;
  const bool big = ws_size >= ((48u << 20) + (512u << 10));

  if (big) {
    // ws: [0,8M) hsb -> dTg | [8,16M) wqkvb/wzb -> o1g | [16,24M) wqkvb -> zbuf
    //     [24,28M) mixed -> whig | [28,32M) mixed -> wlog | [32,40M) mixed -> woutb
    //     [40,44M) qbuf | [44,48M) kbuf -> (with qbuf) gated | [48M..) eg|beta|g|flag
    // d_out: [0,8M) vbuf -> core | [8,16M) dloc; final gemm overwrites all 16M f32.
    bf16*  hsb   = (bf16*)ws;
    bf16*  wqkvb = (bf16*)(ws + (8u << 20));
    bf16*  wzb   = (bf16*)(ws + (8u << 20));
    bf16*  zbuf  = (bf16*)(ws + (16u << 20));
    bf16*  mixed = (bf16*)(ws + (24u << 20));
    bf16*  whig  = (bf16*)(ws + (24u << 20));
    bf16*  wlog  = (bf16*)(ws + (28u << 20));
    bf16*  woutb = (bf16*)(ws + (32u << 20));
    bf16*  qbuf  = (bf16*)(ws + (40u << 20));
    bf16*  kbuf  = (bf16*)(ws + (44u << 20));
    bf16*  gated = (bf16*)(ws + (40u << 20));
    bf16*  dTg   = (bf16*)ws;
    bf16*  o1g   = (bf16*)(ws + (8u << 20));
    float* egp  = (float*)(ws + (48u << 20));
    float* betp = (float*)(ws + (48u << 20) + (128u << 10));
    float* gbp  = (float*)(ws + (48u << 20) + (256u << 10));
    unsigned* flagp = (unsigned*)(ws + (48u << 20) + (384u << 10));
    bf16* vbuf  = (bf16*)d_out;
    bf16* dlocp = (bf16*)((char*)d_out + (8u << 20));
    bf16* corep = (bf16*)d_out;

    detect_dtype<<<1, 64, 0, stream>>>((const u16*)d_in[0], flagp);
    proj_ab<<<SEQ, 256, 0, stream>>>(d_in[0], d_in[2], d_in[3], d_in[6], d_in[7], egp, betp, gbp, flagp);
    cvt_bf16<<<(SEQ * HIDDEN) / 2048, 256, 0, stream>>>(d_in[0], hsb, (long)SEQ * HIDDEN, flagp);
    cvt_bf16<<<(CONV_DIM * HIDDEN) / 2048, 256, 0, stream>>>(d_in[1], wqkvb, (long)CONV_DIM * HIDDEN, flagp);
    gemm_nt<false><<<dim3(CONV_DIM / 128, SEQ / 128), 256, 0, stream>>>(hsb, wqkvb, mixed, CONV_DIM, HIDDEN, flagp, 0, 0);
    cvt_bf16<<<(VAL_DIM * HIDDEN) / 2048, 256, 0, stream>>>(d_in[4], wzb, (long)VAL_DIM * HIDDEN, flagp);
    conv_norm<<<dim3(SEQ, CONV_DIM / 256), 256, 0, stream>>>(mixed, d_in[5], qbuf, kbuf, vbuf, flagp);
    chunk_a<<<512 + 256 + 2048, 256, 0, stream>>>(kbuf, vbuf, gbp, betp, dlocp, whig, wlog,
                                                  hsb, wzb, zbuf, d_in[9], woutb, flagp);
    chunk_b<<<32, 256, 0, stream>>>(qbuf, kbuf, gbp, dlocp, whig, wlog, dTg, o1g);
    chunk_c<<<512, 256, 0, stream>>>(qbuf, kbuf, gbp, dTg, o1g, corep);
    gate_norm<<<SEQ, 256, 0, stream>>>(corep, zbuf, d_in[8], gated, flagp);
    gemm_nt<true><<<dim3(HIDDEN / 128, SEQ / 128), 256, 0, stream>>>(gated, woutb, d_out, HIDDEN, VAL_DIM, flagp, 0, 0);
  } else {
    // Fallback layout (peak 24.26 MiB): r6-style staging GEMMs; per-step scan.
    bf16* mixed = (bf16*)ws;
    bf16* qbuf  = (bf16*)(ws + (16u << 20));
    bf16* kbuf  = (bf16*)(ws + (20u << 20));
    bf16* zbuf  = (bf16*)ws;
    bf16* corep = (bf16*)(ws + (8u << 20));
    bf16* gated = (bf16*)(ws + (16u << 20));
    float* egp  = (float*)(ws + (24u << 20));
    float* betp = (float*)(ws + (24u << 20) + (128u << 10));
    unsigned* flagp = (unsigned*)(ws + (24u << 20) + (256u << 10));
    bf16* vbuf  = (bf16*)d_out;

    detect_dtype<<<1, 64, 0, stream>>>((const u16*)d_in[0], flagp);
    proj_ab<<<SEQ, 256, 0, stream>>>(d_in[0], d_in[2], d_in[3], d_in[6], d_in[7], egp, betp, nullptr, flagp);
    gemm_nt<false><<<dim3(CONV_DIM / 128, SEQ / 128), 256, 0, stream>>>(d_in[0], d_in[1], mixed, CONV_DIM, HIDDEN, flagp, 1, 1);
    conv_norm<<<dim3(SEQ, CONV_DIM / 256), 256, 0, stream>>>(mixed, d_in[5], qbuf, kbuf, vbuf, flagp);
    gemm_nt<false><<<dim3(VAL_DIM / 128, SEQ / 128), 256, 0, stream>>>(d_in[0], d_in[4], zbuf, VAL_DIM, HIDDEN, flagp, 1, 1);
    fused_scan<<<128, 256, 0, stream>>>(qbuf, kbuf, vbuf, egp, betp, corep,
                                        nullptr, nullptr, nullptr, nullptr, nullptr, flagp,
                                        128, 0);
    gate_norm<<<SEQ, 256, 0, stream>>>(corep, zbuf, d_in[8], gated, flagp);
    gemm_nt<true><<<dim3(HIDDEN / 128, SEQ / 128), 256, 0, stream>>>(gated, d_in[9], d_out, HIDDEN, VAL_DIM, flagp, 0, 1);
  }
}

// Round 4
// 503.169 us; speedup vs baseline: 1.3325x; 1.0567x over previous
//
#include <hip/hip_runtime.h>
#include <stdint.h>

// LinearAttention (gated delta rule), S=2048, HID=2048, H=16, DK=64, DV=128, conv K=4.
// r14: latency surgery on chunk_b. r13's chunk_b (117us) was latency-bound: 8772
// cyc/chunk vs ~1200 cyc of issued work (MfmaUtil 1.2%, VALUBusy 2.3%, Occ 1.4%).
// Exposed latencies on the 32-chunk serial chain: per-chunk gbuf global load in
// prefix(); prefetch issued after B2 (drain at next B1 only covered by ~500cyc);
// per-tile ds_read->MFMA interleave exposing LDS latency 4x.
// Fixes: (a) one-time prologue computes ALL chunk decay tables into LDS fSa/dSa
// [32][64] (no global loads on the chain); (b) prefetch issued right after B1 ->
// drained at B2 after the full mm2 window (~free); (c) all LDS fragment loads
// batched ahead of their MFMA clusters; Dl moved from C-init to pack-time add.

#define SEQ 2048
#define HIDDEN 2048
#define NH 16
#define DKv 64
#define DVv 128
#define KEY_DIM 1024
#define VAL_DIM 2048
#define CONV_DIM 4096

typedef __bf16 bf16;
typedef unsigned short u16;
typedef __attribute__((ext_vector_type(8))) __bf16 bf16x8;
typedef __attribute__((ext_vector_type(4))) __bf16 bf16x4;
typedef __attribute__((ext_vector_type(4))) float f32x4;

#define AS1 __attribute__((address_space(1)))
#define AS3 __attribute__((address_space(3)))
#define GLDS16(src, dst) __builtin_amdgcn_global_load_lds((AS1 const void*)(src), (AS3 void*)(dst), 16, 0, 0)

__device__ __forceinline__ float b2f(u16 u) {
  union { unsigned int i; float f; } c; c.i = ((unsigned int)u) << 16; return c.f;
}
__device__ __forceinline__ float sigmoidf_(float x) { return 1.0f / (1.0f + __expf(-x)); }

// ---------------------------------------------------------------- dtype detector
__global__ void detect_dtype(const u16* __restrict__ p, unsigned* __restrict__ flag) {
  int lane = threadIdx.x;  // 64 threads
  int cnt = 0;
  for (int w = lane; w < 2048; w += 64) {
    unsigned e = (p[2 * w] >> 7) & 0xFF;
    if (e < 64) cnt++;
  }
  cnt += __shfl_xor(cnt, 1);  cnt += __shfl_xor(cnt, 2);  cnt += __shfl_xor(cnt, 4);
  cnt += __shfl_xor(cnt, 8);  cnt += __shfl_xor(cnt, 16); cnt += __shfl_xor(cnt, 32);
  if (lane == 0) *flag = (cnt > 64) ? 1u : 0u;   // 1 = inputs are f32
}

// ---------------------------------------------------------------- f32 -> bf16 convert
__global__ __launch_bounds__(256)
void cvt_bf16(const void* __restrict__ src, bf16* __restrict__ dst, long n,
              const unsigned* __restrict__ flagp) {
  long i = ((long)blockIdx.x * 256 + threadIdx.x) * 8;
  if (i >= n) return;
  if (*flagp) {
    const f32x4* s = (const f32x4*)((const float*)src + i);
    f32x4 a = s[0], b = s[1];
    bf16x8 o;
#pragma unroll
    for (int j = 0; j < 4; ++j) { o[j] = (bf16)a[j]; o[4 + j] = (bf16)b[j]; }
    *(bf16x8*)(dst + i) = o;
  } else {
    *(bf16x8*)(dst + i) = *(const bf16x8*)((const bf16*)src + i);
  }
}

// ---------------------------------------------------------------- GEMM (NT) standalone
template<bool F32OUT>
__global__ __launch_bounds__(256, 2)
void gemm_nt(const void* __restrict__ Araw, const void* __restrict__ Braw,
             void* __restrict__ Cv, int N, int K,
             const unsigned* __restrict__ flagp, int useA, int useB) {
  __shared__ __align__(16) bf16 As[128 * 32];
  __shared__ __align__(16) bf16 Bs[128 * 32];
  const bool f32g = (*flagp != 0);
  const bool fA = useA && f32g;
  const bool fB = useB && f32g;
  const int tid  = threadIdx.x;
  const int lane = tid & 63;
  const int wv   = tid >> 6;
  const int wm   = (wv & 1) << 6;
  const int wn   = (wv >> 1) << 6;
  const long bm  = (long)blockIdx.y * 128;
  const long bn  = (long)blockIdx.x * 128;

  f32x4 acc[4][4] = {};

  for (int k0 = 0; k0 < K; k0 += 32) {
#pragma unroll
    for (int it = 0; it < 2; ++it) {
      int e   = (it * 256 + tid) * 8;
      int row = e >> 5;
      int col = e & 31;
      long offA = (bm + row) * (long)K + (k0 + col);
      long offB = (bn + row) * (long)K + (k0 + col);
      if (fA) {
        const float* g = (const float*)Araw + offA;
        f32x4 u0 = *(const f32x4*)g, u1 = *(const f32x4*)(g + 4);
        bf16x8 bv;
#pragma unroll
        for (int j = 0; j < 4; ++j) { bv[j] = (bf16)u0[j]; bv[4 + j] = (bf16)u1[j]; }
        *(bf16x8*)&As[e] = bv;
      } else {
        const bf16* g = (const bf16*)Araw + offA;
        GLDS16(g, &As[e]);
      }
      if (fB) {
        const float* g = (const float*)Braw + offB;
        f32x4 u0 = *(const f32x4*)g, u1 = *(const f32x4*)(g + 4);
        bf16x8 bv;
#pragma unroll
        for (int j = 0; j < 4; ++j) { bv[j] = (bf16)u0[j]; bv[4 + j] = (bf16)u1[j]; }
        *(bf16x8*)&Bs[e] = bv;
      } else {
        const bf16* g = (const bf16*)Braw + offB;
        GLDS16(g, &Bs[e]);
      }
    }
    __syncthreads();

    const bf16x8* As8 = (const bf16x8*)As;
    const bf16x8* Bs8 = (const bf16x8*)Bs;
    const int r = lane & 15, q = lane >> 4;
    bf16x8 af[4], bfr[4];
#pragma unroll
    for (int i = 0; i < 4; ++i) af[i]  = As8[(wm + i * 16 + r) * 4 + q];
#pragma unroll
    for (int j = 0; j < 4; ++j) bfr[j] = Bs8[(wn + j * 16 + r) * 4 + q];
#pragma unroll
    for (int i = 0; i < 4; ++i)
#pragma unroll
      for (int j = 0; j < 4; ++j)
        acc[i][j] = __builtin_amdgcn_mfma_f32_16x16x32_bf16(af[i], bfr[j], acc[i][j], 0, 0, 0);
    __syncthreads();
  }

  const int r = lane & 15, q = lane >> 4;
#pragma unroll
  for (int i = 0; i < 4; ++i)
#pragma unroll
    for (int j = 0; j < 4; ++j) {
      long row = bm + wm + i * 16 + q * 4;
      long col = bn + wn + j * 16 + r;
#pragma unroll
      for (int rr = 0; rr < 4; ++rr) {
        if constexpr (F32OUT) ((float*)Cv)[(row + rr) * N + col] = acc[i][j][rr];
        else                  ((bf16*)Cv)[(row + rr) * N + col] = (bf16)acc[i][j][rr];
      }
    }
}

// ---------------------------------------------------------------- GEMM body (bf16-only, fused)
__device__ void gemm_body_bf16(char* smemc, const bf16* __restrict__ A,
                               const bf16* __restrict__ B, bf16* __restrict__ C,
                               int N, int K, int bx, int by, int tid) {
  bf16* As = (bf16*)smemc;             // 8 KiB
  bf16* Bs = (bf16*)(smemc + 8192);    // 8 KiB
  const int lane = tid & 63;
  const int wv = tid >> 6, wm = (wv & 1) << 6, wn = (wv >> 1) << 6;
  const long bm = (long)by * 128, bn = (long)bx * 128;
  f32x4 acc[4][4] = {};
  for (int k0 = 0; k0 < K; k0 += 32) {
#pragma unroll
    for (int it = 0; it < 2; ++it) {
      int e = (it * 256 + tid) * 8;
      int row = e >> 5, col = e & 31;
      const bf16* gA = A + (bm + row) * (long)K + k0 + col;
      const bf16* gB = B + (bn + row) * (long)K + k0 + col;
      GLDS16(gA, &As[e]);
      GLDS16(gB, &Bs[e]);
    }
    __syncthreads();
    const bf16x8* As8 = (const bf16x8*)As;
    const bf16x8* Bs8 = (const bf16x8*)Bs;
    const int r = lane & 15, q = lane >> 4;
    bf16x8 af[4], bfr[4];
#pragma unroll
    for (int i = 0; i < 4; ++i) af[i]  = As8[(wm + i * 16 + r) * 4 + q];
#pragma unroll
    for (int j = 0; j < 4; ++j) bfr[j] = Bs8[(wn + j * 16 + r) * 4 + q];
#pragma unroll
    for (int i = 0; i < 4; ++i)
#pragma unroll
      for (int j = 0; j < 4; ++j)
        acc[i][j] = __builtin_amdgcn_mfma_f32_16x16x32_bf16(af[i], bfr[j], acc[i][j], 0, 0, 0);
    __syncthreads();
  }
  const int r = lane & 15, q = lane >> 4;
#pragma unroll
  for (int i = 0; i < 4; ++i)
#pragma unroll
    for (int j = 0; j < 4; ++j) {
      long row = bm + wm + i * 16 + q * 4;
      long col = bn + wn + j * 16 + r;
#pragma unroll
      for (int rr = 0; rr < 4; ++rr)
        C[(row + rr) * (long)N + col] = (bf16)acc[i][j][rr];
    }
}

// ---------------------------------------------------------------- a/b proj -> exp(g), g, beta
__global__ __launch_bounds__(256)
void proj_ab(const void* __restrict__ hsr, const void* __restrict__ War,
             const void* __restrict__ Wbr, const void* __restrict__ A_logr,
             const void* __restrict__ dtbr,
             float* __restrict__ eg, float* __restrict__ bet,
             float* __restrict__ gb,
             const unsigned* __restrict__ flagp) {
  const bool f32g = (*flagp != 0);
  const int s = blockIdx.x;
  const int t = threadIdx.x;
  const int o = t & 31;
  const int part = t >> 5;
  const int h = o & 15;
  const int kbeg = part * 256;
  float a0 = 0.f, a1 = 0.f;
  if (f32g) {
    const f32x4* x4 = (const f32x4*)((const float*)hsr + (long)s * HIDDEN + kbeg);
    const f32x4* w4 = (const f32x4*)((const float*)((o < 16) ? War : Wbr) + (long)h * HIDDEN + kbeg);
#pragma unroll 8
    for (int k4 = 0; k4 < 64; ++k4) {
      f32x4 xv = x4[k4], wv = w4[k4];
      a0 += xv[0] * wv[0] + xv[1] * wv[1];
      a1 += xv[2] * wv[2] + xv[3] * wv[3];
    }
  } else {
    const bf16x8* x8 = (const bf16x8*)((const bf16*)hsr + (long)s * HIDDEN + kbeg);
    const bf16x8* w8 = (const bf16x8*)((const bf16*)((o < 16) ? War : Wbr) + (long)h * HIDDEN + kbeg);
#pragma unroll 8
    for (int k8 = 0; k8 < 32; ++k8) {
      bf16x8 xv = x8[k8], wv = w8[k8];
#pragma unroll
      for (int j = 0; j < 4; ++j) a0 += (float)xv[j] * (float)wv[j];
#pragma unroll
      for (int j = 4; j < 8; ++j) a1 += (float)xv[j] * (float)wv[j];
    }
  }
  __shared__ float red[256];
  red[t] = a0 + a1;
  __syncthreads();
  if (t < 32) {
    float a = 0.f;
#pragma unroll
    for (int p = 0; p < 8; ++p) a += red[t + p * 32];
    const int hh = t & 15;
    if (t < 16) {
      float alog = f32g ? ((const float*)A_logr)[hh] : b2f(((const u16*)A_logr)[hh]);
      float dtb  = f32g ? ((const float*)dtbr)[hh]   : b2f(((const u16*)dtbr)[hh]);
      float xx = a + dtb;
      float sp = fmaxf(xx, 0.f) + log1pf(__expf(-fabsf(xx)));   // stable softplus
      float gg = -__expf(alog) * sp;                             // log-decay
      if (gb) gb[(long)s * NH + hh] = gg;
      eg[(long)s * NH + hh] = __expf(gg);
    } else {
      bet[(long)s * NH + hh] = sigmoidf_(a);
    }
  }
}

// ---------------------------------------------------------------- conv + SiLU + l2norm
__global__ __launch_bounds__(256)
void conv_norm(const bf16* __restrict__ mixed, const void* __restrict__ convwr,
               bf16* __restrict__ qbuf, bf16* __restrict__ kbuf, bf16* __restrict__ vbuf,
               const unsigned* __restrict__ flagp) {
  const bool f32g = (*flagp != 0);
  const int s = blockIdx.x;
  const int c = blockIdx.y * 256 + threadIdx.x;
  float w0, w1, w2, w3;
  if (f32g) {
    const float* wp = (const float*)convwr + (long)c * 4;
    w0 = wp[0]; w1 = wp[1]; w2 = wp[2]; w3 = wp[3];
  } else {
    const u16* wp = (const u16*)convwr + (long)c * 4;
    w0 = b2f(wp[0]); w1 = b2f(wp[1]); w2 = b2f(wp[2]); w3 = b2f(wp[3]);
  }
  float acc = w3 * (float)mixed[(long)s * CONV_DIM + c];
  if (s >= 1) acc += w2 * (float)mixed[(long)(s - 1) * CONV_DIM + c];
  if (s >= 2) acc += w1 * (float)mixed[(long)(s - 2) * CONV_DIM + c];
  if (s >= 3) acc += w0 * (float)mixed[(long)(s - 3) * CONV_DIM + c];
  float y = acc * sigmoidf_(acc);  // SiLU
  if (c < 2 * KEY_DIM) {
    float ss = y * y;
    ss += __shfl_xor(ss, 1);  ss += __shfl_xor(ss, 2);  ss += __shfl_xor(ss, 4);
    ss += __shfl_xor(ss, 8);  ss += __shfl_xor(ss, 16); ss += __shfl_xor(ss, 32);
    float scale = rsqrtf(ss + 1e-6f);
    if (c < KEY_DIM) scale *= 0.125f;
    y *= scale;
  }
  if (c < KEY_DIM)            qbuf[(long)s * KEY_DIM + c] = (bf16)y;
  else if (c < 2 * KEY_DIM)   kbuf[(long)s * KEY_DIM + (c - KEY_DIM)] = (bf16)y;
  else                        vbuf[(long)s * VAL_DIM + (c - 2 * KEY_DIM)] = (bf16)y;
}

// ---------------------------------------------------------------- DPP 16-lane sum (fallback scan)
template<int CTRL>
__device__ __forceinline__ float dpp_add(float x) {
  int y = __builtin_amdgcn_update_dpp(0, __float_as_int(x), CTRL, 0xF, 0xF, true);
  return x + __int_as_float(y);
}
__device__ __forceinline__ float dpp_sum16(float x) {
  x = dpp_add<0xB1>(x);   // quad_perm xor1
  x = dpp_add<0x4E>(x);   // quad_perm xor2
  x = dpp_add<0x141>(x);  // row_half_mirror (xor4)
  x = dpp_add<0x140>(x);  // row_mirror (xor8)
  return x;
}

// ---------------------------------------------------------------- fused per-step scan (FALLBACK path only)
__global__ __launch_bounds__(256, 2)
void fused_scan(const bf16* __restrict__ qbuf, const bf16* __restrict__ kbuf,
                const bf16* __restrict__ vbuf, const float* __restrict__ eg,
                const float* __restrict__ bet, bf16* __restrict__ core,
                const bf16* __restrict__ hsb, const bf16* __restrict__ wzb,
                bf16* __restrict__ zbuf, const void* __restrict__ woutr,
                bf16* __restrict__ woutb, const unsigned* __restrict__ flagp,
                int nScan, int nGemm) {
  __shared__ __align__(16) char smem[16384];
  const int t = threadIdx.x;
  const int b = blockIdx.x;

  if (b < nScan) {
    const int h  = b >> 3;
    const int vg = (b & 7) * 16;
    const int g  = t >> 4;
    const int L  = t & 15;
    bf16*  kqs = (bf16*)smem;               // [2][2048] elems
    bf16*  vts = (bf16*)(smem + 8192);      // [2][256] elems
    float* ets = (float*)(smem + 9216);     // [2][16]
    float* bts = (float*)(smem + 9344);     // [2][16]

#define STAGE(buf, s0)                                                          \
    {                                                                           \
      int byte = t * 16;                                                        \
      const bf16* src;                                                          \
      if (byte < 2048) {                                                        \
        int row = byte >> 7, el = (byte & 127) >> 1;                            \
        src = kbuf + (long)((s0) + row) * KEY_DIM + h * DKv + el;               \
      } else {                                                                  \
        int b2 = byte - 2048;                                                   \
        int row = b2 >> 7, el = (b2 & 127) >> 1;                                \
        src = qbuf + (long)((s0) + row) * KEY_DIM + h * DKv + el;               \
      }                                                                         \
      GLDS16(src, smem + (buf) * 4096 + byte);                                  \
      if (t < 32) {                                                             \
        int row = t >> 1, el = (t & 1) * 8;                                     \
        const bf16* vsrc = vbuf + (long)((s0) + row) * VAL_DIM + h * DVv + vg + el; \
        GLDS16(vsrc, smem + 8192 + (buf) * 512 + t * 16);                       \
      }                                                                         \
    }

    float er = 0.f, br = 0.f;
    if (t < 16)      er = eg[(long)t * NH + h];
    else if (t < 32) br = bet[(long)(t - 16) * NH + h];
    STAGE(0, 0);
    if (t < 16)      ets[t] = er;
    else if (t < 32) bts[t - 16] = br;
    __syncthreads();

    float S0 = 0.f, S1 = 0.f, S2 = 0.f, S3 = 0.f;
    for (int tile = 0; tile < 128; ++tile) {
      const int buf = tile & 1, nb = buf ^ 1;
      if (tile < 127) {
        STAGE(nb, (tile + 1) * 16);
        if (t < 16)      er = eg[(long)((tile + 1) * 16 + t) * NH + h];
        else if (t < 32) br = bet[(long)((tile + 1) * 16 + (t - 16)) * NH + h];
      }
      const bf16*  ktb = kqs + buf * 2048;
      const bf16*  qtb = ktb + 1024;
      const bf16*  vtb = vts + buf * 256;
      const float* etb = ets + buf * 16;
      const float* btb = bts + buf * 16;
      const long sbase = (long)tile * 16;

      bf16x4 kR[2], qR[2];
      float  vR[2], eR[2], bR[2];
      kR[0] = *(const bf16x4*)(ktb + 0 * 64 + L * 4);
      qR[0] = *(const bf16x4*)(qtb + 0 * 64 + L * 4);
      vR[0] = (float)vtb[0 * 16 + g];  eR[0] = etb[0];  bR[0] = btb[0];
      kR[1] = *(const bf16x4*)(ktb + 1 * 64 + L * 4);
      qR[1] = *(const bf16x4*)(qtb + 1 * 64 + L * 4);
      vR[1] = (float)vtb[1 * 16 + g];  eR[1] = etb[1];  bR[1] = btb[1];
#pragma unroll
      for (int s = 0; s < 16; ++s) {
        const int sl = s & 1;
        bf16x4 kk = kR[sl], qq = qR[sl];
        float vv = vR[sl], ee = eR[sl], bb = bR[sl];
        if (s < 14) {
          const int s2 = s + 2;
          kR[sl] = *(const bf16x4*)(ktb + s2 * 64 + L * 4);
          qR[sl] = *(const bf16x4*)(qtb + s2 * 64 + L * 4);
          vR[sl] = (float)vtb[s2 * 16 + g];
          eR[sl] = etb[s2];  bR[sl] = btb[s2];
        }
        float ebt = ee * bb, vbt = vv * bb;
        float k0 = (float)kk[0], k1 = (float)kk[1], k2 = (float)kk[2], k3 = (float)kk[3];
        float D0 = S0 * ee, D1 = S1 * ee, D2 = S2 * ee, D3 = S3 * ee;
        float p = (k0 * S0 + k1 * S1) + (k2 * S2 + k3 * S3);
        p = dpp_sum16(p);
        float delta = vbt - ebt * p;
        S0 = fmaf(k0, delta, D0); S1 = fmaf(k1, delta, D1);
        S2 = fmaf(k2, delta, D2); S3 = fmaf(k3, delta, D3);
        float q0 = (float)qq[0], q1 = (float)qq[1], q2 = (float)qq[2], q3 = (float)qq[3];
        float o = (q0 * S0 + q1 * S1) + (q2 * S2 + q3 * S3);
        o = dpp_sum16(o);
        if (L == 0) core[(sbase + s) * VAL_DIM + h * DVv + vg + g] = (bf16)o;
      }
      if (tile < 127) {
        if (t < 16)      ets[nb * 16 + t] = er;
        else if (t < 32) bts[nb * 16 + (t - 16)] = br;
      }
      __syncthreads();
    }
#undef STAGE
  } else if (b < nScan + nGemm) {
    int gb = b - nScan;
    gemm_body_bf16(smem, hsb, wzb, zbuf, VAL_DIM, HIDDEN, gb & 15, gb >> 4, t);
  } else {
    long i = ((long)(b - nScan - nGemm) * 256 + t) * 8;
    if (i < (long)HIDDEN * VAL_DIM) {
      if (*flagp) {
        const f32x4* s = (const f32x4*)((const float*)woutr + i);
        f32x4 a = s[0], c = s[1];
        bf16x8 o;
#pragma unroll
        for (int j = 0; j < 4; ++j) { o[j] = (bf16)a[j]; o[4 + j] = (bf16)c[j]; }
        *(bf16x8*)(woutb + i) = o;
      } else {
        *(bf16x8*)(woutb + i) = *(const bf16x8*)((const bf16*)woutr + i);
      }
    }
  }
}

// ================================================================ CHUNKED DELTA RULE
// chunk length 64, 32 chunks, 16 heads. Per chunk-head (c,h):
//   cum_t = prefix-sum of g; d_t = e^{cum_t}
//   A[t][i] = beta_t e^{cum_t-cum_i} (k_t.k_i), strictly lower
//   [Dloc | W] = (I+A)^{-1} [diag(beta)V | diag(beta*d)K]
//   delta = Dloc - W S0;  S' = e^{cumC} S0 + K'^T delta, K'[i]=e^{cumC-cum_i}k_i
//   O = diag(d) Q S0 + (Minc o Q K^T) delta
// dloc[(c,h)][t][v] bf16 (d_out+8M); negW hi/lo [t][k] bf16 (ws+24M,+28M);
// dTg[(c,h)][v][t] bf16 (ws+0); o1g[(c,h)][v][t] bf16 pre-scaled by d_t (ws+8M).

// ---------------------------------------------------------------- phase A (+ fused zgemm + woutcvt)
__global__ __launch_bounds__(256, 2)
void chunk_a(const bf16* __restrict__ kbuf, const bf16* __restrict__ vbuf,
             const float* __restrict__ gbuf, const float* __restrict__ betp,
             bf16* __restrict__ dloc, bf16* __restrict__ whig, bf16* __restrict__ wlog,
             const bf16* __restrict__ hsb, const bf16* __restrict__ wzb,
             bf16* __restrict__ zbuf, const void* __restrict__ woutr,
             bf16* __restrict__ woutb, const unsigned* __restrict__ flagp) {
  __shared__ __align__(16) char smem[25600];
  const int t = threadIdx.x;
  const int b = blockIdx.x;
  if (b < 512) {
    const int c = b >> 4, h = b & 15;
    bf16*  Ks   = (bf16*)smem;                 // [64][64] 8192 B
    float* At   = (float*)(smem + 8192);       // [64][64] 16384 B, At[i][t] = A[t][i]
    float* cumS = (float*)(smem + 24576);      // 64
    float* bS   = (float*)(smem + 24832);      // 64
    float* dS   = (float*)(smem + 25088);      // 64
    // stage K chunk -> LDS (linear)
#pragma unroll
    for (int it = 0; it < 2; ++it) {
      int byte = (it * 256 + t) * 16;
      int row = byte >> 7, col = (byte & 127) >> 1;
      const bf16* src = kbuf + (long)(c * 64 + row) * KEY_DIM + h * DKv + col;
      GLDS16(src, smem + byte);
    }
    if (t < 64) {  // wave 0: within-chunk prefix sum of log-decay
      float cc = gbuf[(long)(c * 64 + t) * NH + h];
#pragma unroll
      for (int d = 1; d < 64; d <<= 1) { float y = __shfl_up(cc, d); if (t >= d) cc += y; }
      cumS[t] = cc;
      dS[t] = __expf(cc);
      bS[t] = betp[(long)(c * 64 + t) * NH + h];
    }
    {  // zero At (upper+diag must read as 0 in the quad-vectorized substitution)
      f32x4 z = {0.f, 0.f, 0.f, 0.f};
#pragma unroll
      for (int i = 0; i < 4; ++i) ((f32x4*)At)[t * 4 + i] = z;
    }
    __syncthreads();
    // G = K K^T via MFMA; masked+scaled, stored transposed into At
    {
      const int lane = t & 63, wv = t >> 6;
      const int r = lane & 15, q = lane >> 4;
      const bf16x8* Ks8 = (const bf16x8*)Ks;
#pragma unroll
      for (int n = 0; n < 4; ++n) {
        f32x4 acc = {0.f, 0.f, 0.f, 0.f};
#pragma unroll
        for (int kk = 0; kk < 2; ++kk) {
          bf16x8 af  = Ks8[(wv * 16 + r) * 8 + kk * 4 + q];
          bf16x8 bfv = Ks8[(n  * 16 + r) * 8 + kk * 4 + q];
          acc = __builtin_amdgcn_mfma_f32_16x16x32_bf16(af, bfv, acc, 0, 0, 0);
        }
        const int i = n * 16 + r;
#pragma unroll
        for (int rr = 0; rr < 4; ++rr) {
          const int tr = wv * 16 + q * 4 + rr;
          if (i < tr)
            At[i * 64 + tr] = bS[tr] * __expf(cumS[tr] - cumS[i]) * acc[rr];
        }
      }
    }
    __syncthreads();
    // column-parallel forward substitution: x = (I+A)^{-1} r, one column per thread
    if (t < 192) {
      float x[64];
      const long base = ((long)(c * 16 + h)) * 64;
      if (t < 128) {
#pragma unroll
        for (int s = 0; s < 64; ++s)
          x[s] = bS[s] * (float)vbuf[(long)(c * 64 + s) * VAL_DIM + h * DVv + t];
      } else {
        const int k = t - 128;
#pragma unroll
        for (int s = 0; s < 64; ++s)
          x[s] = bS[s] * dS[s] * (float)Ks[s * 64 + k];
      }
#pragma unroll
      for (int s = 0; s < 64; ++s) {
        const float val = x[s];
        const f32x4* row4 = (const f32x4*)(At + s * 64);
#pragma unroll
        for (int qd = (s >> 2); qd < 16; ++qd) {
          f32x4 a4 = row4[qd];
          x[qd * 4 + 0] = fmaf(-a4[0], val, x[qd * 4 + 0]);
          x[qd * 4 + 1] = fmaf(-a4[1], val, x[qd * 4 + 1]);
          x[qd * 4 + 2] = fmaf(-a4[2], val, x[qd * 4 + 2]);
          x[qd * 4 + 3] = fmaf(-a4[3], val, x[qd * 4 + 3]);
        }
      }
      if (t < 128) {          // Dloc column t  -> dloc[t][v] rows (bf16)
#pragma unroll
        for (int s = 0; s < 64; ++s)
          dloc[(base + s) * 128 + t] = (bf16)x[s];
      } else {                // W column k -> negW hi/lo [t][k] (coalesced per-s across wave)
        const int k = t - 128;
        const long wb = base * 64;   // = (c*16+h)*4096
#pragma unroll
        for (int s = 0; s < 64; ++s) {
          float v = -x[s];
          bf16 hh = (bf16)v;
          whig[wb + s * 64 + k] = hh;
          wlog[wb + s * 64 + k] = (bf16)(v - (float)hh);
        }
      }
    }
  } else if (b < 768) {
    int gb = b - 512;
    gemm_body_bf16(smem, hsb, wzb, zbuf, VAL_DIM, HIDDEN, gb & 15, gb >> 4, t);
  } else {
    long i = ((long)(b - 768) * 256 + t) * 8;
    if (i < (long)HIDDEN * VAL_DIM) {
      if (*flagp) {
        const f32x4* s = (const f32x4*)((const float*)woutr + i);
        f32x4 a = s[0], cc = s[1];
        bf16x8 o;
#pragma unroll
        for (int j = 0; j < 4; ++j) { o[j] = (bf16)a[j]; o[4 + j] = (bf16)cc[j]; }
        *(bf16x8*)(woutb + i) = o;
      } else {
        *(bf16x8*)(woutb + i) = *(const bf16x8*)((const bf16*)woutr + i);
      }
    }
  }
}

// ---------------------------------------------------------------- phase B: MFMA chunk-serial recurrence
// grid 32 = h*2 + vhalf (64 v per block). State: persistent f32 accregs (wave w owns
// v-rows w*16..w*16+15); bf16 hi/lo copies in LDS (X8 swizzle) feed MFMA B-operands.
// r14 latency schedule per chunk:
//   B1 -> issue prefetch (drained at B2 after full mm2 window) -> KT build ->
//   batched frag loads -> 40 MFMA -> pack/stores -> B2 -> batched S-update.
// Decay tables for ALL chunks precomputed once into LDS (no global loads on chain).
__global__ __launch_bounds__(256, 1)
void chunk_b(const bf16* __restrict__ qbuf, const bf16* __restrict__ kbuf,
             const float* __restrict__ gbuf, const bf16* __restrict__ dloc,
             const bf16* __restrict__ whig, const bf16* __restrict__ wlog,
             bf16* __restrict__ dTg, bf16* __restrict__ o1g) {
  __shared__ __align__(16) char smem[139264];
  bf16* Wh  = (bf16*)(smem);             // [2][64][64] swz
  bf16* Wl  = (bf16*)(smem + 16384);     // [2][64][64] swz
  bf16* Qs  = (bf16*)(smem + 32768);     // [2][64][64] swz
  bf16* Ks  = (bf16*)(smem + 49152);     // [2][64][64] linear
  bf16* Dls = (bf16*)(smem + 65536);     // [2][64][64] swz
  bf16* KT  = (bf16*)(smem + 81920);     // [64][64] swz (K^T)
  bf16* Shi = (bf16*)(smem + 90112);     // [64][64] swz
  bf16* Slo = (bf16*)(smem + 98304);     // [64][64] swz
  bf16* Dth = (bf16*)(smem + 106496);    // [64][64] swz (fS-scaled deltaT hi)
  bf16* Dtl = (bf16*)(smem + 114688);    // [64][64] swz (lo)
  float* fSa = (float*)(smem + 122880);  // [32][64] e^{cumC-cum_t}
  float* dSa = (float*)(smem + 131072);  // [32][64] e^{cum_t}

  const int t = threadIdx.x;
  const int h = blockIdx.x >> 1, vhalf = blockIdx.x & 1;
  const int lane = t & 63, w = t >> 6;
  const int r = lane & 15, q = lane >> 4;
  const int tb = w * 16 + q * 4;         // this lane's C-row base (t or v dim)

  auto stage = [&](int bb, int cc) {
    const long c16h = (long)(cc * 16 + h);
#pragma unroll
    for (int it = 0; it < 2; ++it) {
      int p = it * 256 + t;              // 16B-group id, 0..511
      int row = p >> 3, g = p & 7;
      int sg = ((g ^ (row & 7)) << 3);   // pre-swizzled source column
      GLDS16(whig + c16h * 4096 + row * 64 + sg, (char*)Wh + bb * 8192 + p * 16);
      GLDS16(wlog + c16h * 4096 + row * 64 + sg, (char*)Wl + bb * 8192 + p * 16);
      GLDS16(qbuf + (long)(cc * 64 + row) * KEY_DIM + h * DKv + sg, (char*)Qs + bb * 8192 + p * 16);
      GLDS16(kbuf + (long)(cc * 64 + row) * KEY_DIM + h * DKv + (g << 3), (char*)Ks + bb * 8192 + p * 16);
      GLDS16(dloc + (c16h * 64 + row) * 128 + vhalf * 64 + sg, (char*)Dls + bb * 8192 + p * 16);
    }
  };

  // prologue: one-time decay tables for ALL 32 chunks (wave w -> chunks w*8..w*8+7)
  {
    float g8[8];
#pragma unroll
    for (int i = 0; i < 8; ++i)
      g8[i] = gbuf[(long)((w * 8 + i) * 64 + lane) * NH + h];
#pragma unroll
    for (int i = 0; i < 8; ++i) {
      float cs = g8[i];
#pragma unroll
      for (int d = 1; d < 64; d <<= 1) { float y = __shfl_up(cs, d); if (lane >= d) cs += y; }
      float tot = __shfl(cs, 63);
      fSa[(w * 8 + i) * 64 + lane] = __expf(tot - cs);
      dSa[(w * 8 + i) * 64 + lane] = __expf(cs);
    }
  }
  {
    f32x4 z = {0.f, 0.f, 0.f, 0.f};
    ((f32x4*)Shi)[t] = z; ((f32x4*)Shi)[t + 256] = z;
    ((f32x4*)Slo)[t] = z; ((f32x4*)Slo)[t + 256] = z;
  }
  stage(0, 0);
  f32x4 Sacc[4] = {};   // k-tiles n=0..3 for this wave's v-rows

  for (int c = 0; c < 32; ++c) {
    const int buf = c & 1, nb = buf ^ 1;
    __syncthreads();   // B1: stage[buf] drained; prev chunk's S hi/lo visible
    if (c < 31) stage(nb, c + 1);   // prefetch EARLY: drained at B2 after mm2 window
    const bf16* wh = Wh + buf * 4096;
    const bf16* wl = Wl + buf * 4096;
    const bf16* qs = Qs + buf * 4096;
    const bf16* ks = Ks + buf * 4096;
    const bf16* dl = Dls + buf * 4096;
    const float* fS = fSa + c * 64;
    const float* dS = dSa + c * 64;
    const long gch = (long)(c * 16 + h) * 8192 + (long)(vhalf * 64) * 64;

    // K^T build (swizzled): lane k, rows i = w*16..w*16+15 (update-only)
    if (c < 31) {
      const int k = lane;
#pragma unroll
      for (int ii = 0; ii < 16; ++ii) {
        const int i = w * 16 + ii;
        const int pg = (i >> 3) ^ (k & 7);
        KT[k * 64 + pg * 8 + (i & 7)] = ks[i * 64 + k];
      }
    }

    // hoisted decay factors for this lane's 4 t-rows (from LDS tables)
    float fs4[4], ds4[4];
#pragma unroll
    for (int rr = 0; rr < 4; ++rr) { fs4[rr] = fS[tb + rr]; ds4[rr] = dS[tb + rr]; }

    // ---- batched fragment loads (all ds_reads in flight before MFMA) ----
    bf16x8 wahi[2], walo[2], qa[2];
#pragma unroll
    for (int kk = 0; kk < 2; ++kk) {
      const int row = w * 16 + r;
      const int g = (kk * 4 + q) ^ (row & 7);
      wahi[kk] = *(const bf16x8*)(wh + row * 64 + g * 8);
      walo[kk] = *(const bf16x8*)(wl + row * 64 + g * 8);
      qa[kk]   = *(const bf16x8*)(qs + row * 64 + g * 8);
    }
    bf16x8 sh[4][2], sl[4][2];
#pragma unroll
    for (int n = 0; n < 4; ++n)
#pragma unroll
      for (int kk = 0; kk < 2; ++kk) {
        const int vrow = n * 16 + r;
        const int g = (kk * 4 + q) ^ (vrow & 7);
        sh[n][kk] = *(const bf16x8*)(Shi + vrow * 64 + g * 8);
        sl[n][kk] = *(const bf16x8*)(Slo + vrow * 64 + g * 8);
      }
    float dl4[4][4];
#pragma unroll
    for (int n = 0; n < 4; ++n)
#pragma unroll
      for (int rr = 0; rr < 4; ++rr) {
        const int vrow = n * 16 + r, trow = tb + rr;
        const int pg = (vrow >> 3) ^ (trow & 7);
        dl4[n][rr] = (float)dl[trow * 64 + pg * 8 + (vrow & 7)];
      }

    // ---- 40 MFMA, 4 independent chains ----
    f32x4 da[4] = {}, oa[4] = {};
#pragma unroll
    for (int n = 0; n < 4; ++n)
#pragma unroll
      for (int kk = 0; kk < 2; ++kk) {
        da[n] = __builtin_amdgcn_mfma_f32_16x16x32_bf16(wahi[kk], sh[n][kk], da[n], 0, 0, 0);
        da[n] = __builtin_amdgcn_mfma_f32_16x16x32_bf16(wahi[kk], sl[n][kk], da[n], 0, 0, 0);
        da[n] = __builtin_amdgcn_mfma_f32_16x16x32_bf16(walo[kk], sh[n][kk], da[n], 0, 0, 0);
        oa[n] = __builtin_amdgcn_mfma_f32_16x16x32_bf16(qa[kk],   sh[n][kk], oa[n], 0, 0, 0);
        oa[n] = __builtin_amdgcn_mfma_f32_16x16x32_bf16(qa[kk],   sl[n][kk], oa[n], 0, 0, 0);
      }

    // ---- pack + stores (Dl added here instead of C-init: same sum) ----
#pragma unroll
    for (int n = 0; n < 4; ++n) {
      const int vrow = n * 16 + r;
      bf16x4 dpk, opk, fhk, flk;
#pragma unroll
      for (int rr = 0; rr < 4; ++rr) {
        float dv = dl4[n][rr] + da[n][rr];
        dpk[rr] = (bf16)dv;
        float p = fs4[rr] * dv;
        bf16 ph = (bf16)p;
        fhk[rr] = ph;
        flk[rr] = (bf16)(p - (float)ph);
        opk[rr] = (bf16)(ds4[rr] * oa[n][rr]);
      }
      *(bf16x4*)(dTg + gch + (long)vrow * 64 + tb) = dpk;
      *(bf16x4*)(o1g + gch + (long)vrow * 64 + tb) = opk;
      const int pg = (tb >> 3) ^ (vrow & 7);
      *(bf16x4*)(Dth + vrow * 64 + pg * 8 + (tb & 7)) = fhk;
      *(bf16x4*)(Dtl + vrow * 64 + pg * 8 + (tb & 7)) = flk;
    }

    __syncthreads();   // B2: DltT + KT visible; prefetch DMA drained (hidden by mm2)
    if (c < 31) {
      // update: S' = dC*S + DltT(hi/lo) x KT   [wave w owns v-rows w*16..+15]
      const float dC = dS[63];
      bf16x8 dh[2], dlo2[2], ktf[4][2];
#pragma unroll
      for (int kk = 0; kk < 2; ++kk) {
        const int vrow = w * 16 + r;
        const int g = (kk * 4 + q) ^ (vrow & 7);
        dh[kk]   = *(const bf16x8*)(Dth + vrow * 64 + g * 8);
        dlo2[kk] = *(const bf16x8*)(Dtl + vrow * 64 + g * 8);
      }
#pragma unroll
      for (int n = 0; n < 4; ++n)
#pragma unroll
        for (int kk = 0; kk < 2; ++kk) {
          const int krow = n * 16 + r;
          const int g = (kk * 4 + q) ^ (krow & 7);
          ktf[n][kk] = *(const bf16x8*)(KT + krow * 64 + g * 8);
        }
#pragma unroll
      for (int n = 0; n < 4; ++n) {
        f32x4 sa;
#pragma unroll
        for (int rr = 0; rr < 4; ++rr) sa[rr] = dC * Sacc[n][rr];
#pragma unroll
        for (int kk = 0; kk < 2; ++kk) {
          sa = __builtin_amdgcn_mfma_f32_16x16x32_bf16(dh[kk],   ktf[n][kk], sa, 0, 0, 0);
          sa = __builtin_amdgcn_mfma_f32_16x16x32_bf16(dlo2[kk], ktf[n][kk], sa, 0, 0, 0);
        }
        Sacc[n] = sa;
        // write S hi/lo (swizzled scalar stores): elems (v = tb+rr, k = n*16+r)
        const int k = n * 16 + r;
#pragma unroll
        for (int rr = 0; rr < 4; ++rr) {
          const int v = tb + rr;
          float s = sa[rr];
          bf16 hh = (bf16)s;
          const int pg = (k >> 3) ^ (v & 7);
          Shi[v * 64 + pg * 8 + (k & 7)] = hh;
          Slo[v * 64 + pg * 8 + (k & 7)] = (bf16)(s - (float)hh);
        }
      }
    }
  }
}

// ---------------------------------------------------------------- phase C: outputs, MFMA
// grid 512 = c*16 + h.  O[t][v] = o1[v][t] + sum_i P[t][i] delta^T[v][i]
__global__ __launch_bounds__(256, 2)
void chunk_c(const bf16* __restrict__ qbuf, const bf16* __restrict__ kbuf,
             const float* __restrict__ gbuf, const bf16* __restrict__ dTg,
             const bf16* __restrict__ o1g, bf16* __restrict__ core) {
  // Qs@0 8K | Ks@8192 8K | Pl@16384 8K | dT@24576 16K | o1l@40960 16K | cum@57344
  __shared__ __align__(16) char smem[57600];
  const int t = threadIdx.x;
  const int c = blockIdx.x >> 4, h = blockIdx.x & 15;
  const long c16h = (long)(c * 16 + h);
  bf16* Qs  = (bf16*)smem;
  bf16* Ksl = (bf16*)(smem + 8192);
  bf16* Pl  = (bf16*)(smem + 16384);
  const bf16* dT  = (const bf16*)(smem + 24576);
  const bf16* o1l = (const bf16*)(smem + 40960);
  float* cumS = (float*)(smem + 57344);

#pragma unroll
  for (int it = 0; it < 2; ++it) {
    int byte = (it * 256 + t) * 16;
    int row = byte >> 7, col = (byte & 127) >> 1;
    GLDS16(qbuf + (long)(c * 64 + row) * KEY_DIM + h * DKv + col, smem + byte);
    GLDS16(kbuf + (long)(c * 64 + row) * KEY_DIM + h * DKv + col, smem + 8192 + byte);
  }
#pragma unroll
  for (int it = 0; it < 4; ++it) {
    int byte = (it * 256 + t) * 16;
    GLDS16(dTg + c16h * 8192 + (byte >> 1), smem + 24576 + byte);
    GLDS16(o1g + c16h * 8192 + (byte >> 1), smem + 40960 + byte);
  }
  if (t < 64) {
    float cc = gbuf[(long)(c * 64 + t) * NH + h];
#pragma unroll
    for (int d = 1; d < 64; d <<= 1) { float y = __shfl_up(cc, d); if (t >= d) cc += y; }
    cumS[t] = cc;
  }
  __syncthreads();

  const int lane = t & 63, wv = t >> 6;
  const int r = lane & 15, q = lane >> 4;
  const bf16x8* Qs8 = (const bf16x8*)Qs;
  const bf16x8* Ks8 = (const bf16x8*)Ksl;

  // c1: P[t][i] = (i<=t) ? e^{cum_t-cum_i} (q_t.k_i) : 0
#pragma unroll
  for (int n = 0; n < 4; ++n) {
    f32x4 acc = {0.f, 0.f, 0.f, 0.f};
#pragma unroll
    for (int kk = 0; kk < 2; ++kk)
      acc = __builtin_amdgcn_mfma_f32_16x16x32_bf16(
          Qs8[(wv * 16 + r) * 8 + kk * 4 + q], Ks8[(n * 16 + r) * 8 + kk * 4 + q], acc, 0, 0, 0);
    const int i = n * 16 + r;
#pragma unroll
    for (int rr = 0; rr < 4; ++rr) {
      const int tr = wv * 16 + q * 4 + rr;
      Pl[tr * 64 + i] = (i <= tr) ? (bf16)(__expf(cumS[tr] - cumS[i]) * acc[rr]) : (bf16)0.0f;
    }
  }
  __syncthreads();

  // c2: O = o1 (acc init) + P.deltaT via MFMA
  {
    const bf16x8* Pl8 = (const bf16x8*)Pl;
    const bf16x8* dT8 = (const bf16x8*)dT;
    bf16x8 pf[2];
#pragma unroll
    for (int kk = 0; kk < 2; ++kk) pf[kk] = Pl8[(wv * 16 + r) * 8 + kk * 4 + q];
#pragma unroll
    for (int n = 0; n < 8; ++n) {
      const int v = n * 16 + r;
      f32x4 acc;
#pragma unroll
      for (int rr = 0; rr < 4; ++rr)
        acc[rr] = (float)o1l[v * 64 + (wv * 16 + q * 4 + rr)];
#pragma unroll
      for (int kk = 0; kk < 2; ++kk)
        acc = __builtin_amdgcn_mfma_f32_16x16x32_bf16(
            pf[kk], dT8[(n * 16 + r) * 8 + kk * 4 + q], acc, 0, 0, 0);
#pragma unroll
      for (int rr = 0; rr < 4; ++rr) {
        const int tr = wv * 16 + q * 4 + rr;
        core[(long)(c * 64 + tr) * VAL_DIM + h * DVv + v] = (bf16)acc[rr];
      }
    }
  }
}

// ---------------------------------------------------------------- RMSNorm + SiLU(z) gate
__global__ __launch_bounds__(256)
void gate_norm(const bf16* __restrict__ core, const bf16* __restrict__ zb,
               const void* __restrict__ normwr, bf16* __restrict__ gated,
               const unsigned* __restrict__ flagp) {
  const bool f32g = (*flagp != 0);
  const int s  = blockIdx.x;
  const int t  = threadIdx.x;
  const int h  = t >> 4;
  const int li = t & 15;
  const long base = (long)s * VAL_DIM + h * DVv + li * 8;
  bf16x8 c8 = *(const bf16x8*)(core + base);
  bf16x8 z8 = *(const bf16x8*)(zb + base);
  float x[8], z[8], nw[8];
  float ss = 0.f;
#pragma unroll
  for (int j = 0; j < 8; ++j) { x[j] = (float)c8[j]; z[j] = (float)z8[j]; ss += x[j] * x[j]; }
  if (f32g) {
    const float* np_ = (const float*)normwr + li * 8;
#pragma unroll
    for (int j = 0; j < 8; ++j) nw[j] = np_[j];
  } else {
    const u16* np_ = (const u16*)normwr + li * 8;
#pragma unroll
    for (int j = 0; j < 8; ++j) nw[j] = b2f(np_[j]);
  }
  ss += __shfl_xor(ss, 1); ss += __shfl_xor(ss, 2);
  ss += __shfl_xor(ss, 4); ss += __shfl_xor(ss, 8);
  float scale = rsqrtf(ss * (1.f / 128.f) + 1e-6f);
#pragma unroll
  for (int j = 0; j < 8; ++j) {
    float y = x[j] * scale * nw[j];
    y *= z[j] * sigmoidf_(z[j]);
    gated[base + j] = (bf16)y;
  }
}

// ---------------------------------------------------------------- launcher
extern "C" void kernel_launch(void* const* d_in, const int* in_sizes, int n_in,
                              void* d_out, int out_size, void* d_ws, size_t ws_size,
                              hipStream_t stream) {
  char* ws = (char*)d_ws;
  const bool big = ws_size >= ((48u << 20) + (512u << 10));

  if (big) {
    // ws: [0,8M) hsb -> dTg | [8,16M) wqkvb/wzb -> o1g | [16,24M) wqkvb -> zbuf
    //     [24,28M) mixed -> whig | [28,32M) mixed -> wlog | [32,40M) mixed -> woutb
    //     [40,44M) qbuf | [44,48M) kbuf -> (with qbuf) gated | [48M..) eg|beta|g|flag
    // d_out: [0,8M) vbuf -> core | [8,16M) dloc; final gemm overwrites all 16M f32.
    bf16*  hsb   = (bf16*)ws;
    bf16*  wqkvb = (bf16*)(ws + (8u << 20));
    bf16*  wzb   = (bf16*)(ws + (8u << 20));
    bf16*  zbuf  = (bf16*)(ws + (16u << 20));
    bf16*  mixed = (bf16*)(ws + (24u << 20));
    bf16*  whig  = (bf16*)(ws + (24u << 20));
    bf16*  wlog  = (bf16*)(ws + (28u << 20));
    bf16*  woutb = (bf16*)(ws + (32u << 20));
    bf16*  qbuf  = (bf16*)(ws + (40u << 20));
    bf16*  kbuf  = (bf16*)(ws + (44u << 20));
    bf16*  gated = (bf16*)(ws + (40u << 20));
    bf16*  dTg   = (bf16*)ws;
    bf16*  o1g   = (bf16*)(ws + (8u << 20));
    float* egp  = (float*)(ws + (48u << 20));
    float* betp = (float*)(ws + (48u << 20) + (128u << 10));
    float* gbp  = (float*)(ws + (48u << 20) + (256u << 10));
    unsigned* flagp = (unsigned*)(ws + (48u << 20) + (384u << 10));
    bf16* vbuf  = (bf16*)d_out;
    bf16* dlocp = (bf16*)((char*)d_out + (8u << 20));
    bf16* corep = (bf16*)d_out;

    detect_dtype<<<1, 64, 0, stream>>>((const u16*)d_in[0], flagp);
    proj_ab<<<SEQ, 256, 0, stream>>>(d_in[0], d_in[2], d_in[3], d_in[6], d_in[7], egp, betp, gbp, flagp);
    cvt_bf16<<<(SEQ * HIDDEN) / 2048, 256, 0, stream>>>(d_in[0], hsb, (long)SEQ * HIDDEN, flagp);
    cvt_bf16<<<(CONV_DIM * HIDDEN) / 2048, 256, 0, stream>>>(d_in[1], wqkvb, (long)CONV_DIM * HIDDEN, flagp);
    gemm_nt<false><<<dim3(CONV_DIM / 128, SEQ / 128), 256, 0, stream>>>(hsb, wqkvb, mixed, CONV_DIM, HIDDEN, flagp, 0, 0);
    cvt_bf16<<<(VAL_DIM * HIDDEN) / 2048, 256, 0, stream>>>(d_in[4], wzb, (long)VAL_DIM * HIDDEN, flagp);
    conv_norm<<<dim3(SEQ, CONV_DIM / 256), 256, 0, stream>>>(mixed, d_in[5], qbuf, kbuf, vbuf, flagp);
    chunk_a<<<512 + 256 + 2048, 256, 0, stream>>>(kbuf, vbuf, gbp, betp, dlocp, whig, wlog,
                                                  hsb, wzb, zbuf, d_in[9], woutb, flagp);
    chunk_b<<<32, 256, 0, stream>>>(qbuf, kbuf, gbp, dlocp, whig, wlog, dTg, o1g);
    chunk_c<<<512, 256, 0, stream>>>(qbuf, kbuf, gbp, dTg, o1g, corep);
    gate_norm<<<SEQ, 256, 0, stream>>>(corep, zbuf, d_in[8], gated, flagp);
    gemm_nt<true><<<dim3(HIDDEN / 128, SEQ / 128), 256, 0, stream>>>(gated, woutb, d_out, HIDDEN, VAL_DIM, flagp, 0, 0);
  } else {
    // Fallback layout (peak 24.26 MiB): r6-style staging GEMMs; per-step scan.
    bf16* mixed = (bf16*)ws;
    bf16* qbuf  = (bf16*)(ws + (16u << 20));
    bf16* kbuf  = (bf16*)(ws + (20u << 20));
    bf16* zbuf  = (bf16*)ws;
    bf16* corep = (bf16*)(ws + (8u << 20));
    bf16* gated = (bf16*)(ws + (16u << 20));
    float* egp  = (float*)(ws + (24u << 20));
    float* betp = (float*)(ws + (24u << 20) + (128u << 10));
    unsigned* flagp = (unsigned*)(ws + (24u << 20) + (256u << 10));
    bf16* vbuf  = (bf16*)d_out;

    detect_dtype<<<1, 64, 0, stream>>>((const u16*)d_in[0], flagp);
    proj_ab<<<SEQ, 256, 0, stream>>>(d_in[0], d_in[2], d_in[3], d_in[6], d_in[7], egp, betp, nullptr, flagp);
    gemm_nt<false><<<dim3(CONV_DIM / 128, SEQ / 128), 256, 0, stream>>>(d_in[0], d_in[1], mixed, CONV_DIM, HIDDEN, flagp, 1, 1);
    conv_norm<<<dim3(SEQ, CONV_DIM / 256), 256, 0, stream>>>(mixed, d_in[5], qbuf, kbuf, vbuf, flagp);
    gemm_nt<false><<<dim3(VAL_DIM / 128, SEQ / 128), 256, 0, stream>>>(d_in[0], d_in[4], zbuf, VAL_DIM, HIDDEN, flagp, 1, 1);
    fused_scan<<<128, 256, 0, stream>>>(qbuf, kbuf, vbuf, egp, betp, corep,
                                        nullptr, nullptr, nullptr, nullptr, nullptr, flagp,
                                        128, 0);
    gate_norm<<<SEQ, 256, 0, stream>>>(corep, zbuf, d_in[8], gated, flagp);
    gemm_nt<true><<<dim3(HIDDEN / 128, SEQ / 128), 256, 0, stream>>>(gated, d_in[9], d_out, HIDDEN, VAL_DIM, flagp, 0, 1);
  }
}

// Round 5
// 491.104 us; speedup vs baseline: 1.3652x; 1.0246x over previous
//
#include <hip/hip_runtime.h>
#include <stdint.h>

// LinearAttention (gated delta rule), S=2048, HID=2048, H=16, DK=64, DV=128, conv K=4.
// r15: fix proj_ab. r14's top dispatch (96us, HBM 1.3%, VALU 7%, Occ 52% -> nothing
// busy) was an L2-rebroadcast problem: 2048 blocks (one per s-row) each re-reading the
// full 256KB Wa/Wb from L2 = 512MB L2 traffic + 32-row scattered wave loads.
// New proj_ab: grid 256 (8 s-rows/block), thread = (s_loc, output), full-K f32 dot in
// registers (no LDS reduction). W L2 traffic 8x down; x-loads wave-broadcast; w-loads
// sequential per row (L1 serves 3/4 of touches). Decay/beta math kept f32 (absmax
// margin 0.0527 vs 0.0544 forbids bf16 on this path); only summation order changes.

#define SEQ 2048
#define HIDDEN 2048
#define NH 16
#define DKv 64
#define DVv 128
#define KEY_DIM 1024
#define VAL_DIM 2048
#define CONV_DIM 4096

typedef __bf16 bf16;
typedef unsigned short u16;
typedef __attribute__((ext_vector_type(8))) __bf16 bf16x8;
typedef __attribute__((ext_vector_type(4))) __bf16 bf16x4;
typedef __attribute__((ext_vector_type(4))) float f32x4;

#define AS1 __attribute__((address_space(1)))
#define AS3 __attribute__((address_space(3)))
#define GLDS16(src, dst) __builtin_amdgcn_global_load_lds((AS1 const void*)(src), (AS3 void*)(dst), 16, 0, 0)

__device__ __forceinline__ float b2f(u16 u) {
  union { unsigned int i; float f; } c; c.i = ((unsigned int)u) << 16; return c.f;
}
__device__ __forceinline__ float sigmoidf_(float x) { return 1.0f / (1.0f + __expf(-x)); }

// ---------------------------------------------------------------- dtype detector
__global__ void detect_dtype(const u16* __restrict__ p, unsigned* __restrict__ flag) {
  int lane = threadIdx.x;  // 64 threads
  int cnt = 0;
  for (int w = lane; w < 2048; w += 64) {
    unsigned e = (p[2 * w] >> 7) & 0xFF;
    if (e < 64) cnt++;
  }
  cnt += __shfl_xor(cnt, 1);  cnt += __shfl_xor(cnt, 2);  cnt += __shfl_xor(cnt, 4);
  cnt += __shfl_xor(cnt, 8);  cnt += __shfl_xor(cnt, 16); cnt += __shfl_xor(cnt, 32);
  if (lane == 0) *flag = (cnt > 64) ? 1u : 0u;   // 1 = inputs are f32
}

// ---------------------------------------------------------------- f32 -> bf16 convert
__global__ __launch_bounds__(256)
void cvt_bf16(const void* __restrict__ src, bf16* __restrict__ dst, long n,
              const unsigned* __restrict__ flagp) {
  long i = ((long)blockIdx.x * 256 + threadIdx.x) * 8;
  if (i >= n) return;
  if (*flagp) {
    const f32x4* s = (const f32x4*)((const float*)src + i);
    f32x4 a = s[0], b = s[1];
    bf16x8 o;
#pragma unroll
    for (int j = 0; j < 4; ++j) { o[j] = (bf16)a[j]; o[4 + j] = (bf16)b[j]; }
    *(bf16x8*)(dst + i) = o;
  } else {
    *(bf16x8*)(dst + i) = *(const bf16x8*)((const bf16*)src + i);
  }
}

// ---------------------------------------------------------------- GEMM (NT) standalone
template<bool F32OUT>
__global__ __launch_bounds__(256, 2)
void gemm_nt(const void* __restrict__ Araw, const void* __restrict__ Braw,
             void* __restrict__ Cv, int N, int K,
             const unsigned* __restrict__ flagp, int useA, int useB) {
  __shared__ __align__(16) bf16 As[128 * 32];
  __shared__ __align__(16) bf16 Bs[128 * 32];
  const bool f32g = (*flagp != 0);
  const bool fA = useA && f32g;
  const bool fB = useB && f32g;
  const int tid  = threadIdx.x;
  const int lane = tid & 63;
  const int wv   = tid >> 6;
  const int wm   = (wv & 1) << 6;
  const int wn   = (wv >> 1) << 6;
  const long bm  = (long)blockIdx.y * 128;
  const long bn  = (long)blockIdx.x * 128;

  f32x4 acc[4][4] = {};

  for (int k0 = 0; k0 < K; k0 += 32) {
#pragma unroll
    for (int it = 0; it < 2; ++it) {
      int e   = (it * 256 + tid) * 8;
      int row = e >> 5;
      int col = e & 31;
      long offA = (bm + row) * (long)K + (k0 + col);
      long offB = (bn + row) * (long)K + (k0 + col);
      if (fA) {
        const float* g = (const float*)Araw + offA;
        f32x4 u0 = *(const f32x4*)g, u1 = *(const f32x4*)(g + 4);
        bf16x8 bv;
#pragma unroll
        for (int j = 0; j < 4; ++j) { bv[j] = (bf16)u0[j]; bv[4 + j] = (bf16)u1[j]; }
        *(bf16x8*)&As[e] = bv;
      } else {
        const bf16* g = (const bf16*)Araw + offA;
        GLDS16(g, &As[e]);
      }
      if (fB) {
        const float* g = (const float*)Braw + offB;
        f32x4 u0 = *(const f32x4*)g, u1 = *(const f32x4*)(g + 4);
        bf16x8 bv;
#pragma unroll
        for (int j = 0; j < 4; ++j) { bv[j] = (bf16)u0[j]; bv[4 + j] = (bf16)u1[j]; }
        *(bf16x8*)&Bs[e] = bv;
      } else {
        const bf16* g = (const bf16*)Braw + offB;
        GLDS16(g, &Bs[e]);
      }
    }
    __syncthreads();

    const bf16x8* As8 = (const bf16x8*)As;
    const bf16x8* Bs8 = (const bf16x8*)Bs;
    const int r = lane & 15, q = lane >> 4;
    bf16x8 af[4], bfr[4];
#pragma unroll
    for (int i = 0; i < 4; ++i) af[i]  = As8[(wm + i * 16 + r) * 4 + q];
#pragma unroll
    for (int j = 0; j < 4; ++j) bfr[j] = Bs8[(wn + j * 16 + r) * 4 + q];
#pragma unroll
    for (int i = 0; i < 4; ++i)
#pragma unroll
      for (int j = 0; j < 4; ++j)
        acc[i][j] = __builtin_amdgcn_mfma_f32_16x16x32_bf16(af[i], bfr[j], acc[i][j], 0, 0, 0);
    __syncthreads();
  }

  const int r = lane & 15, q = lane >> 4;
#pragma unroll
  for (int i = 0; i < 4; ++i)
#pragma unroll
    for (int j = 0; j < 4; ++j) {
      long row = bm + wm + i * 16 + q * 4;
      long col = bn + wn + j * 16 + r;
#pragma unroll
      for (int rr = 0; rr < 4; ++rr) {
        if constexpr (F32OUT) ((float*)Cv)[(row + rr) * N + col] = acc[i][j][rr];
        else                  ((bf16*)Cv)[(row + rr) * N + col] = (bf16)acc[i][j][rr];
      }
    }
}

// ---------------------------------------------------------------- GEMM body (bf16-only, fused)
__device__ void gemm_body_bf16(char* smemc, const bf16* __restrict__ A,
                               const bf16* __restrict__ B, bf16* __restrict__ C,
                               int N, int K, int bx, int by, int tid) {
  bf16* As = (bf16*)smemc;             // 8 KiB
  bf16* Bs = (bf16*)(smemc + 8192);    // 8 KiB
  const int lane = tid & 63;
  const int wv = tid >> 6, wm = (wv & 1) << 6, wn = (wv >> 1) << 6;
  const long bm = (long)by * 128, bn = (long)bx * 128;
  f32x4 acc[4][4] = {};
  for (int k0 = 0; k0 < K; k0 += 32) {
#pragma unroll
    for (int it = 0; it < 2; ++it) {
      int e = (it * 256 + tid) * 8;
      int row = e >> 5, col = e & 31;
      const bf16* gA = A + (bm + row) * (long)K + k0 + col;
      const bf16* gB = B + (bn + row) * (long)K + k0 + col;
      GLDS16(gA, &As[e]);
      GLDS16(gB, &Bs[e]);
    }
    __syncthreads();
    const bf16x8* As8 = (const bf16x8*)As;
    const bf16x8* Bs8 = (const bf16x8*)Bs;
    const int r = lane & 15, q = lane >> 4;
    bf16x8 af[4], bfr[4];
#pragma unroll
    for (int i = 0; i < 4; ++i) af[i]  = As8[(wm + i * 16 + r) * 4 + q];
#pragma unroll
    for (int j = 0; j < 4; ++j) bfr[j] = Bs8[(wn + j * 16 + r) * 4 + q];
#pragma unroll
    for (int i = 0; i < 4; ++i)
#pragma unroll
      for (int j = 0; j < 4; ++j)
        acc[i][j] = __builtin_amdgcn_mfma_f32_16x16x32_bf16(af[i], bfr[j], acc[i][j], 0, 0, 0);
    __syncthreads();
  }
  const int r = lane & 15, q = lane >> 4;
#pragma unroll
  for (int i = 0; i < 4; ++i)
#pragma unroll
    for (int j = 0; j < 4; ++j) {
      long row = bm + wm + i * 16 + q * 4;
      long col = bn + wn + j * 16 + r;
#pragma unroll
      for (int rr = 0; rr < 4; ++rr)
        C[(row + rr) * (long)N + col] = (bf16)acc[i][j][rr];
    }
}

// ---------------------------------------------------------------- a/b proj -> exp(g), g, beta
// r15: grid SEQ/8; thread = (s_loc = t>>5, o = t&31); full-K f32 dot per thread.
// x-loads broadcast across the 32 lanes sharing s_loc; w-loads walk rows
// sequentially (L1-friendly). No LDS. Decay path stays f32.
__global__ __launch_bounds__(256)
void proj_ab(const void* __restrict__ hsr, const void* __restrict__ War,
             const void* __restrict__ Wbr, const void* __restrict__ A_logr,
             const void* __restrict__ dtbr,
             float* __restrict__ eg, float* __restrict__ bet,
             float* __restrict__ gb,
             const unsigned* __restrict__ flagp) {
  const bool f32g = (*flagp != 0);
  const int t  = threadIdx.x;
  const int sl = t >> 5;
  const int o  = t & 31;
  const int h  = o & 15;
  const long s = (long)blockIdx.x * 8 + sl;
  float a0 = 0.f, a1 = 0.f, a2 = 0.f, a3 = 0.f;
  if (f32g) {
    const f32x4* x4 = (const f32x4*)((const float*)hsr + s * HIDDEN);
    const f32x4* w4 = (const f32x4*)((const float*)((o < 16) ? War : Wbr) + (long)h * HIDDEN);
#pragma unroll 8
    for (int k4 = 0; k4 < 512; ++k4) {
      f32x4 xv = x4[k4], wv = w4[k4];
      a0 = fmaf(xv[0], wv[0], a0);
      a1 = fmaf(xv[1], wv[1], a1);
      a2 = fmaf(xv[2], wv[2], a2);
      a3 = fmaf(xv[3], wv[3], a3);
    }
  } else {
    const bf16x8* x8 = (const bf16x8*)((const bf16*)hsr + s * HIDDEN);
    const bf16x8* w8 = (const bf16x8*)((const bf16*)((o < 16) ? War : Wbr) + (long)h * HIDDEN);
#pragma unroll 8
    for (int k8 = 0; k8 < 256; ++k8) {
      bf16x8 xv = x8[k8], wv = w8[k8];
      a0 += (float)xv[0] * (float)wv[0] + (float)xv[4] * (float)wv[4];
      a1 += (float)xv[1] * (float)wv[1] + (float)xv[5] * (float)wv[5];
      a2 += (float)xv[2] * (float)wv[2] + (float)xv[6] * (float)wv[6];
      a3 += (float)xv[3] * (float)wv[3] + (float)xv[7] * (float)wv[7];
    }
  }
  const float a = (a0 + a1) + (a2 + a3);
  if (o < 16) {
    float alog = f32g ? ((const float*)A_logr)[h] : b2f(((const u16*)A_logr)[h]);
    float dtb  = f32g ? ((const float*)dtbr)[h]   : b2f(((const u16*)dtbr)[h]);
    float xx = a + dtb;
    float sp = fmaxf(xx, 0.f) + log1pf(__expf(-fabsf(xx)));   // stable softplus
    float gg = -__expf(alog) * sp;                             // log-decay
    if (gb) gb[s * NH + h] = gg;
    eg[s * NH + h] = __expf(gg);
  } else {
    bet[s * NH + h] = sigmoidf_(a);
  }
}

// ---------------------------------------------------------------- conv + SiLU + l2norm
__global__ __launch_bounds__(256)
void conv_norm(const bf16* __restrict__ mixed, const void* __restrict__ convwr,
               bf16* __restrict__ qbuf, bf16* __restrict__ kbuf, bf16* __restrict__ vbuf,
               const unsigned* __restrict__ flagp) {
  const bool f32g = (*flagp != 0);
  const int s = blockIdx.x;
  const int c = blockIdx.y * 256 + threadIdx.x;
  float w0, w1, w2, w3;
  if (f32g) {
    const float* wp = (const float*)convwr + (long)c * 4;
    w0 = wp[0]; w1 = wp[1]; w2 = wp[2]; w3 = wp[3];
  } else {
    const u16* wp = (const u16*)convwr + (long)c * 4;
    w0 = b2f(wp[0]); w1 = b2f(wp[1]); w2 = b2f(wp[2]); w3 = b2f(wp[3]);
  }
  float acc = w3 * (float)mixed[(long)s * CONV_DIM + c];
  if (s >= 1) acc += w2 * (float)mixed[(long)(s - 1) * CONV_DIM + c];
  if (s >= 2) acc += w1 * (float)mixed[(long)(s - 2) * CONV_DIM + c];
  if (s >= 3) acc += w0 * (float)mixed[(long)(s - 3) * CONV_DIM + c];
  float y = acc * sigmoidf_(acc);  // SiLU
  if (c < 2 * KEY_DIM) {
    float ss = y * y;
    ss += __shfl_xor(ss, 1);  ss += __shfl_xor(ss, 2);  ss += __shfl_xor(ss, 4);
    ss += __shfl_xor(ss, 8);  ss += __shfl_xor(ss, 16); ss += __shfl_xor(ss, 32);
    float scale = rsqrtf(ss + 1e-6f);
    if (c < KEY_DIM) scale *= 0.125f;
    y *= scale;
  }
  if (c < KEY_DIM)            qbuf[(long)s * KEY_DIM + c] = (bf16)y;
  else if (c < 2 * KEY_DIM)   kbuf[(long)s * KEY_DIM + (c - KEY_DIM)] = (bf16)y;
  else                        vbuf[(long)s * VAL_DIM + (c - 2 * KEY_DIM)] = (bf16)y;
}

// ---------------------------------------------------------------- DPP 16-lane sum (fallback scan)
template<int CTRL>
__device__ __forceinline__ float dpp_add(float x) {
  int y = __builtin_amdgcn_update_dpp(0, __float_as_int(x), CTRL, 0xF, 0xF, true);
  return x + __int_as_float(y);
}
__device__ __forceinline__ float dpp_sum16(float x) {
  x = dpp_add<0xB1>(x);   // quad_perm xor1
  x = dpp_add<0x4E>(x);   // quad_perm xor2
  x = dpp_add<0x141>(x);  // row_half_mirror (xor4)
  x = dpp_add<0x140>(x);  // row_mirror (xor8)
  return x;
}

// ---------------------------------------------------------------- fused per-step scan (FALLBACK path only)
__global__ __launch_bounds__(256, 2)
void fused_scan(const bf16* __restrict__ qbuf, const bf16* __restrict__ kbuf,
                const bf16* __restrict__ vbuf, const float* __restrict__ eg,
                const float* __restrict__ bet, bf16* __restrict__ core,
                const bf16* __restrict__ hsb, const bf16* __restrict__ wzb,
                bf16* __restrict__ zbuf, const void* __restrict__ woutr,
                bf16* __restrict__ woutb, const unsigned* __restrict__ flagp,
                int nScan, int nGemm) {
  __shared__ __align__(16) char smem[16384];
  const int t = threadIdx.x;
  const int b = blockIdx.x;

  if (b < nScan) {
    const int h  = b >> 3;
    const int vg = (b & 7) * 16;
    const int g  = t >> 4;
    const int L  = t & 15;
    bf16*  kqs = (bf16*)smem;               // [2][2048] elems
    bf16*  vts = (bf16*)(smem + 8192);      // [2][256] elems
    float* ets = (float*)(smem + 9216);     // [2][16]
    float* bts = (float*)(smem + 9344);     // [2][16]

#define STAGE(buf, s0)                                                          \
    {                                                                           \
      int byte = t * 16;                                                        \
      const bf16* src;                                                          \
      if (byte < 2048) {                                                        \
        int row = byte >> 7, el = (byte & 127) >> 1;                            \
        src = kbuf + (long)((s0) + row) * KEY_DIM + h * DKv + el;               \
      } else {                                                                  \
        int b2 = byte - 2048;                                                   \
        int row = b2 >> 7, el = (b2 & 127) >> 1;                                \
        src = qbuf + (long)((s0) + row) * KEY_DIM + h * DKv + el;               \
      }                                                                         \
      GLDS16(src, smem + (buf) * 4096 + byte);                                  \
      if (t < 32) {                                                             \
        int row = t >> 1, el = (t & 1) * 8;                                     \
        const bf16* vsrc = vbuf + (long)((s0) + row) * VAL_DIM + h * DVv + vg + el; \
        GLDS16(vsrc, smem + 8192 + (buf) * 512 + t * 16);                       \
      }                                                                         \
    }

    float er = 0.f, br = 0.f;
    if (t < 16)      er = eg[(long)t * NH + h];
    else if (t < 32) br = bet[(long)(t - 16) * NH + h];
    STAGE(0, 0);
    if (t < 16)      ets[t] = er;
    else if (t < 32) bts[t - 16] = br;
    __syncthreads();

    float S0 = 0.f, S1 = 0.f, S2 = 0.f, S3 = 0.f;
    for (int tile = 0; tile < 128; ++tile) {
      const int buf = tile & 1, nb = buf ^ 1;
      if (tile < 127) {
        STAGE(nb, (tile + 1) * 16);
        if (t < 16)      er = eg[(long)((tile + 1) * 16 + t) * NH + h];
        else if (t < 32) br = bet[(long)((tile + 1) * 16 + (t - 16)) * NH + h];
      }
      const bf16*  ktb = kqs + buf * 2048;
      const bf16*  qtb = ktb + 1024;
      const bf16*  vtb = vts + buf * 256;
      const float* etb = ets + buf * 16;
      const float* btb = bts + buf * 16;
      const long sbase = (long)tile * 16;

      bf16x4 kR[2], qR[2];
      float  vR[2], eR[2], bR[2];
      kR[0] = *(const bf16x4*)(ktb + 0 * 64 + L * 4);
      qR[0] = *(const bf16x4*)(qtb + 0 * 64 + L * 4);
      vR[0] = (float)vtb[0 * 16 + g];  eR[0] = etb[0];  bR[0] = btb[0];
      kR[1] = *(const bf16x4*)(ktb + 1 * 64 + L * 4);
      qR[1] = *(const bf16x4*)(qtb + 1 * 64 + L * 4);
      vR[1] = (float)vtb[1 * 16 + g];  eR[1] = etb[1];  bR[1] = btb[1];
#pragma unroll
      for (int s = 0; s < 16; ++s) {
        const int sl = s & 1;
        bf16x4 kk = kR[sl], qq = qR[sl];
        float vv = vR[sl], ee = eR[sl], bb = bR[sl];
        if (s < 14) {
          const int s2 = s + 2;
          kR[sl] = *(const bf16x4*)(ktb + s2 * 64 + L * 4);
          qR[sl] = *(const bf16x4*)(qtb + s2 * 64 + L * 4);
          vR[sl] = (float)vtb[s2 * 16 + g];
          eR[sl] = etb[s2];  bR[sl] = btb[s2];
        }
        float ebt = ee * bb, vbt = vv * bb;
        float k0 = (float)kk[0], k1 = (float)kk[1], k2 = (float)kk[2], k3 = (float)kk[3];
        float D0 = S0 * ee, D1 = S1 * ee, D2 = S2 * ee, D3 = S3 * ee;
        float p = (k0 * S0 + k1 * S1) + (k2 * S2 + k3 * S3);
        p = dpp_sum16(p);
        float delta = vbt - ebt * p;
        S0 = fmaf(k0, delta, D0); S1 = fmaf(k1, delta, D1);
        S2 = fmaf(k2, delta, D2); S3 = fmaf(k3, delta, D3);
        float q0 = (float)qq[0], q1 = (float)qq[1], q2 = (float)qq[2], q3 = (float)qq[3];
        float o = (q0 * S0 + q1 * S1) + (q2 * S2 + q3 * S3);
        o = dpp_sum16(o);
        if (L == 0) core[(sbase + s) * VAL_DIM + h * DVv + vg + g] = (bf16)o;
      }
      if (tile < 127) {
        if (t < 16)      ets[nb * 16 + t] = er;
        else if (t < 32) bts[nb * 16 + (t - 16)] = br;
      }
      __syncthreads();
    }
#undef STAGE
  } else if (b < nScan + nGemm) {
    int gb = b - nScan;
    gemm_body_bf16(smem, hsb, wzb, zbuf, VAL_DIM, HIDDEN, gb & 15, gb >> 4, t);
  } else {
    long i = ((long)(b - nScan - nGemm) * 256 + t) * 8;
    if (i < (long)HIDDEN * VAL_DIM) {
      if (*flagp) {
        const f32x4* s = (const f32x4*)((const float*)woutr + i);
        f32x4 a = s[0], c = s[1];
        bf16x8 o;
#pragma unroll
        for (int j = 0; j < 4; ++j) { o[j] = (bf16)a[j]; o[4 + j] = (bf16)c[j]; }
        *(bf16x8*)(woutb + i) = o;
      } else {
        *(bf16x8*)(woutb + i) = *(const bf16x8*)((const bf16*)woutr + i);
      }
    }
  }
}

// ================================================================ CHUNKED DELTA RULE
// chunk length 64, 32 chunks, 16 heads. Per chunk-head (c,h):
//   cum_t = prefix-sum of g; d_t = e^{cum_t}
//   A[t][i] = beta_t e^{cum_t-cum_i} (k_t.k_i), strictly lower
//   [Dloc | W] = (I+A)^{-1} [diag(beta)V | diag(beta*d)K]
//   delta = Dloc - W S0;  S' = e^{cumC} S0 + K'^T delta, K'[i]=e^{cumC-cum_i}k_i
//   O = diag(d) Q S0 + (Minc o Q K^T) delta
// dloc[(c,h)][t][v] bf16 (d_out+8M); negW hi/lo [t][k] bf16 (ws+24M,+28M);
// dTg[(c,h)][v][t] bf16 (ws+0); o1g[(c,h)][v][t] bf16 pre-scaled by d_t (ws+8M).

// ---------------------------------------------------------------- phase A (+ fused zgemm + woutcvt)
__global__ __launch_bounds__(256, 2)
void chunk_a(const bf16* __restrict__ kbuf, const bf16* __restrict__ vbuf,
             const float* __restrict__ gbuf, const float* __restrict__ betp,
             bf16* __restrict__ dloc, bf16* __restrict__ whig, bf16* __restrict__ wlog,
             const bf16* __restrict__ hsb, const bf16* __restrict__ wzb,
             bf16* __restrict__ zbuf, const void* __restrict__ woutr,
             bf16* __restrict__ woutb, const unsigned* __restrict__ flagp) {
  __shared__ __align__(16) char smem[25600];
  const int t = threadIdx.x;
  const int b = blockIdx.x;
  if (b < 512) {
    const int c = b >> 4, h = b & 15;
    bf16*  Ks   = (bf16*)smem;                 // [64][64] 8192 B
    float* At   = (float*)(smem + 8192);       // [64][64] 16384 B, At[i][t] = A[t][i]
    float* cumS = (float*)(smem + 24576);      // 64
    float* bS   = (float*)(smem + 24832);      // 64
    float* dS   = (float*)(smem + 25088);      // 64
    // stage K chunk -> LDS (linear)
#pragma unroll
    for (int it = 0; it < 2; ++it) {
      int byte = (it * 256 + t) * 16;
      int row = byte >> 7, col = (byte & 127) >> 1;
      const bf16* src = kbuf + (long)(c * 64 + row) * KEY_DIM + h * DKv + col;
      GLDS16(src, smem + byte);
    }
    if (t < 64) {  // wave 0: within-chunk prefix sum of log-decay
      float cc = gbuf[(long)(c * 64 + t) * NH + h];
#pragma unroll
      for (int d = 1; d < 64; d <<= 1) { float y = __shfl_up(cc, d); if (t >= d) cc += y; }
      cumS[t] = cc;
      dS[t] = __expf(cc);
      bS[t] = betp[(long)(c * 64 + t) * NH + h];
    }
    {  // zero At (upper+diag must read as 0 in the quad-vectorized substitution)
      f32x4 z = {0.f, 0.f, 0.f, 0.f};
#pragma unroll
      for (int i = 0; i < 4; ++i) ((f32x4*)At)[t * 4 + i] = z;
    }
    __syncthreads();
    // G = K K^T via MFMA; masked+scaled, stored transposed into At
    {
      const int lane = t & 63, wv = t >> 6;
      const int r = lane & 15, q = lane >> 4;
      const bf16x8* Ks8 = (const bf16x8*)Ks;
#pragma unroll
      for (int n = 0; n < 4; ++n) {
        f32x4 acc = {0.f, 0.f, 0.f, 0.f};
#pragma unroll
        for (int kk = 0; kk < 2; ++kk) {
          bf16x8 af  = Ks8[(wv * 16 + r) * 8 + kk * 4 + q];
          bf16x8 bfv = Ks8[(n  * 16 + r) * 8 + kk * 4 + q];
          acc = __builtin_amdgcn_mfma_f32_16x16x32_bf16(af, bfv, acc, 0, 0, 0);
        }
        const int i = n * 16 + r;
#pragma unroll
        for (int rr = 0; rr < 4; ++rr) {
          const int tr = wv * 16 + q * 4 + rr;
          if (i < tr)
            At[i * 64 + tr] = bS[tr] * __expf(cumS[tr] - cumS[i]) * acc[rr];
        }
      }
    }
    __syncthreads();
    // column-parallel forward substitution: x = (I+A)^{-1} r, one column per thread
    if (t < 192) {
      float x[64];
      const long base = ((long)(c * 16 + h)) * 64;
      if (t < 128) {
#pragma unroll
        for (int s = 0; s < 64; ++s)
          x[s] = bS[s] * (float)vbuf[(long)(c * 64 + s) * VAL_DIM + h * DVv + t];
      } else {
        const int k = t - 128;
#pragma unroll
        for (int s = 0; s < 64; ++s)
          x[s] = bS[s] * dS[s] * (float)Ks[s * 64 + k];
      }
#pragma unroll
      for (int s = 0; s < 64; ++s) {
        const float val = x[s];
        const f32x4* row4 = (const f32x4*)(At + s * 64);
#pragma unroll
        for (int qd = (s >> 2); qd < 16; ++qd) {
          f32x4 a4 = row4[qd];
          x[qd * 4 + 0] = fmaf(-a4[0], val, x[qd * 4 + 0]);
          x[qd * 4 + 1] = fmaf(-a4[1], val, x[qd * 4 + 1]);
          x[qd * 4 + 2] = fmaf(-a4[2], val, x[qd * 4 + 2]);
          x[qd * 4 + 3] = fmaf(-a4[3], val, x[qd * 4 + 3]);
        }
      }
      if (t < 128) {          // Dloc column t  -> dloc[t][v] rows (bf16)
#pragma unroll
        for (int s = 0; s < 64; ++s)
          dloc[(base + s) * 128 + t] = (bf16)x[s];
      } else {                // W column k -> negW hi/lo [t][k] (coalesced per-s across wave)
        const int k = t - 128;
        const long wb = base * 64;   // = (c*16+h)*4096
#pragma unroll
        for (int s = 0; s < 64; ++s) {
          float v = -x[s];
          bf16 hh = (bf16)v;
          whig[wb + s * 64 + k] = hh;
          wlog[wb + s * 64 + k] = (bf16)(v - (float)hh);
        }
      }
    }
  } else if (b < 768) {
    int gb = b - 512;
    gemm_body_bf16(smem, hsb, wzb, zbuf, VAL_DIM, HIDDEN, gb & 15, gb >> 4, t);
  } else {
    long i = ((long)(b - 768) * 256 + t) * 8;
    if (i < (long)HIDDEN * VAL_DIM) {
      if (*flagp) {
        const f32x4* s = (const f32x4*)((const float*)woutr + i);
        f32x4 a = s[0], cc = s[1];
        bf16x8 o;
#pragma unroll
        for (int j = 0; j < 4; ++j) { o[j] = (bf16)a[j]; o[4 + j] = (bf16)cc[j]; }
        *(bf16x8*)(woutb + i) = o;
      } else {
        *(bf16x8*)(woutb + i) = *(const bf16x8*)((const bf16*)woutr + i);
      }
    }
  }
}

// ---------------------------------------------------------------- phase B: MFMA chunk-serial recurrence
// grid 32 = h*2 + vhalf (64 v per block). State: persistent f32 accregs (wave w owns
// v-rows w*16..w*16+15); bf16 hi/lo copies in LDS (X8 swizzle) feed MFMA B-operands.
// Latency schedule per chunk:
//   B1 -> issue prefetch (drained at B2 after full mm2 window) -> KT build ->
//   batched frag loads -> 40 MFMA -> pack/stores -> B2 -> batched S-update.
// Decay tables for ALL chunks precomputed once into LDS (no global loads on chain).
__global__ __launch_bounds__(256, 1)
void chunk_b(const bf16* __restrict__ qbuf, const bf16* __restrict__ kbuf,
             const float* __restrict__ gbuf, const bf16* __restrict__ dloc,
             const bf16* __restrict__ whig, const bf16* __restrict__ wlog,
             bf16* __restrict__ dTg, bf16* __restrict__ o1g) {
  __shared__ __align__(16) char smem[139264];
  bf16* Wh  = (bf16*)(smem);             // [2][64][64] swz
  bf16* Wl  = (bf16*)(smem + 16384);     // [2][64][64] swz
  bf16* Qs  = (bf16*)(smem + 32768);     // [2][64][64] swz
  bf16* Ks  = (bf16*)(smem + 49152);     // [2][64][64] linear
  bf16* Dls = (bf16*)(smem + 65536);     // [2][64][64] swz
  bf16* KT  = (bf16*)(smem + 81920);     // [64][64] swz (K^T)
  bf16* Shi = (bf16*)(smem + 90112);     // [64][64] swz
  bf16* Slo = (bf16*)(smem + 98304);     // [64][64] swz
  bf16* Dth = (bf16*)(smem + 106496);    // [64][64] swz (fS-scaled deltaT hi)
  bf16* Dtl = (bf16*)(smem + 114688);    // [64][64] swz (lo)
  float* fSa = (float*)(smem + 122880);  // [32][64] e^{cumC-cum_t}
  float* dSa = (float*)(smem + 131072);  // [32][64] e^{cum_t}

  const int t = threadIdx.x;
  const int h = blockIdx.x >> 1, vhalf = blockIdx.x & 1;
  const int lane = t & 63, w = t >> 6;
  const int r = lane & 15, q = lane >> 4;
  const int tb = w * 16 + q * 4;         // this lane's C-row base (t or v dim)

  auto stage = [&](int bb, int cc) {
    const long c16h = (long)(cc * 16 + h);
#pragma unroll
    for (int it = 0; it < 2; ++it) {
      int p = it * 256 + t;              // 16B-group id, 0..511
      int row = p >> 3, g = p & 7;
      int sg = ((g ^ (row & 7)) << 3);   // pre-swizzled source column
      GLDS16(whig + c16h * 4096 + row * 64 + sg, (char*)Wh + bb * 8192 + p * 16);
      GLDS16(wlog + c16h * 4096 + row * 64 + sg, (char*)Wl + bb * 8192 + p * 16);
      GLDS16(qbuf + (long)(cc * 64 + row) * KEY_DIM + h * DKv + sg, (char*)Qs + bb * 8192 + p * 16);
      GLDS16(kbuf + (long)(cc * 64 + row) * KEY_DIM + h * DKv + (g << 3), (char*)Ks + bb * 8192 + p * 16);
      GLDS16(dloc + (c16h * 64 + row) * 128 + vhalf * 64 + sg, (char*)Dls + bb * 8192 + p * 16);
    }
  };

  // prologue: one-time decay tables for ALL 32 chunks (wave w -> chunks w*8..w*8+7)
  {
    float g8[8];
#pragma unroll
    for (int i = 0; i < 8; ++i)
      g8[i] = gbuf[(long)((w * 8 + i) * 64 + lane) * NH + h];
#pragma unroll
    for (int i = 0; i < 8; ++i) {
      float cs = g8[i];
#pragma unroll
      for (int d = 1; d < 64; d <<= 1) { float y = __shfl_up(cs, d); if (lane >= d) cs += y; }
      float tot = __shfl(cs, 63);
      fSa[(w * 8 + i) * 64 + lane] = __expf(tot - cs);
      dSa[(w * 8 + i) * 64 + lane] = __expf(cs);
    }
  }
  {
    f32x4 z = {0.f, 0.f, 0.f, 0.f};
    ((f32x4*)Shi)[t] = z; ((f32x4*)Shi)[t + 256] = z;
    ((f32x4*)Slo)[t] = z; ((f32x4*)Slo)[t + 256] = z;
  }
  stage(0, 0);
  f32x4 Sacc[4] = {};   // k-tiles n=0..3 for this wave's v-rows

  for (int c = 0; c < 32; ++c) {
    const int buf = c & 1, nb = buf ^ 1;
    __syncthreads();   // B1: stage[buf] drained; prev chunk's S hi/lo visible
    if (c < 31) stage(nb, c + 1);   // prefetch EARLY: drained at B2 after mm2 window
    const bf16* wh = Wh + buf * 4096;
    const bf16* wl = Wl + buf * 4096;
    const bf16* qs = Qs + buf * 4096;
    const bf16* ks = Ks + buf * 4096;
    const bf16* dl = Dls + buf * 4096;
    const float* fS = fSa + c * 64;
    const float* dS = dSa + c * 64;
    const long gch = (long)(c * 16 + h) * 8192 + (long)(vhalf * 64) * 64;

    // K^T build (swizzled): lane k, rows i = w*16..w*16+15 (update-only)
    if (c < 31) {
      const int k = lane;
#pragma unroll
      for (int ii = 0; ii < 16; ++ii) {
        const int i = w * 16 + ii;
        const int pg = (i >> 3) ^ (k & 7);
        KT[k * 64 + pg * 8 + (i & 7)] = ks[i * 64 + k];
      }
    }

    // hoisted decay factors for this lane's 4 t-rows (from LDS tables)
    float fs4[4], ds4[4];
#pragma unroll
    for (int rr = 0; rr < 4; ++rr) { fs4[rr] = fS[tb + rr]; ds4[rr] = dS[tb + rr]; }

    // ---- batched fragment loads (all ds_reads in flight before MFMA) ----
    bf16x8 wahi[2], walo[2], qa[2];
#pragma unroll
    for (int kk = 0; kk < 2; ++kk) {
      const int row = w * 16 + r;
      const int g = (kk * 4 + q) ^ (row & 7);
      wahi[kk] = *(const bf16x8*)(wh + row * 64 + g * 8);
      walo[kk] = *(const bf16x8*)(wl + row * 64 + g * 8);
      qa[kk]   = *(const bf16x8*)(qs + row * 64 + g * 8);
    }
    bf16x8 sh[4][2], sl[4][2];
#pragma unroll
    for (int n = 0; n < 4; ++n)
#pragma unroll
      for (int kk = 0; kk < 2; ++kk) {
        const int vrow = n * 16 + r;
        const int g = (kk * 4 + q) ^ (vrow & 7);
        sh[n][kk] = *(const bf16x8*)(Shi + vrow * 64 + g * 8);
        sl[n][kk] = *(const bf16x8*)(Slo + vrow * 64 + g * 8);
      }
    float dl4[4][4];
#pragma unroll
    for (int n = 0; n < 4; ++n)
#pragma unroll
      for (int rr = 0; rr < 4; ++rr) {
        const int vrow = n * 16 + r, trow = tb + rr;
        const int pg = (vrow >> 3) ^ (trow & 7);
        dl4[n][rr] = (float)dl[trow * 64 + pg * 8 + (vrow & 7)];
      }

    // ---- 40 MFMA, 4 independent chains ----
    f32x4 da[4] = {}, oa[4] = {};
#pragma unroll
    for (int n = 0; n < 4; ++n)
#pragma unroll
      for (int kk = 0; kk < 2; ++kk) {
        da[n] = __builtin_amdgcn_mfma_f32_16x16x32_bf16(wahi[kk], sh[n][kk], da[n], 0, 0, 0);
        da[n] = __builtin_amdgcn_mfma_f32_16x16x32_bf16(wahi[kk], sl[n][kk], da[n], 0, 0, 0);
        da[n] = __builtin_amdgcn_mfma_f32_16x16x32_bf16(walo[kk], sh[n][kk], da[n], 0, 0, 0);
        oa[n] = __builtin_amdgcn_mfma_f32_16x16x32_bf16(qa[kk],   sh[n][kk], oa[n], 0, 0, 0);
        oa[n] = __builtin_amdgcn_mfma_f32_16x16x32_bf16(qa[kk],   sl[n][kk], oa[n], 0, 0, 0);
      }

    // ---- pack + stores (Dl added here instead of C-init: same sum) ----
#pragma unroll
    for (int n = 0; n < 4; ++n) {
      const int vrow = n * 16 + r;
      bf16x4 dpk, opk, fhk, flk;
#pragma unroll
      for (int rr = 0; rr < 4; ++rr) {
        float dv = dl4[n][rr] + da[n][rr];
        dpk[rr] = (bf16)dv;
        float p = fs4[rr] * dv;
        bf16 ph = (bf16)p;
        fhk[rr] = ph;
        flk[rr] = (bf16)(p - (float)ph);
        opk[rr] = (bf16)(ds4[rr] * oa[n][rr]);
      }
      *(bf16x4*)(dTg + gch + (long)vrow * 64 + tb) = dpk;
      *(bf16x4*)(o1g + gch + (long)vrow * 64 + tb) = opk;
      const int pg = (tb >> 3) ^ (vrow & 7);
      *(bf16x4*)(Dth + vrow * 64 + pg * 8 + (tb & 7)) = fhk;
      *(bf16x4*)(Dtl + vrow * 64 + pg * 8 + (tb & 7)) = flk;
    }

    __syncthreads();   // B2: DltT + KT visible; prefetch DMA drained (hidden by mm2)
    if (c < 31) {
      // update: S' = dC*S + DltT(hi/lo) x KT   [wave w owns v-rows w*16..+15]
      const float dC = dS[63];
      bf16x8 dh[2], dlo2[2], ktf[4][2];
#pragma unroll
      for (int kk = 0; kk < 2; ++kk) {
        const int vrow = w * 16 + r;
        const int g = (kk * 4 + q) ^ (vrow & 7);
        dh[kk]   = *(const bf16x8*)(Dth + vrow * 64 + g * 8);
        dlo2[kk] = *(const bf16x8*)(Dtl + vrow * 64 + g * 8);
      }
#pragma unroll
      for (int n = 0; n < 4; ++n)
#pragma unroll
        for (int kk = 0; kk < 2; ++kk) {
          const int krow = n * 16 + r;
          const int g = (kk * 4 + q) ^ (krow & 7);
          ktf[n][kk] = *(const bf16x8*)(KT + krow * 64 + g * 8);
        }
#pragma unroll
      for (int n = 0; n < 4; ++n) {
        f32x4 sa;
#pragma unroll
        for (int rr = 0; rr < 4; ++rr) sa[rr] = dC * Sacc[n][rr];
#pragma unroll
        for (int kk = 0; kk < 2; ++kk) {
          sa = __builtin_amdgcn_mfma_f32_16x16x32_bf16(dh[kk],   ktf[n][kk], sa, 0, 0, 0);
          sa = __builtin_amdgcn_mfma_f32_16x16x32_bf16(dlo2[kk], ktf[n][kk], sa, 0, 0, 0);
        }
        Sacc[n] = sa;
        // write S hi/lo (swizzled scalar stores): elems (v = tb+rr, k = n*16+r)
        const int k = n * 16 + r;
#pragma unroll
        for (int rr = 0; rr < 4; ++rr) {
          const int v = tb + rr;
          float s = sa[rr];
          bf16 hh = (bf16)s;
          const int pg = (k >> 3) ^ (v & 7);
          Shi[v * 64 + pg * 8 + (k & 7)] = hh;
          Slo[v * 64 + pg * 8 + (k & 7)] = (bf16)(s - (float)hh);
        }
      }
    }
  }
}

// ---------------------------------------------------------------- phase C: outputs, MFMA
// grid 512 = c*16 + h.  O[t][v] = o1[v][t] + sum_i P[t][i] delta^T[v][i]
__global__ __launch_bounds__(256, 2)
void chunk_c(const bf16* __restrict__ qbuf, const bf16* __restrict__ kbuf,
             const float* __restrict__ gbuf, const bf16* __restrict__ dTg,
             const bf16* __restrict__ o1g, bf16* __restrict__ core) {
  // Qs@0 8K | Ks@8192 8K | Pl@16384 8K | dT@24576 16K | o1l@40960 16K | cum@57344
  __shared__ __align__(16) char smem[57600];
  const int t = threadIdx.x;
  const int c = blockIdx.x >> 4, h = blockIdx.x & 15;
  const long c16h = (long)(c * 16 + h);
  bf16* Qs  = (bf16*)smem;
  bf16* Ksl = (bf16*)(smem + 8192);
  bf16* Pl  = (bf16*)(smem + 16384);
  const bf16* dT  = (const bf16*)(smem + 24576);
  const bf16* o1l = (const bf16*)(smem + 40960);
  float* cumS = (float*)(smem + 57344);

#pragma unroll
  for (int it = 0; it < 2; ++it) {
    int byte = (it * 256 + t) * 16;
    int row = byte >> 7, col = (byte & 127) >> 1;
    GLDS16(qbuf + (long)(c * 64 + row) * KEY_DIM + h * DKv + col, smem + byte);
    GLDS16(kbuf + (long)(c * 64 + row) * KEY_DIM + h * DKv + col, smem + 8192 + byte);
  }
#pragma unroll
  for (int it = 0; it < 4; ++it) {
    int byte = (it * 256 + t) * 16;
    GLDS16(dTg + c16h * 8192 + (byte >> 1), smem + 24576 + byte);
    GLDS16(o1g + c16h * 8192 + (byte >> 1), smem + 40960 + byte);
  }
  if (t < 64) {
    float cc = gbuf[(long)(c * 64 + t) * NH + h];
#pragma unroll
    for (int d = 1; d < 64; d <<= 1) { float y = __shfl_up(cc, d); if (t >= d) cc += y; }
    cumS[t] = cc;
  }
  __syncthreads();

  const int lane = t & 63, wv = t >> 6;
  const int r = lane & 15, q = lane >> 4;
  const bf16x8* Qs8 = (const bf16x8*)Qs;
  const bf16x8* Ks8 = (const bf16x8*)Ksl;

  // c1: P[t][i] = (i<=t) ? e^{cum_t-cum_i} (q_t.k_i) : 0
#pragma unroll
  for (int n = 0; n < 4; ++n) {
    f32x4 acc = {0.f, 0.f, 0.f, 0.f};
#pragma unroll
    for (int kk = 0; kk < 2; ++kk)
      acc = __builtin_amdgcn_mfma_f32_16x16x32_bf16(
          Qs8[(wv * 16 + r) * 8 + kk * 4 + q], Ks8[(n * 16 + r) * 8 + kk * 4 + q], acc, 0, 0, 0);
    const int i = n * 16 + r;
#pragma unroll
    for (int rr = 0; rr < 4; ++rr) {
      const int tr = wv * 16 + q * 4 + rr;
      Pl[tr * 64 + i] = (i <= tr) ? (bf16)(__expf(cumS[tr] - cumS[i]) * acc[rr]) : (bf16)0.0f;
    }
  }
  __syncthreads();

  // c2: O = o1 (acc init) + P.deltaT via MFMA
  {
    const bf16x8* Pl8 = (const bf16x8*)Pl;
    const bf16x8* dT8 = (const bf16x8*)dT;
    bf16x8 pf[2];
#pragma unroll
    for (int kk = 0; kk < 2; ++kk) pf[kk] = Pl8[(wv * 16 + r) * 8 + kk * 4 + q];
#pragma unroll
    for (int n = 0; n < 8; ++n) {
      const int v = n * 16 + r;
      f32x4 acc;
#pragma unroll
      for (int rr = 0; rr < 4; ++rr)
        acc[rr] = (float)o1l[v * 64 + (wv * 16 + q * 4 + rr)];
#pragma unroll
      for (int kk = 0; kk < 2; ++kk)
        acc = __builtin_amdgcn_mfma_f32_16x16x32_bf16(
            pf[kk], dT8[(n * 16 + r) * 8 + kk * 4 + q], acc, 0, 0, 0);
#pragma unroll
      for (int rr = 0; rr < 4; ++rr) {
        const int tr = wv * 16 + q * 4 + rr;
        core[(long)(c * 64 + tr) * VAL_DIM + h * DVv + v] = (bf16)acc[rr];
      }
    }
  }
}

// ---------------------------------------------------------------- RMSNorm + SiLU(z) gate
__global__ __launch_bounds__(256)
void gate_norm(const bf16* __restrict__ core, const bf16* __restrict__ zb,
               const void* __restrict__ normwr, bf16* __restrict__ gated,
               const unsigned* __restrict__ flagp) {
  const bool f32g = (*flagp != 0);
  const int s  = blockIdx.x;
  const int t  = threadIdx.x;
  const int h  = t >> 4;
  const int li = t & 15;
  const long base = (long)s * VAL_DIM + h * DVv + li * 8;
  bf16x8 c8 = *(const bf16x8*)(core + base);
  bf16x8 z8 = *(const bf16x8*)(zb + base);
  float x[8], z[8], nw[8];
  float ss = 0.f;
#pragma unroll
  for (int j = 0; j < 8; ++j) { x[j] = (float)c8[j]; z[j] = (float)z8[j]; ss += x[j] * x[j]; }
  if (f32g) {
    const float* np_ = (const float*)normwr + li * 8;
#pragma unroll
    for (int j = 0; j < 8; ++j) nw[j] = np_[j];
  } else {
    const u16* np_ = (const u16*)normwr + li * 8;
#pragma unroll
    for (int j = 0; j < 8; ++j) nw[j] = b2f(np_[j]);
  }
  ss += __shfl_xor(ss, 1); ss += __shfl_xor(ss, 2);
  ss += __shfl_xor(ss, 4); ss += __shfl_xor(ss, 8);
  float scale = rsqrtf(ss * (1.f / 128.f) + 1e-6f);
#pragma unroll
  for (int j = 0; j < 8; ++j) {
    float y = x[j] * scale * nw[j];
    y *= z[j] * sigmoidf_(z[j]);
    gated[base + j] = (bf16)y;
  }
}

// ---------------------------------------------------------------- launcher
extern "C" void kernel_launch(void* const* d_in, const int* in_sizes, int n_in,
                              void* d_out, int out_size, void* d_ws, size_t ws_size,
                              hipStream_t stream) {
  char* ws = (char*)d_ws;
  const bool big = ws_size >= ((48u << 20) + (512u << 10));

  if (big) {
    // ws: [0,8M) hsb -> dTg | [8,16M) wqkvb/wzb -> o1g | [16,24M) wqkvb -> zbuf
    //     [24,28M) mixed -> whig | [28,32M) mixed -> wlog | [32,40M) mixed -> woutb
    //     [40,44M) qbuf | [44,48M) kbuf -> (with qbuf) gated | [48M..) eg|beta|g|flag
    // d_out: [0,8M) vbuf -> core | [8,16M) dloc; final gemm overwrites all 16M f32.
    bf16*  hsb   = (bf16*)ws;
    bf16*  wqkvb = (bf16*)(ws + (8u << 20));
    bf16*  wzb   = (bf16*)(ws + (8u << 20));
    bf16*  zbuf  = (bf16*)(ws + (16u << 20));
    bf16*  mixed = (bf16*)(ws + (24u << 20));
    bf16*  whig  = (bf16*)(ws + (24u << 20));
    bf16*  wlog  = (bf16*)(ws + (28u << 20));
    bf16*  woutb = (bf16*)(ws + (32u << 20));
    bf16*  qbuf  = (bf16*)(ws + (40u << 20));
    bf16*  kbuf  = (bf16*)(ws + (44u << 20));
    bf16*  gated = (bf16*)(ws + (40u << 20));
    bf16*  dTg   = (bf16*)ws;
    bf16*  o1g   = (bf16*)(ws + (8u << 20));
    float* egp  = (float*)(ws + (48u << 20));
    float* betp = (float*)(ws + (48u << 20) + (128u << 10));
    float* gbp  = (float*)(ws + (48u << 20) + (256u << 10));
    unsigned* flagp = (unsigned*)(ws + (48u << 20) + (384u << 10));
    bf16* vbuf  = (bf16*)d_out;
    bf16* dlocp = (bf16*)((char*)d_out + (8u << 20));
    bf16* corep = (bf16*)d_out;

    detect_dtype<<<1, 64, 0, stream>>>((const u16*)d_in[0], flagp);
    proj_ab<<<SEQ / 8, 256, 0, stream>>>(d_in[0], d_in[2], d_in[3], d_in[6], d_in[7], egp, betp, gbp, flagp);
    cvt_bf16<<<(SEQ * HIDDEN) / 2048, 256, 0, stream>>>(d_in[0], hsb, (long)SEQ * HIDDEN, flagp);
    cvt_bf16<<<(CONV_DIM * HIDDEN) / 2048, 256, 0, stream>>>(d_in[1], wqkvb, (long)CONV_DIM * HIDDEN, flagp);
    gemm_nt<false><<<dim3(CONV_DIM / 128, SEQ / 128), 256, 0, stream>>>(hsb, wqkvb, mixed, CONV_DIM, HIDDEN, flagp, 0, 0);
    cvt_bf16<<<(VAL_DIM * HIDDEN) / 2048, 256, 0, stream>>>(d_in[4], wzb, (long)VAL_DIM * HIDDEN, flagp);
    conv_norm<<<dim3(SEQ, CONV_DIM / 256), 256, 0, stream>>>(mixed, d_in[5], qbuf, kbuf, vbuf, flagp);
    chunk_a<<<512 + 256 + 2048, 256, 0, stream>>>(kbuf, vbuf, gbp, betp, dlocp, whig, wlog,
                                                  hsb, wzb, zbuf, d_in[9], woutb, flagp);
    chunk_b<<<32, 256, 0, stream>>>(qbuf, kbuf, gbp, dlocp, whig, wlog, dTg, o1g);
    chunk_c<<<512, 256, 0, stream>>>(qbuf, kbuf, gbp, dTg, o1g, corep);
    gate_norm<<<SEQ, 256, 0, stream>>>(corep, zbuf, d_in[8], gated, flagp);
    gemm_nt<true><<<dim3(HIDDEN / 128, SEQ / 128), 256, 0, stream>>>(gated, woutb, d_out, HIDDEN, VAL_DIM, flagp, 0, 0);
  } else {
    // Fallback layout (peak 24.26 MiB): r6-style staging GEMMs; per-step scan.
    bf16* mixed = (bf16*)ws;
    bf16* qbuf  = (bf16*)(ws + (16u << 20));
    bf16* kbuf  = (bf16*)(ws + (20u << 20));
    bf16* zbuf  = (bf16*)ws;
    bf16* corep = (bf16*)(ws + (8u << 20));
    bf16* gated = (bf16*)(ws + (16u << 20));
    float* egp  = (float*)(ws + (24u << 20));
    float* betp = (float*)(ws + (24u << 20) + (128u << 10));
    unsigned* flagp = (unsigned*)(ws + (24u << 20) + (256u << 10));
    bf16* vbuf  = (bf16*)d_out;

    detect_dtype<<<1, 64, 0, stream>>>((const u16*)d_in[0], flagp);
    proj_ab<<<SEQ / 8, 256, 0, stream>>>(d_in[0], d_in[2], d_in[3], d_in[6], d_in[7], egp, betp, nullptr, flagp);
    gemm_nt<false><<<dim3(CONV_DIM / 128, SEQ / 128), 256, 0, stream>>>(d_in[0], d_in[1], mixed, CONV_DIM, HIDDEN, flagp, 1, 1);
    conv_norm<<<dim3(SEQ, CONV_DIM / 256), 256, 0, stream>>>(mixed, d_in[5], qbuf, kbuf, vbuf, flagp);
    gemm_nt<false><<<dim3(VAL_DIM / 128, SEQ / 128), 256, 0, stream>>>(d_in[0], d_in[4], zbuf, VAL_DIM, HIDDEN, flagp, 1, 1);
    fused_scan<<<128, 256, 0, stream>>>(qbuf, kbuf, vbuf, egp, betp, corep,
                                        nullptr, nullptr, nullptr, nullptr, nullptr, flagp,
                                        128, 0);
    gate_norm<<<SEQ, 256, 0, stream>>>(corep, zbuf, d_in[8], gated, flagp);
    gemm_nt<true><<<dim3(HIDDEN / 128, SEQ / 128), 256, 0, stream>>>(gated, d_in[9], d_out, HIDDEN, VAL_DIM, flagp, 0, 1);
  }
}